// Round 1
// baseline (12251.969 us; speedup 1.0000x reference)
//
#include <hip/hip_runtime.h>
#include <cfloat>
#include <cmath>

// ---------------- problem constants ----------------
constexpr int NB    = 16;    // batch
constexpr int IMGSZ = 384;
constexpr int PSZ   = 16;
constexpr int NCH   = 3;
constexpr int DMODEL= 256;
constexpr int DEPTH = 6;
constexpr int NHEAD = 4;
constexpr int DHEAD = 64;
constexpr int DQKV  = 768;   // 3*INNER
constexpr int DMLP  = 512;
constexpr int NCLS  = 21;
constexpr int HPATCH= 24;    // IMG/P
constexpr int NTOK  = 576;   // HP*HP
constexpr int NPD   = 768;   // C*P*P
constexpr int TOPK  = 16;
constexpr int NROWS = NB * NTOK;          // 9216
constexpr int OUT_TOTAL = NB * NCLS * IMGSZ * IMGSZ; // 49545216

// ---------------- patchify: img[B,3,384,384] -> A[9216,768] ----------------
__global__ __launch_bounds__(256) void k_patchify(const float* __restrict__ img,
                                                  float* __restrict__ A) {
    int t = blockIdx.x * 256 + threadIdx.x;
    if (t >= NROWS * NPD) return;
    int r  = t / NPD, pd = t - r * NPD;
    int b  = r / NTOK, n = r - b * NTOK;
    int hy = n / HPATCH, hx = n - hy * HPATCH;
    int c  = pd % NCH;  int q = pd / NCH;
    int p2 = q % PSZ;   int p1 = q / PSZ;
    A[t] = img[(((size_t)(b * NCH + c)) * IMGSZ + hy * PSZ + p1) * IMGSZ + hx * PSZ + p2];
}

// ---------------- fp32 tiled GEMM: out[M,N] = A[M,K] @ W[K,N] (+epilogue) ----
// EPI: 0=none, 1=bias+residual(out += ...), 2=bias+gelu(exact), 3=bias+pos_emb
template <int EPI>
__global__ __launch_bounds__(256) void k_gemm(const float* __restrict__ A,
                                              const float* __restrict__ W,
                                              const float* __restrict__ bias,
                                              const float* __restrict__ extra,
                                              float* __restrict__ out,
                                              int M, int Nn, int K) {
    __shared__ float As[64][17];
    __shared__ float Ws[16][64];
    const int bm = blockIdx.y * 64, bn = blockIdx.x * 64;
    const int tid = threadIdx.x;
    const int tx = tid & 15, ty = tid >> 4;
    float acc[4][4] = {};
    for (int k0 = 0; k0 < K; k0 += 16) {
        {
            const int kk = tid & 15, m0 = tid >> 4;
            #pragma unroll
            for (int mm = 0; mm < 64; mm += 16)
                As[m0 + mm][kk] = A[(size_t)(bm + m0 + mm) * K + k0 + kk];
            const int nn = tid & 63, kq = tid >> 6;
            #pragma unroll
            for (int kk2 = 0; kk2 < 16; kk2 += 4)
                Ws[kq + kk2][nn] = W[(size_t)(k0 + kq + kk2) * Nn + bn + nn];
        }
        __syncthreads();
        #pragma unroll
        for (int kk = 0; kk < 16; ++kk) {
            float a0 = As[ty * 4 + 0][kk];
            float a1 = As[ty * 4 + 1][kk];
            float a2 = As[ty * 4 + 2][kk];
            float a3 = As[ty * 4 + 3][kk];
            float4 bv = *reinterpret_cast<const float4*>(&Ws[kk][tx * 4]);
            acc[0][0] += a0 * bv.x; acc[0][1] += a0 * bv.y; acc[0][2] += a0 * bv.z; acc[0][3] += a0 * bv.w;
            acc[1][0] += a1 * bv.x; acc[1][1] += a1 * bv.y; acc[1][2] += a1 * bv.z; acc[1][3] += a1 * bv.w;
            acc[2][0] += a2 * bv.x; acc[2][1] += a2 * bv.y; acc[2][2] += a2 * bv.z; acc[2][3] += a2 * bv.w;
            acc[3][0] += a3 * bv.x; acc[3][1] += a3 * bv.y; acc[3][2] += a3 * bv.z; acc[3][3] += a3 * bv.w;
        }
        __syncthreads();
    }
    #pragma unroll
    for (int i = 0; i < 4; ++i) {
        const int r = bm + ty * 4 + i;
        #pragma unroll
        for (int j = 0; j < 4; ++j) {
            const int c = bn + tx * 4 + j;
            float v = acc[i][j];
            if (EPI != 0) v += bias[c];
            if (EPI == 1) v += out[(size_t)r * Nn + c];                 // residual in-place
            if (EPI == 2) v = 0.5f * v * (1.0f + erff(v * 0.70710678118f)); // exact gelu
            if (EPI == 3) v += extra[(size_t)(r % NTOK) * Nn + c];      // pos_emb
            out[(size_t)r * Nn + c] = v;
        }
    }
}

// ---------------- LayerNorm over last dim (256) ----------------
__global__ __launch_bounds__(256) void k_ln(const float* __restrict__ x,
                                            const float* __restrict__ g,
                                            const float* __restrict__ bb,
                                            float* __restrict__ y) {
    const int row = blockIdx.x, tid = threadIdx.x;
    float v = x[(size_t)row * DMODEL + tid];
    float s = v;
    #pragma unroll
    for (int off = 32; off; off >>= 1) s += __shfl_xor(s, off);
    __shared__ float ls[4], ls2[4];
    if ((tid & 63) == 0) ls[tid >> 6] = s;
    __syncthreads();
    float mu = (ls[0] + ls[1] + ls[2] + ls[3]) * (1.0f / DMODEL);
    float d = v - mu;
    float qq = d * d;
    #pragma unroll
    for (int off = 32; off; off >>= 1) qq += __shfl_xor(qq, off);
    if ((tid & 63) == 0) ls2[tid >> 6] = qq;
    __syncthreads();
    float var = (ls2[0] + ls2[1] + ls2[2] + ls2[3]) * (1.0f / DMODEL);
    y[(size_t)row * DMODEL + tid] = d * rsqrtf(var + 1e-5f) * g[tid] + bb[tid];
}

// ---------------- fused hybrid attention row kernel ----------------
// One block per (b,h,i). Computes dots row, exact top-16 (lax.top_k tie
// semantics via 16x argmax-with-min-index), combined sparse/global softmax,
// and PV. Output written as [B,N,INNER] (h-major) for the out-proj GEMM.
__global__ __launch_bounds__(256) void k_attn(const float* __restrict__ qkv,
                                              const float* __restrict__ alpha_l,
                                              float* __restrict__ ao) {
    const int i = blockIdx.x, h = blockIdx.y, b = blockIdx.z;
    const int tid = threadIdx.x;
    __shared__ float qv[DHEAD];
    __shared__ float s[NTOK];
    __shared__ float s2[NTOK];
    __shared__ int   selm[NTOK];
    __shared__ float wred[4];
    __shared__ int   wredi[4];
    __shared__ float bc;       // row max
    __shared__ float rg[4], rs[4];
    __shared__ float pv[4][DHEAD];

    if (tid < DHEAD) qv[tid] = qkv[((size_t)(b * NTOK + i)) * DQKV + h * DHEAD + tid];
    __syncthreads();

    // dots
    for (int j = tid; j < NTOK; j += 256) {
        const float4* kp = reinterpret_cast<const float4*>(
            qkv + ((size_t)(b * NTOK + j)) * DQKV + 256 + h * DHEAD);
        const float4* q4 = reinterpret_cast<const float4*>(qv);
        float acc = 0.f;
        #pragma unroll
        for (int d = 0; d < DHEAD / 4; ++d) {
            float4 kk = kp[d], qq = q4[d];
            acc += qq.x * kk.x + qq.y * kk.y + qq.z * kk.z + qq.w * kk.w;
        }
        float val = acc * 0.125f;  // DH^-0.5
        s[j] = val; s2[j] = val; selm[j] = 0;
    }
    __syncthreads();

    // top-16 selection
    for (int it = 0; it < TOPK; ++it) {
        float bv = -FLT_MAX; int bi = NTOK;
        for (int j = tid; j < NTOK; j += 256) {
            float v2 = s2[j];
            if (v2 > bv) { bv = v2; bi = j; }   // ascending j => strict '>' keeps min idx
        }
        #pragma unroll
        for (int off = 32; off; off >>= 1) {
            float ov = __shfl_xor(bv, off);
            int   oi = __shfl_xor(bi, off);
            if (ov > bv || (ov == bv && oi < bi)) { bv = ov; bi = oi; }
        }
        if ((tid & 63) == 0) { wred[tid >> 6] = bv; wredi[tid >> 6] = bi; }
        __syncthreads();
        if (tid == 0) {
            float fv = wred[0]; int fi = wredi[0];
            #pragma unroll
            for (int w = 1; w < 4; ++w) {
                float ov = wred[w]; int oi = wredi[w];
                if (ov > fv || (ov == fv && oi < fi)) { fv = ov; fi = oi; }
            }
            selm[fi] = 1; s2[fi] = -FLT_MAX;
            if (it == 0) bc = fv;              // global row max
        }
        __syncthreads();
    }
    const float M = bc;

    // softmax denominators
    float gs = 0.f, ss = 0.f;
    for (int j = tid; j < NTOK; j += 256) {
        float e = expf(s[j] - M);
        gs += e; if (selm[j]) ss += e;
    }
    #pragma unroll
    for (int off = 32; off; off >>= 1) { gs += __shfl_xor(gs, off); ss += __shfl_xor(ss, off); }
    if ((tid & 63) == 0) { rg[tid >> 6] = gs; rs[tid >> 6] = ss; }
    __syncthreads();
    const float Sg  = rg[0] + rg[1] + rg[2] + rg[3];
    const float Ssp = rs[0] + rs[1] + rs[2] + rs[3];
    float a = alpha_l[0];
    a = fminf(fmaxf(a, 0.f), 1.f);
    const float ca = a / Sg;
    const float cs = (1.f - a) / Ssp;
    for (int j = tid; j < NTOK; j += 256) {
        float e = expf(s[j] - M);
        s[j] = e * (ca + (selm[j] ? cs : 0.f));
    }
    __syncthreads();

    // PV: 4 j-groups x 64 dims
    const int d = tid & 63, gq = tid >> 6;
    float acc = 0.f;
    for (int j = gq; j < NTOK; j += 4)
        acc += s[j] * qkv[((size_t)(b * NTOK + j)) * DQKV + 512 + h * DHEAD + d];
    pv[gq][d] = acc;
    __syncthreads();
    if (tid < DHEAD) {
        float o = pv[0][tid] + pv[1][tid] + pv[2][tid] + pv[3][tid];
        ao[((size_t)(b * NTOK + i)) * DMODEL + h * DHEAD + tid] = o;
    }
}

// ---------------- [B,N,D] -> [B,D,24,24] ----------------
__global__ __launch_bounds__(256) void k_tonchw(const float* __restrict__ x,
                                                float* __restrict__ f) {
    int t = blockIdx.x * 256 + threadIdx.x;
    if (t >= NB * DMODEL * NTOK) return;
    int hx = t % HPATCH; int r1 = t / HPATCH;
    int hy = r1 % HPATCH; int r2 = r1 / HPATCH;
    int d  = r2 % DMODEL; int b = r2 / DMODEL;
    f[t] = x[((size_t)(b * NTOK) + hy * HPATCH + hx) * DMODEL + d];
}

// ---------------- conv1: 3x3 SAME, 256->128 @24x24, relu ----------------
__global__ __launch_bounds__(576) void k_conv1(const float* __restrict__ in,
                                               const float* __restrict__ w,
                                               const float* __restrict__ bias,
                                               float* __restrict__ outp) {
    const int oc = blockIdx.x & 127, b = blockIdx.x >> 7;
    const int tid = threadIdx.x;         // 0..575
    const int y = tid / 24, x = tid % 24;
    __shared__ float pl[4][576];
    float acc = 0.f;
    const float* wbase = w + (size_t)oc * (256 * 9);
    for (int ic0 = 0; ic0 < 256; ic0 += 4) {
        #pragma unroll
        for (int qd = 0; qd < 4; ++qd)
            pl[qd][tid] = in[((size_t)(b * 256 + ic0 + qd)) * 576 + tid];
        __syncthreads();
        #pragma unroll
        for (int qd = 0; qd < 4; ++qd) {
            const float* wp = wbase + (ic0 + qd) * 9;
            #pragma unroll
            for (int ky = 0; ky < 3; ++ky) {
                int yy = y + ky - 1;
                if ((unsigned)yy >= 24u) continue;
                #pragma unroll
                for (int kx = 0; kx < 3; ++kx) {
                    int xx = x + kx - 1;
                    if ((unsigned)xx >= 24u) continue;
                    acc += wp[ky * 3 + kx] * pl[qd][yy * 24 + xx];
                }
            }
        }
        __syncthreads();
    }
    acc += bias[oc];
    outp[((size_t)(b * 128 + oc)) * 576 + tid] = fmaxf(acc, 0.f);
}

// ---------------- conv2: 3x3 SAME, 128->64 @48x48, relu ----------------
__global__ __launch_bounds__(256) void k_conv2(const float* __restrict__ in,
                                               const float* __restrict__ w,
                                               const float* __restrict__ bias,
                                               float* __restrict__ outp) {
    const int oc = blockIdx.x & 63, b = blockIdx.x >> 6;
    const int tid = threadIdx.x;
    __shared__ float pl[2][2304];
    float acc[9] = {};
    const float* wbase = w + (size_t)oc * (128 * 9);
    for (int ic0 = 0; ic0 < 128; ic0 += 2) {
        #pragma unroll
        for (int qd = 0; qd < 2; ++qd)
            for (int t2 = tid; t2 < 2304; t2 += 256)
                pl[qd][t2] = in[((size_t)(b * 128 + ic0 + qd)) * 2304 + t2];
        __syncthreads();
        #pragma unroll
        for (int qd = 0; qd < 2; ++qd) {
            const float* wp = wbase + (ic0 + qd) * 9;
            float w9[9];
            #pragma unroll
            for (int tt = 0; tt < 9; ++tt) w9[tt] = wp[tt];
            #pragma unroll
            for (int p = 0; p < 9; ++p) {
                int pix = tid + p * 256;
                int py = pix / 48, px = pix - py * 48;
                float su = 0.f;
                #pragma unroll
                for (int ky = 0; ky < 3; ++ky) {
                    int yy = py + ky - 1;
                    if ((unsigned)yy >= 48u) continue;
                    #pragma unroll
                    for (int kx = 0; kx < 3; ++kx) {
                        int xx = px + kx - 1;
                        if ((unsigned)xx >= 48u) continue;
                        su += w9[ky * 3 + kx] * pl[qd][yy * 48 + xx];
                    }
                }
                acc[p] += su;
            }
        }
        __syncthreads();
    }
    const float bz = bias[oc];
    #pragma unroll
    for (int p = 0; p < 9; ++p)
        outp[((size_t)(b * 64 + oc)) * 2304 + tid + p * 256] = fmaxf(acc[p] + bz, 0.f);
}

// ---------------- bilinear helpers (jax.image.resize half-pixel semantics) --
__device__ __forceinline__ void bilin_axis(float sF, int H, int& i0, int& i1, float& f) {
    float fl = floorf(sF);
    f = sF - fl;
    int lo = (int)fl;
    i0 = lo < 0 ? 0 : (lo > H - 1 ? H - 1 : lo);
    int hi = lo + 1;
    i1 = hi < 0 ? 0 : (hi > H - 1 ? H - 1 : hi);
}

__global__ __launch_bounds__(256) void k_up2(const float* __restrict__ in,
                                             float* __restrict__ outp,
                                             int Cn, int Hin) {
    const int Ho = 2 * Hin;
    const int total = NB * Cn * Ho * Ho;
    int t = blockIdx.x * 256 + threadIdx.x;
    if (t >= total) return;
    int x = t % Ho; int r = t / Ho; int y = r % Ho; int bc = r / Ho;
    int i0, i1, j0, j1; float fy, fx;
    bilin_axis(0.5f * y - 0.25f, Hin, i0, i1, fy);
    bilin_axis(0.5f * x - 0.25f, Hin, j0, j1, fx);
    const float* p = in + (size_t)bc * Hin * Hin;
    outp[t] = (1.f - fy) * ((1.f - fx) * p[i0 * Hin + j0] + fx * p[i0 * Hin + j1])
            + fy        * ((1.f - fx) * p[i1 * Hin + j0] + fx * p[i1 * Hin + j1]);
}

// ---------------- conv3: 1x1, 64->21 @96x96 ----------------
__global__ __launch_bounds__(256) void k_conv3(const float* __restrict__ in,
                                               const float* __restrict__ w,
                                               const float* __restrict__ bias,
                                               float* __restrict__ outp) {
    int t = blockIdx.x * 256 + threadIdx.x;  // over B*96*96
    if (t >= NB * 9216) return;
    int pix = t % 9216, b = t / 9216;
    const float* ip = in + (size_t)b * 64 * 9216 + pix;
    float acc[NCLS];
    #pragma unroll
    for (int o = 0; o < NCLS; ++o) acc[o] = bias[o];
    for (int ic = 0; ic < 64; ++ic) {
        float v = ip[(size_t)ic * 9216];
        #pragma unroll
        for (int o = 0; o < NCLS; ++o) acc[o] += v * w[o * 64 + ic];
    }
    float* op = outp + (size_t)b * NCLS * 9216 + pix;
    #pragma unroll
    for (int o = 0; o < NCLS; ++o) op[(size_t)o * 9216] = acc[o];
}

// ---------------- final resize 96 -> 384 (4x bilinear) ----------------
__global__ __launch_bounds__(256) void k_resize4(const float* __restrict__ in,
                                                 float* __restrict__ outp) {
    int t = blockIdx.x * 256 + threadIdx.x;
    if (t >= OUT_TOTAL) return;
    int x = t % IMGSZ; int r = t / IMGSZ; int y = r % IMGSZ; int bc = r / IMGSZ;
    int i0, i1, j0, j1; float fy, fx;
    bilin_axis(0.25f * y - 0.375f, 96, i0, i1, fy);
    bilin_axis(0.25f * x - 0.375f, 96, j0, j1, fx);
    const float* p = in + (size_t)bc * 9216;
    outp[t] = (1.f - fy) * ((1.f - fx) * p[i0 * 96 + j0] + fx * p[i0 * 96 + j1])
            + fy        * ((1.f - fx) * p[i1 * 96 + j0] + fx * p[i1 * 96 + j1]);
}

// ---------------- orchestration ----------------
extern "C" void kernel_launch(void* const* d_in, const int* in_sizes, int n_in,
                              void* d_out, int out_size, void* d_ws, size_t ws_size,
                              hipStream_t stream) {
    const float* img     = (const float*)d_in[0];
    const float* patch_w = (const float*)d_in[1];
    const float* patch_b = (const float*)d_in[2];
    const float* pos_emb = (const float*)d_in[3];
    const float* ln1_g   = (const float*)d_in[4];
    const float* ln1_b   = (const float*)d_in[5];
    const float* qkv_w   = (const float*)d_in[6];
    const float* out_w   = (const float*)d_in[7];
    const float* out_b   = (const float*)d_in[8];
    const float* alpha   = (const float*)d_in[9];
    const float* ln2_g   = (const float*)d_in[10];
    const float* ln2_b   = (const float*)d_in[11];
    const float* ff_w1   = (const float*)d_in[12];
    const float* ff_b1   = (const float*)d_in[13];
    const float* ff_w2   = (const float*)d_in[14];
    const float* ff_b2   = (const float*)d_in[15];
    const float* lnf_g   = (const float*)d_in[16];
    const float* lnf_b   = (const float*)d_in[17];
    const float* conv1_w = (const float*)d_in[18];
    const float* conv1_b = (const float*)d_in[19];
    const float* conv2_w = (const float*)d_in[20];
    const float* conv2_b = (const float*)d_in[21];
    const float* conv3_w = (const float*)d_in[22];
    const float* conv3_b = (const float*)d_in[23];

    // workspace layout (floats). Total ~26.7M floats = ~107 MB.
    float* ws   = (float*)d_ws;
    float* x    = ws;                         // [9216,256]
    float* xn   = x    + (size_t)NROWS * DMODEL;   // [9216,256]
    float* qkvb = xn   + (size_t)NROWS * DMODEL;   // [9216,768]  (also patchify A, also MLP h)
    float* ao   = qkvb + (size_t)NROWS * DQKV;     // [9216,256]
    float* u2   = ao   + (size_t)NROWS * DMODEL;   // [16,64,96,96]
    float* c3   = u2   + (size_t)NB * 64 * 9216;   // [16,21,96,96]
    // conv-stage aliases of transformer buffers (safe: producers/consumers disjoint)
    float* f1 = x;     // [16,256,24,24]  (2359296)
    float* c1 = ao;    // [16,128,24,24]  (1179648 <= 2359296)
    float* u1 = qkvb;  // [16,128,48,48]  (4718592 <= 7077888)
    float* c2 = xn;    // [16,64,48,48]   (2359296)

    // ---- patch embed ----
    k_patchify<<<(NROWS * NPD + 255) / 256, 256, 0, stream>>>(img, qkvb);
    {
        dim3 g(DMODEL / 64, NROWS / 64);
        k_gemm<3><<<g, 256, 0, stream>>>(qkvb, patch_w, patch_b, pos_emb, x,
                                         NROWS, DMODEL, NPD);
    }

    // ---- transformer layers ----
    for (int l = 0; l < DEPTH; ++l) {
        k_ln<<<NROWS, 256, 0, stream>>>(x, ln1_g + l * DMODEL, ln1_b + l * DMODEL, xn);
        {
            dim3 g(DQKV / 64, NROWS / 64);
            k_gemm<0><<<g, 256, 0, stream>>>(xn, qkv_w + (size_t)l * DMODEL * DQKV,
                                             nullptr, nullptr, qkvb, NROWS, DQKV, DMODEL);
        }
        k_attn<<<dim3(NTOK, NHEAD, NB), 256, 0, stream>>>(qkvb, alpha + l, ao);
        {
            dim3 g(DMODEL / 64, NROWS / 64);
            k_gemm<1><<<g, 256, 0, stream>>>(ao, out_w + (size_t)l * DMODEL * DMODEL,
                                             out_b + l * DMODEL, nullptr, x,
                                             NROWS, DMODEL, DMODEL);
        }
        k_ln<<<NROWS, 256, 0, stream>>>(x, ln2_g + l * DMODEL, ln2_b + l * DMODEL, xn);
        {
            dim3 g(DMLP / 64, NROWS / 64);
            k_gemm<2><<<g, 256, 0, stream>>>(xn, ff_w1 + (size_t)l * DMODEL * DMLP,
                                             ff_b1 + l * DMLP, nullptr, qkvb,
                                             NROWS, DMLP, DMODEL);
        }
        {
            dim3 g(DMODEL / 64, NROWS / 64);
            k_gemm<1><<<g, 256, 0, stream>>>(qkvb, ff_w2 + (size_t)l * DMLP * DMODEL,
                                             ff_b2 + l * DMODEL, nullptr, x,
                                             NROWS, DMODEL, DMLP);
        }
    }

    // ---- head ----
    k_ln<<<NROWS, 256, 0, stream>>>(x, lnf_g, lnf_b, xn);
    k_tonchw<<<(NB * DMODEL * NTOK + 255) / 256, 256, 0, stream>>>(xn, f1);
    k_conv1<<<NB * 128, 576, 0, stream>>>(f1, conv1_w, conv1_b, c1);
    k_up2<<<(NB * 128 * 48 * 48 + 255) / 256, 256, 0, stream>>>(c1, u1, 128, 24);
    k_conv2<<<NB * 64, 256, 0, stream>>>(u1, conv2_w, conv2_b, c2);
    k_up2<<<(NB * 64 * 96 * 96 + 255) / 256, 256, 0, stream>>>(c2, u2, 64, 48);
    k_conv3<<<(NB * 9216 + 255) / 256, 256, 0, stream>>>(u2, conv3_w, conv3_b, c3);
    k_resize4<<<(OUT_TOTAL + 255) / 256, 256, 0, stream>>>(c3, (float*)d_out);
}

// Round 2
// 5534.592 us; speedup vs baseline: 2.2137x; 2.2137x over previous
//
#include <hip/hip_runtime.h>
#include <cfloat>
#include <cmath>

// ---------------- problem constants ----------------
constexpr int NB    = 16;    // batch
constexpr int IMGSZ = 384;
constexpr int PSZ   = 16;
constexpr int NCH   = 3;
constexpr int DMODEL= 256;
constexpr int DEPTH = 6;
constexpr int NHEAD = 4;
constexpr int DHEAD = 64;
constexpr int DQKV  = 768;   // 3*INNER
constexpr int DMLP  = 512;
constexpr int NCLS  = 21;
constexpr int HPATCH= 24;    // IMG/P
constexpr int NTOK  = 576;   // HP*HP
constexpr int NPD   = 768;   // C*P*P
constexpr int TOPK  = 16;
constexpr int NROWS = NB * NTOK;          // 9216
constexpr int OUT_TOTAL = NB * NCLS * IMGSZ * IMGSZ; // 49545216

// attention tiling
constexpr int RPB    = 16;          // query rows per block
constexpr int CHUNK  = 64;          // key/value chunk
constexpr int NCHUNK = NTOK / CHUNK; // 9
constexpr int KPAD   = 65;          // scalar-read pad (odd => conflict-free)
constexpr int VPAD   = 68;          // float4-read pad
constexpr int SPAD   = 577;         // scores row stride

// ---------------- patchify: img[B,3,384,384] -> A[9216,768] ----------------
__global__ __launch_bounds__(256) void k_patchify(const float* __restrict__ img,
                                                  float* __restrict__ A) {
    int t = blockIdx.x * 256 + threadIdx.x;
    if (t >= NROWS * NPD) return;
    int r  = t / NPD, pd = t - r * NPD;
    int b  = r / NTOK, n = r - b * NTOK;
    int hy = n / HPATCH, hx = n - hy * HPATCH;
    int c  = pd % NCH;  int q = pd / NCH;
    int p2 = q % PSZ;   int p1 = q / PSZ;
    A[t] = img[(((size_t)(b * NCH + c)) * IMGSZ + hy * PSZ + p1) * IMGSZ + hx * PSZ + p2];
}

// ---------------- fp32 tiled GEMM: out[M,N] = A[M,K] @ W[K,N] (+epilogue) ----
// EPI: 0=none, 1=bias+residual(out += ...), 2=bias+gelu(exact), 3=bias+pos_emb
template <int EPI>
__global__ __launch_bounds__(256) void k_gemm(const float* __restrict__ A,
                                              const float* __restrict__ W,
                                              const float* __restrict__ bias,
                                              const float* __restrict__ extra,
                                              float* __restrict__ out,
                                              int M, int Nn, int K) {
    __shared__ float As[64][17];
    __shared__ float Ws[16][64];
    const int bm = blockIdx.y * 64, bn = blockIdx.x * 64;
    const int tid = threadIdx.x;
    const int tx = tid & 15, ty = tid >> 4;
    float acc[4][4] = {};
    for (int k0 = 0; k0 < K; k0 += 16) {
        {
            const int kk = tid & 15, m0 = tid >> 4;
            #pragma unroll
            for (int mm = 0; mm < 64; mm += 16)
                As[m0 + mm][kk] = A[(size_t)(bm + m0 + mm) * K + k0 + kk];
            const int nn = tid & 63, kq = tid >> 6;
            #pragma unroll
            for (int kk2 = 0; kk2 < 16; kk2 += 4)
                Ws[kq + kk2][nn] = W[(size_t)(k0 + kq + kk2) * Nn + bn + nn];
        }
        __syncthreads();
        #pragma unroll
        for (int kk = 0; kk < 16; ++kk) {
            float a0 = As[ty * 4 + 0][kk];
            float a1 = As[ty * 4 + 1][kk];
            float a2 = As[ty * 4 + 2][kk];
            float a3 = As[ty * 4 + 3][kk];
            float4 bv = *reinterpret_cast<const float4*>(&Ws[kk][tx * 4]);
            acc[0][0] += a0 * bv.x; acc[0][1] += a0 * bv.y; acc[0][2] += a0 * bv.z; acc[0][3] += a0 * bv.w;
            acc[1][0] += a1 * bv.x; acc[1][1] += a1 * bv.y; acc[1][2] += a1 * bv.z; acc[1][3] += a1 * bv.w;
            acc[2][0] += a2 * bv.x; acc[2][1] += a2 * bv.y; acc[2][2] += a2 * bv.z; acc[2][3] += a2 * bv.w;
            acc[3][0] += a3 * bv.x; acc[3][1] += a3 * bv.y; acc[3][2] += a3 * bv.z; acc[3][3] += a3 * bv.w;
        }
        __syncthreads();
    }
    #pragma unroll
    for (int i = 0; i < 4; ++i) {
        const int r = bm + ty * 4 + i;
        #pragma unroll
        for (int j = 0; j < 4; ++j) {
            const int c = bn + tx * 4 + j;
            float v = acc[i][j];
            if (EPI != 0) v += bias[c];
            if (EPI == 1) v += out[(size_t)r * Nn + c];                 // residual in-place
            if (EPI == 2) v = 0.5f * v * (1.0f + erff(v * 0.70710678118f)); // exact gelu
            if (EPI == 3) v += extra[(size_t)(r % NTOK) * Nn + c];      // pos_emb
            out[(size_t)r * Nn + c] = v;
        }
    }
}

// ---------------- LayerNorm over last dim (256) ----------------
__global__ __launch_bounds__(256) void k_ln(const float* __restrict__ x,
                                            const float* __restrict__ g,
                                            const float* __restrict__ bb,
                                            float* __restrict__ y) {
    const int row = blockIdx.x, tid = threadIdx.x;
    float v = x[(size_t)row * DMODEL + tid];
    float s = v;
    #pragma unroll
    for (int off = 32; off; off >>= 1) s += __shfl_xor(s, off);
    __shared__ float ls[4], ls2[4];
    if ((tid & 63) == 0) ls[tid >> 6] = s;
    __syncthreads();
    float mu = (ls[0] + ls[1] + ls[2] + ls[3]) * (1.0f / DMODEL);
    float d = v - mu;
    float qq = d * d;
    #pragma unroll
    for (int off = 32; off; off >>= 1) qq += __shfl_xor(qq, off);
    if ((tid & 63) == 0) ls2[tid >> 6] = qq;
    __syncthreads();
    float var = (ls2[0] + ls2[1] + ls2[2] + ls2[3]) * (1.0f / DMODEL);
    y[(size_t)row * DMODEL + tid] = d * rsqrtf(var + 1e-5f) * g[tid] + bb[tid];
}

// ---------------- fused hybrid attention, 16 rows/block ----------------
// Block handles 16 query rows of one (b,h). K/V staged in LDS chunk-wise
// (64 j per chunk, reused by all 16 rows). Dots: 2x2 register tile.
// Top-16: wave-per-row, fully in registers (9 vals/lane), exact
// argmax-with-min-index semantics matching lax.top_k. PV: 2row x 8dim tile
// with 4-way j-split reduced by in-wave shuffles.
__global__ __launch_bounds__(256) void k_attn(const float* __restrict__ qkv,
                                              const float* __restrict__ alpha_l,
                                              float* __restrict__ ao) {
    __shared__ float qs[RPB][KPAD];
    __shared__ float sc[RPB][SPAD];
    __shared__ float kv[CHUNK * VPAD];

    const int tid = threadIdx.x;
    const int h = blockIdx.y, b = blockIdx.z;
    const int i0 = blockIdx.x * RPB;

    // ---- stage Q (16 rows x 64 d) ----
    {
        int r = tid >> 6, d = tid & 63;
        #pragma unroll
        for (int rep = 0; rep < 4; ++rep)
            qs[rep * 4 + r][d] =
                qkv[((size_t)(b * NTOK + i0 + rep * 4 + r)) * DQKV + h * DHEAD + d];
    }

    // ---- dots: sc[r][j] = (q_r . k_j) * scale ----
    const int rp = tid >> 5;   // 0..7 -> rows 2rp, 2rp+1
    const int jp = tid & 31;   // 0..31 -> cols 2jp, 2jp+1 within chunk
    for (int c = 0; c < NCHUNK; ++c) {
        __syncthreads();
        #pragma unroll
        for (int rep = 0; rep < 4; ++rep) {
            int idx = rep * 256 + tid;
            int jj = idx >> 4, dq = idx & 15;
            const float4 v = *reinterpret_cast<const float4*>(
                &qkv[((size_t)(b * NTOK + c * CHUNK + jj)) * DQKV + DMODEL + h * DHEAD + dq * 4]);
            float* p = &kv[jj * KPAD + dq * 4];
            p[0] = v.x; p[1] = v.y; p[2] = v.z; p[3] = v.w;
        }
        __syncthreads();
        float a00 = 0.f, a01 = 0.f, a10 = 0.f, a11 = 0.f;
        const float* q0 = qs[2 * rp];
        const float* q1 = qs[2 * rp + 1];
        const float* k0 = &kv[(2 * jp) * KPAD];
        const float* k1 = &kv[(2 * jp + 1) * KPAD];
        #pragma unroll
        for (int d = 0; d < DHEAD; ++d) {
            float x0 = q0[d], x1 = q1[d], y0 = k0[d], y1 = k1[d];
            a00 += x0 * y0; a01 += x0 * y1;
            a10 += x1 * y0; a11 += x1 * y1;
        }
        const int j0 = c * CHUNK + 2 * jp;
        sc[2 * rp][j0]     = a00 * 0.125f;
        sc[2 * rp][j0 + 1] = a01 * 0.125f;
        sc[2 * rp + 1][j0]     = a10 * 0.125f;
        sc[2 * rp + 1][j0 + 1] = a11 * 0.125f;
    }
    __syncthreads();

    // ---- top-16 + combined softmax weights (wave per row, 4 rows/wave) ----
    const int wv = tid >> 6, lane = tid & 63;
    float alpha = alpha_l[0];
    alpha = fminf(fmaxf(alpha, 0.f), 1.f);
    for (int rr = 0; rr < 4; ++rr) {
        const int row = wv * 4 + rr;
        float o[9], vv[9];
        #pragma unroll
        for (int t = 0; t < 9; ++t) { o[t] = sc[row][t * 64 + lane]; vv[t] = o[t]; }
        unsigned mask = 0; float M = 0.f;
        for (int k = 0; k < TOPK; ++k) {
            float bv = vv[0]; int bt = 0;
            #pragma unroll
            for (int t = 1; t < 9; ++t)
                if (vv[t] > bv) { bv = vv[t]; bt = t; }   // strict > keeps min t (min j)
            int bj = bt * 64 + lane;
            #pragma unroll
            for (int off = 1; off < 64; off <<= 1) {
                float ov = __shfl_xor(bv, off);
                int   oj = __shfl_xor(bj, off);
                if (ov > bv || (ov == bv && oj < bj)) { bv = ov; bj = oj; }
            }
            if (k == 0) M = bv;
            if ((bj & 63) == lane) { vv[bj >> 6] = -FLT_MAX; mask |= 1u << (bj >> 6); }
        }
        float e[9], gsl = 0.f, ssl = 0.f;
        #pragma unroll
        for (int t = 0; t < 9; ++t) {
            e[t] = expf(o[t] - M);
            gsl += e[t];
            if ((mask >> t) & 1u) ssl += e[t];
        }
        #pragma unroll
        for (int off = 1; off < 64; off <<= 1) {
            gsl += __shfl_xor(gsl, off);
            ssl += __shfl_xor(ssl, off);
        }
        const float ca = alpha / gsl, cs = (1.f - alpha) / ssl;
        #pragma unroll
        for (int t = 0; t < 9; ++t)
            sc[row][t * 64 + lane] = e[t] * (ca + (((mask >> t) & 1u) ? cs : 0.f));
    }

    // ---- PV: out[r][d] = sum_j w[r][j] * v[j][d] ----
    const int rp2 = tid >> 5;          // 0..7 -> rows 2rp2, 2rp2+1
    const int jq  = (tid >> 3) & 3;    // 4-way j split (in-wave, lane bits 3..4)
    const int dg  = tid & 7;           // 8 d-groups of 8
    float4 acc0a = {0,0,0,0}, acc0b = {0,0,0,0};
    float4 acc1a = {0,0,0,0}, acc1b = {0,0,0,0};
    for (int c = 0; c < NCHUNK; ++c) {
        __syncthreads();
        #pragma unroll
        for (int rep = 0; rep < 4; ++rep) {
            int idx = rep * 256 + tid;
            int jj = idx >> 4, dq = idx & 15;
            const float4 v = *reinterpret_cast<const float4*>(
                &qkv[((size_t)(b * NTOK + c * CHUNK + jj)) * DQKV + 2 * DMODEL + h * DHEAD + dq * 4]);
            *reinterpret_cast<float4*>(&kv[jj * VPAD + dq * 4]) = v;
        }
        __syncthreads();
        const int r0 = 2 * rp2, r1 = r0 + 1;
        #pragma unroll
        for (int t = 0; t < 16; ++t) {
            const int jj = jq + 4 * t;
            const float w0 = sc[r0][c * CHUNK + jj];
            const float w1 = sc[r1][c * CHUNK + jj];
            const float4 va = *reinterpret_cast<const float4*>(&kv[jj * VPAD + dg * 8]);
            const float4 vb = *reinterpret_cast<const float4*>(&kv[jj * VPAD + dg * 8 + 4]);
            acc0a.x += w0 * va.x; acc0a.y += w0 * va.y; acc0a.z += w0 * va.z; acc0a.w += w0 * va.w;
            acc0b.x += w0 * vb.x; acc0b.y += w0 * vb.y; acc0b.z += w0 * vb.z; acc0b.w += w0 * vb.w;
            acc1a.x += w1 * va.x; acc1a.y += w1 * va.y; acc1a.z += w1 * va.z; acc1a.w += w1 * va.w;
            acc1b.x += w1 * vb.x; acc1b.y += w1 * vb.y; acc1b.z += w1 * vb.z; acc1b.w += w1 * vb.w;
        }
    }
    // reduce over jq (lane bits 3,4 -> shuffle dist 8,16: in-wave)
    #pragma unroll
    for (int off = 8; off <= 16; off <<= 1) {
        acc0a.x += __shfl_xor(acc0a.x, off); acc0a.y += __shfl_xor(acc0a.y, off);
        acc0a.z += __shfl_xor(acc0a.z, off); acc0a.w += __shfl_xor(acc0a.w, off);
        acc0b.x += __shfl_xor(acc0b.x, off); acc0b.y += __shfl_xor(acc0b.y, off);
        acc0b.z += __shfl_xor(acc0b.z, off); acc0b.w += __shfl_xor(acc0b.w, off);
        acc1a.x += __shfl_xor(acc1a.x, off); acc1a.y += __shfl_xor(acc1a.y, off);
        acc1a.z += __shfl_xor(acc1a.z, off); acc1a.w += __shfl_xor(acc1a.w, off);
        acc1b.x += __shfl_xor(acc1b.x, off); acc1b.y += __shfl_xor(acc1b.y, off);
        acc1b.z += __shfl_xor(acc1b.z, off); acc1b.w += __shfl_xor(acc1b.w, off);
    }
    if (jq == 0) {
        const int r0 = 2 * rp2, r1 = r0 + 1;
        float* p0 = &ao[((size_t)(b * NTOK + i0 + r0)) * DMODEL + h * DHEAD + dg * 8];
        float* p1 = &ao[((size_t)(b * NTOK + i0 + r1)) * DMODEL + h * DHEAD + dg * 8];
        *reinterpret_cast<float4*>(p0)     = acc0a;
        *reinterpret_cast<float4*>(p0 + 4) = acc0b;
        *reinterpret_cast<float4*>(p1)     = acc1a;
        *reinterpret_cast<float4*>(p1 + 4) = acc1b;
    }
}

// ---------------- [B,N,D] -> [B,D,24,24] ----------------
__global__ __launch_bounds__(256) void k_tonchw(const float* __restrict__ x,
                                                float* __restrict__ f) {
    int t = blockIdx.x * 256 + threadIdx.x;
    if (t >= NB * DMODEL * NTOK) return;
    int hx = t % HPATCH; int r1 = t / HPATCH;
    int hy = r1 % HPATCH; int r2 = r1 / HPATCH;
    int d  = r2 % DMODEL; int b = r2 / DMODEL;
    f[t] = x[((size_t)(b * NTOK) + hy * HPATCH + hx) * DMODEL + d];
}

// ---------------- conv1: 3x3 SAME, 256->128 @24x24, relu ----------------
__global__ __launch_bounds__(576) void k_conv1(const float* __restrict__ in,
                                               const float* __restrict__ w,
                                               const float* __restrict__ bias,
                                               float* __restrict__ outp) {
    const int oc = blockIdx.x & 127, b = blockIdx.x >> 7;
    const int tid = threadIdx.x;         // 0..575
    const int y = tid / 24, x = tid % 24;
    __shared__ float pl[4][576];
    float acc = 0.f;
    const float* wbase = w + (size_t)oc * (256 * 9);
    for (int ic0 = 0; ic0 < 256; ic0 += 4) {
        #pragma unroll
        for (int qd = 0; qd < 4; ++qd)
            pl[qd][tid] = in[((size_t)(b * 256 + ic0 + qd)) * 576 + tid];
        __syncthreads();
        #pragma unroll
        for (int qd = 0; qd < 4; ++qd) {
            const float* wp = wbase + (ic0 + qd) * 9;
            #pragma unroll
            for (int ky = 0; ky < 3; ++ky) {
                int yy = y + ky - 1;
                if ((unsigned)yy >= 24u) continue;
                #pragma unroll
                for (int kx = 0; kx < 3; ++kx) {
                    int xx = x + kx - 1;
                    if ((unsigned)xx >= 24u) continue;
                    acc += wp[ky * 3 + kx] * pl[qd][yy * 24 + xx];
                }
            }
        }
        __syncthreads();
    }
    acc += bias[oc];
    outp[((size_t)(b * 128 + oc)) * 576 + tid] = fmaxf(acc, 0.f);
}

// ---------------- conv2: 3x3 SAME, 128->64 @48x48, relu ----------------
__global__ __launch_bounds__(256) void k_conv2(const float* __restrict__ in,
                                               const float* __restrict__ w,
                                               const float* __restrict__ bias,
                                               float* __restrict__ outp) {
    const int oc = blockIdx.x & 63, b = blockIdx.x >> 6;
    const int tid = threadIdx.x;
    __shared__ float pl[2][2304];
    float acc[9] = {};
    const float* wbase = w + (size_t)oc * (128 * 9);
    for (int ic0 = 0; ic0 < 128; ic0 += 2) {
        #pragma unroll
        for (int qd = 0; qd < 2; ++qd)
            for (int t2 = tid; t2 < 2304; t2 += 256)
                pl[qd][t2] = in[((size_t)(b * 128 + ic0 + qd)) * 2304 + t2];
        __syncthreads();
        #pragma unroll
        for (int qd = 0; qd < 2; ++qd) {
            const float* wp = wbase + (ic0 + qd) * 9;
            float w9[9];
            #pragma unroll
            for (int tt = 0; tt < 9; ++tt) w9[tt] = wp[tt];
            #pragma unroll
            for (int p = 0; p < 9; ++p) {
                int pix = tid + p * 256;
                int py = pix / 48, px = pix - py * 48;
                float su = 0.f;
                #pragma unroll
                for (int ky = 0; ky < 3; ++ky) {
                    int yy = py + ky - 1;
                    if ((unsigned)yy >= 48u) continue;
                    #pragma unroll
                    for (int kx = 0; kx < 3; ++kx) {
                        int xx = px + kx - 1;
                        if ((unsigned)xx >= 48u) continue;
                        su += w9[ky * 3 + kx] * pl[qd][yy * 48 + xx];
                    }
                }
                acc[p] += su;
            }
        }
        __syncthreads();
    }
    const float bz = bias[oc];
    #pragma unroll
    for (int p = 0; p < 9; ++p)
        outp[((size_t)(b * 64 + oc)) * 2304 + tid + p * 256] = fmaxf(acc[p] + bz, 0.f);
}

// ---------------- bilinear helpers (jax.image.resize half-pixel semantics) --
__device__ __forceinline__ void bilin_axis(float sF, int H, int& i0, int& i1, float& f) {
    float fl = floorf(sF);
    f = sF - fl;
    int lo = (int)fl;
    i0 = lo < 0 ? 0 : (lo > H - 1 ? H - 1 : lo);
    int hi = lo + 1;
    i1 = hi < 0 ? 0 : (hi > H - 1 ? H - 1 : hi);
}

__global__ __launch_bounds__(256) void k_up2(const float* __restrict__ in,
                                             float* __restrict__ outp,
                                             int Cn, int Hin) {
    const int Ho = 2 * Hin;
    const int total = NB * Cn * Ho * Ho;
    int t = blockIdx.x * 256 + threadIdx.x;
    if (t >= total) return;
    int x = t % Ho; int r = t / Ho; int y = r % Ho; int bc = r / Ho;
    int i0, i1, j0, j1; float fy, fx;
    bilin_axis(0.5f * y - 0.25f, Hin, i0, i1, fy);
    bilin_axis(0.5f * x - 0.25f, Hin, j0, j1, fx);
    const float* p = in + (size_t)bc * Hin * Hin;
    outp[t] = (1.f - fy) * ((1.f - fx) * p[i0 * Hin + j0] + fx * p[i0 * Hin + j1])
            + fy        * ((1.f - fx) * p[i1 * Hin + j0] + fx * p[i1 * Hin + j1]);
}

// ---------------- conv3: 1x1, 64->21 @96x96 ----------------
__global__ __launch_bounds__(256) void k_conv3(const float* __restrict__ in,
                                               const float* __restrict__ w,
                                               const float* __restrict__ bias,
                                               float* __restrict__ outp) {
    int t = blockIdx.x * 256 + threadIdx.x;  // over B*96*96
    if (t >= NB * 9216) return;
    int pix = t % 9216, b = t / 9216;
    const float* ip = in + (size_t)b * 64 * 9216 + pix;
    float acc[NCLS];
    #pragma unroll
    for (int o = 0; o < NCLS; ++o) acc[o] = bias[o];
    for (int ic = 0; ic < 64; ++ic) {
        float v = ip[(size_t)ic * 9216];
        #pragma unroll
        for (int o = 0; o < NCLS; ++o) acc[o] += v * w[o * 64 + ic];
    }
    float* op = outp + (size_t)b * NCLS * 9216 + pix;
    #pragma unroll
    for (int o = 0; o < NCLS; ++o) op[(size_t)o * 9216] = acc[o];
}

// ---------------- final resize 96 -> 384 (4x bilinear) ----------------
__global__ __launch_bounds__(256) void k_resize4(const float* __restrict__ in,
                                                 float* __restrict__ outp) {
    int t = blockIdx.x * 256 + threadIdx.x;
    if (t >= OUT_TOTAL) return;
    int x = t % IMGSZ; int r = t / IMGSZ; int y = r % IMGSZ; int bc = r / IMGSZ;
    int i0, i1, j0, j1; float fy, fx;
    bilin_axis(0.25f * y - 0.375f, 96, i0, i1, fy);
    bilin_axis(0.25f * x - 0.375f, 96, j0, j1, fx);
    const float* p = in + (size_t)bc * 9216;
    outp[t] = (1.f - fy) * ((1.f - fx) * p[i0 * 96 + j0] + fx * p[i0 * 96 + j1])
            + fy        * ((1.f - fx) * p[i1 * 96 + j0] + fx * p[i1 * 96 + j1]);
}

// ---------------- orchestration ----------------
extern "C" void kernel_launch(void* const* d_in, const int* in_sizes, int n_in,
                              void* d_out, int out_size, void* d_ws, size_t ws_size,
                              hipStream_t stream) {
    const float* img     = (const float*)d_in[0];
    const float* patch_w = (const float*)d_in[1];
    const float* patch_b = (const float*)d_in[2];
    const float* pos_emb = (const float*)d_in[3];
    const float* ln1_g   = (const float*)d_in[4];
    const float* ln1_b   = (const float*)d_in[5];
    const float* qkv_w   = (const float*)d_in[6];
    const float* out_w   = (const float*)d_in[7];
    const float* out_b   = (const float*)d_in[8];
    const float* alpha   = (const float*)d_in[9];
    const float* ln2_g   = (const float*)d_in[10];
    const float* ln2_b   = (const float*)d_in[11];
    const float* ff_w1   = (const float*)d_in[12];
    const float* ff_b1   = (const float*)d_in[13];
    const float* ff_w2   = (const float*)d_in[14];
    const float* ff_b2   = (const float*)d_in[15];
    const float* lnf_g   = (const float*)d_in[16];
    const float* lnf_b   = (const float*)d_in[17];
    const float* conv1_w = (const float*)d_in[18];
    const float* conv1_b = (const float*)d_in[19];
    const float* conv2_w = (const float*)d_in[20];
    const float* conv2_b = (const float*)d_in[21];
    const float* conv3_w = (const float*)d_in[22];
    const float* conv3_b = (const float*)d_in[23];

    // workspace layout (floats). Total ~26.7M floats = ~107 MB.
    float* ws   = (float*)d_ws;
    float* x    = ws;                         // [9216,256]
    float* xn   = x    + (size_t)NROWS * DMODEL;   // [9216,256]
    float* qkvb = xn   + (size_t)NROWS * DMODEL;   // [9216,768]  (also patchify A, also MLP h)
    float* ao   = qkvb + (size_t)NROWS * DQKV;     // [9216,256]
    float* u2   = ao   + (size_t)NROWS * DMODEL;   // [16,64,96,96]
    float* c3   = u2   + (size_t)NB * 64 * 9216;   // [16,21,96,96]
    // conv-stage aliases of transformer buffers (safe: producers/consumers disjoint)
    float* f1 = x;     // [16,256,24,24]
    float* c1 = ao;    // [16,128,24,24]
    float* u1 = qkvb;  // [16,128,48,48]
    float* c2 = xn;    // [16,64,48,48]

    // ---- patch embed ----
    k_patchify<<<(NROWS * NPD + 255) / 256, 256, 0, stream>>>(img, qkvb);
    {
        dim3 g(DMODEL / 64, NROWS / 64);
        k_gemm<3><<<g, 256, 0, stream>>>(qkvb, patch_w, patch_b, pos_emb, x,
                                         NROWS, DMODEL, NPD);
    }

    // ---- transformer layers ----
    for (int l = 0; l < DEPTH; ++l) {
        k_ln<<<NROWS, 256, 0, stream>>>(x, ln1_g + l * DMODEL, ln1_b + l * DMODEL, xn);
        {
            dim3 g(DQKV / 64, NROWS / 64);
            k_gemm<0><<<g, 256, 0, stream>>>(xn, qkv_w + (size_t)l * DMODEL * DQKV,
                                             nullptr, nullptr, qkvb, NROWS, DQKV, DMODEL);
        }
        k_attn<<<dim3(NTOK / RPB, NHEAD, NB), 256, 0, stream>>>(qkvb, alpha + l, ao);
        {
            dim3 g(DMODEL / 64, NROWS / 64);
            k_gemm<1><<<g, 256, 0, stream>>>(ao, out_w + (size_t)l * DMODEL * DMODEL,
                                             out_b + l * DMODEL, nullptr, x,
                                             NROWS, DMODEL, DMODEL);
        }
        k_ln<<<NROWS, 256, 0, stream>>>(x, ln2_g + l * DMODEL, ln2_b + l * DMODEL, xn);
        {
            dim3 g(DMLP / 64, NROWS / 64);
            k_gemm<2><<<g, 256, 0, stream>>>(xn, ff_w1 + (size_t)l * DMODEL * DMLP,
                                             ff_b1 + l * DMLP, nullptr, qkvb,
                                             NROWS, DMLP, DMODEL);
        }
        {
            dim3 g(DMODEL / 64, NROWS / 64);
            k_gemm<1><<<g, 256, 0, stream>>>(qkvb, ff_w2 + (size_t)l * DMLP * DMODEL,
                                             ff_b2 + l * DMODEL, nullptr, x,
                                             NROWS, DMODEL, DMLP);
        }
    }

    // ---- head ----
    k_ln<<<NROWS, 256, 0, stream>>>(x, lnf_g, lnf_b, xn);
    k_tonchw<<<(NB * DMODEL * NTOK + 255) / 256, 256, 0, stream>>>(xn, f1);
    k_conv1<<<NB * 128, 576, 0, stream>>>(f1, conv1_w, conv1_b, c1);
    k_up2<<<(NB * 128 * 48 * 48 + 255) / 256, 256, 0, stream>>>(c1, u1, 128, 24);
    k_conv2<<<NB * 64, 256, 0, stream>>>(u1, conv2_w, conv2_b, c2);
    k_up2<<<(NB * 64 * 96 * 96 + 255) / 256, 256, 0, stream>>>(c2, u2, 64, 48);
    k_conv3<<<(NB * 9216 + 255) / 256, 256, 0, stream>>>(u2, conv3_w, conv3_b, c3);
    k_resize4<<<(OUT_TOTAL + 255) / 256, 256, 0, stream>>>(c3, (float*)d_out);
}

// Round 3
// 3475.497 us; speedup vs baseline: 3.5252x; 1.5925x over previous
//
#include <hip/hip_runtime.h>
#include <cfloat>
#include <cmath>

// ---------------- problem constants ----------------
constexpr int NB    = 16;    // batch
constexpr int IMGSZ = 384;
constexpr int PSZ   = 16;
constexpr int NCH   = 3;
constexpr int DMODEL= 256;
constexpr int DEPTH = 6;
constexpr int NHEAD = 4;
constexpr int DHEAD = 64;
constexpr int DQKV  = 768;   // 3*INNER
constexpr int DMLP  = 512;
constexpr int NCLS  = 21;
constexpr int HPATCH= 24;    // IMG/P
constexpr int NTOK  = 576;   // HP*HP
constexpr int NPD   = 768;   // C*P*P
constexpr int TOPK  = 16;
constexpr int NROWS = NB * NTOK;          // 9216
constexpr int OUT_TOTAL = NB * NCLS * IMGSZ * IMGSZ; // 49545216

// attention tiling
constexpr int RPB    = 16;          // query rows per block
constexpr int CHUNK  = 64;          // key/value chunk
constexpr int NCHUNK = NTOK / CHUNK; // 9
constexpr int KPAD   = 65;
constexpr int VPAD   = 68;
constexpr int SPAD   = 577;

typedef __attribute__((ext_vector_type(8))) short bf16x8;
typedef __attribute__((ext_vector_type(4))) float f32x4;

__device__ __forceinline__ unsigned short f2bf(float f) {
    unsigned u = __builtin_bit_cast(unsigned, f);
    unsigned r = (u + 0x7FFFu + ((u >> 16) & 1u)) >> 16;
    return (unsigned short)r;
}
__device__ __forceinline__ float bf2f(unsigned short h) {
    unsigned u = ((unsigned)h) << 16;
    return __builtin_bit_cast(float, u);
}

// ---------------- weight cast+transpose: W[L][K][N] f32 -> Wt[L][N][K] bf16 --
__global__ __launch_bounds__(256) void k_castT(const float* __restrict__ src,
                                               unsigned short* __restrict__ dst,
                                               int K, int N) {
    int t = blockIdx.x * 256 + threadIdx.x;
    if (t >= K * N) return;
    size_t base = (size_t)blockIdx.y * K * N;
    int n = t / K, k = t - n * K;
    dst[base + t] = f2bf(src[base + (size_t)k * N + n]);
}

// conv w [OC][IC][3][3] f32 -> [OC][9][IC] bf16 (tap-major K)
template <int IC>
__global__ __launch_bounds__(256) void k_castConv(const float* __restrict__ src,
                                                  unsigned short* __restrict__ dst,
                                                  int OC) {
    int t = blockIdx.x * 256 + threadIdx.x;
    if (t >= OC * 9 * IC) return;
    int oc = t / (9 * IC);
    int r = t - oc * 9 * IC;
    int tap = r / IC, ic = r - tap * IC;
    dst[t] = f2bf(src[((size_t)(oc * IC + ic)) * 9 + tap]);
}

// ---------------- patchify: img[B,3,384,384] -> A[9216,768] bf16 ------------
__global__ __launch_bounds__(256) void k_patchify(const float* __restrict__ img,
                                                  unsigned short* __restrict__ A) {
    int t = blockIdx.x * 256 + threadIdx.x;
    if (t >= NROWS * NPD) return;
    int r  = t / NPD, pd = t - r * NPD;
    int b  = r / NTOK, n = r - b * NTOK;
    int hy = n / HPATCH, hx = n - hy * HPATCH;
    int c  = pd % NCH;  int q = pd / NCH;
    int p2 = q % PSZ;   int p1 = q / PSZ;
    A[t] = f2bf(img[(((size_t)(b * NCH + c)) * IMGSZ + hy * PSZ + p1) * IMGSZ + hx * PSZ + p2]);
}

// ---------------- unified bf16 MFMA GEMM / implicit conv --------------------
// out[M,N] = A[M,K](bf16) @ Wt[N,K]^T(bf16), fp32 accumulate.
// EPI: 0 none->f32 | 1 bias+residual->f32 | 2 bias+gelu->bf16
//      3 bias+posemb->f32 | 4 bias+relu->bf16
// CIN>0: gather A from NHWC [NB][H][W][CIN] with 3x3 taps (K = 9*CIN, tap-major)
template <int BM, int BN, int EPI, int CIN>
__global__ __launch_bounds__(256) void k_mm(
    const unsigned short* __restrict__ Abf,
    const unsigned short* __restrict__ Wt,
    const float* __restrict__ bias,
    const float* __restrict__ extra,
    float* __restrict__ outf,
    unsigned short* __restrict__ outb,
    int M, int Nn, int K, int H, int Wd)
{
    constexpr int MF = BM / 32;
    constexpr int NF = BN / 32;
    constexpr bool GATHER = (CIN > 0);
    constexpr int AREP = BM * 4 / 256;
    constexpr int BREP = BN * 4 / 256;
    __shared__ __align__(16) short As[4][BM][8];
    __shared__ __align__(16) short Bs[4][BN][8];
    const int tid = threadIdx.x;
    const int bn = blockIdx.x * BN, bm = blockIdx.y * BM;
    const int lane = tid & 63, wid = tid >> 6;
    const int wm = wid >> 1, wn = wid & 1;

    int pb_[AREP], py_[AREP], px_[AREP];
    if (GATHER) {
        #pragma unroll
        for (int rep = 0; rep < AREP; ++rep) {
            int idx = rep * 256 + tid;
            int m = idx >> 2;
            int pix = bm + m;
            px_[rep] = pix % Wd;
            int r = pix / Wd;
            py_[rep] = r % H;
            pb_[rep] = r / H;
        }
    }

    f32x4 acc[MF][NF];
    #pragma unroll
    for (int i = 0; i < MF; ++i)
        #pragma unroll
        for (int j = 0; j < NF; ++j)
            acc[i][j] = (f32x4){0.f, 0.f, 0.f, 0.f};

    for (int k0 = 0; k0 < K; k0 += 32) {
        #pragma unroll
        for (int rep = 0; rep < AREP; ++rep) {
            int idx = rep * 256 + tid;
            int m = idx >> 2, kg = idx & 3;
            if (!GATHER) {
                *(bf16x8*)As[kg][m] =
                    *(const bf16x8*)(Abf + (size_t)(bm + m) * K + k0 + kg * 8);
            } else {
                int k = k0 + kg * 8;
                int tap = k / CIN;
                int ic = k - tap * CIN;
                int dy = tap / 3 - 1, dx = tap % 3 - 1;
                int yy = py_[rep] + dy, xx = px_[rep] + dx;
                bf16x8 v = (bf16x8){0, 0, 0, 0, 0, 0, 0, 0};
                if ((unsigned)yy < (unsigned)H && (unsigned)xx < (unsigned)Wd)
                    v = *(const bf16x8*)(Abf +
                        ((size_t)((pb_[rep] * H + yy) * Wd + xx)) * CIN + ic);
                *(bf16x8*)As[kg][m] = v;
            }
        }
        #pragma unroll
        for (int rep = 0; rep < BREP; ++rep) {
            int idx = rep * 256 + tid;
            int n = idx >> 2, kg = idx & 3;
            *(bf16x8*)Bs[kg][n] =
                *(const bf16x8*)(Wt + (size_t)(bn + n) * K + k0 + kg * 8);
        }
        __syncthreads();
        bf16x8 af[MF], bfv[NF];
        #pragma unroll
        for (int i = 0; i < MF; ++i)
            af[i] = *(const bf16x8*)As[lane >> 4][wm * (BM / 2) + i * 16 + (lane & 15)];
        #pragma unroll
        for (int j = 0; j < NF; ++j)
            bfv[j] = *(const bf16x8*)Bs[lane >> 4][wn * (BN / 2) + j * 16 + (lane & 15)];
        #pragma unroll
        for (int i = 0; i < MF; ++i)
            #pragma unroll
            for (int j = 0; j < NF; ++j)
                acc[i][j] = __builtin_amdgcn_mfma_f32_16x16x32_bf16(
                    af[i], bfv[j], acc[i][j], 0, 0, 0);
        __syncthreads();
    }

    #pragma unroll
    for (int i = 0; i < MF; ++i) {
        const int row0 = bm + wm * (BM / 2) + i * 16 + (lane >> 4) * 4;
        #pragma unroll
        for (int j = 0; j < NF; ++j) {
            const int col = bn + wn * (BN / 2) + j * 16 + (lane & 15);
            #pragma unroll
            for (int r = 0; r < 4; ++r) {
                const int rr = row0 + r;
                float v = acc[i][j][r];
                if (EPI >= 1) v += bias[col];
                if (EPI == 1) v += outf[(size_t)rr * Nn + col];
                if (EPI == 2) v = 0.5f * v * (1.0f + erff(v * 0.70710678118f));
                if (EPI == 3) v += extra[(size_t)(rr % NTOK) * Nn + col];
                if (EPI == 4) v = fmaxf(v, 0.f);
                if (EPI == 2 || EPI == 4)
                    outb[(size_t)rr * Nn + col] = f2bf(v);
                else
                    outf[(size_t)rr * Nn + col] = v;
            }
        }
    }
}

// ---------------- LayerNorm over last dim (256), bf16 out -------------------
__global__ __launch_bounds__(256) void k_ln(const float* __restrict__ x,
                                            const float* __restrict__ g,
                                            const float* __restrict__ bb,
                                            unsigned short* __restrict__ y) {
    const int row = blockIdx.x, tid = threadIdx.x;
    float v = x[(size_t)row * DMODEL + tid];
    float s = v;
    #pragma unroll
    for (int off = 32; off; off >>= 1) s += __shfl_xor(s, off);
    __shared__ float ls[4], ls2[4];
    if ((tid & 63) == 0) ls[tid >> 6] = s;
    __syncthreads();
    float mu = (ls[0] + ls[1] + ls[2] + ls[3]) * (1.0f / DMODEL);
    float d = v - mu;
    float qq = d * d;
    #pragma unroll
    for (int off = 32; off; off >>= 1) qq += __shfl_xor(qq, off);
    if ((tid & 63) == 0) ls2[tid >> 6] = qq;
    __syncthreads();
    float var = (ls2[0] + ls2[1] + ls2[2] + ls2[3]) * (1.0f / DMODEL);
    y[(size_t)row * DMODEL + tid] = f2bf(d * rsqrtf(var + 1e-5f) * g[tid] + bb[tid]);
}

// ---------------- fused hybrid attention, 16 rows/block (fp32 math) ---------
__global__ __launch_bounds__(256) void k_attn(const float* __restrict__ qkv,
                                              const float* __restrict__ alpha_l,
                                              unsigned short* __restrict__ ao) {
    __shared__ float qs[RPB][KPAD];
    __shared__ float sc[RPB][SPAD];
    __shared__ float kv[CHUNK * VPAD];

    const int tid = threadIdx.x;
    const int h = blockIdx.y, b = blockIdx.z;
    const int i0 = blockIdx.x * RPB;

    {
        int r = tid >> 6, d = tid & 63;
        #pragma unroll
        for (int rep = 0; rep < 4; ++rep)
            qs[rep * 4 + r][d] =
                qkv[((size_t)(b * NTOK + i0 + rep * 4 + r)) * DQKV + h * DHEAD + d];
    }

    const int rp = tid >> 5;
    const int jp = tid & 31;
    for (int c = 0; c < NCHUNK; ++c) {
        __syncthreads();
        #pragma unroll
        for (int rep = 0; rep < 4; ++rep) {
            int idx = rep * 256 + tid;
            int jj = idx >> 4, dq = idx & 15;
            const float4 v = *reinterpret_cast<const float4*>(
                &qkv[((size_t)(b * NTOK + c * CHUNK + jj)) * DQKV + DMODEL + h * DHEAD + dq * 4]);
            float* p = &kv[jj * KPAD + dq * 4];
            p[0] = v.x; p[1] = v.y; p[2] = v.z; p[3] = v.w;
        }
        __syncthreads();
        float a00 = 0.f, a01 = 0.f, a10 = 0.f, a11 = 0.f;
        const float* q0 = qs[2 * rp];
        const float* q1 = qs[2 * rp + 1];
        const float* k0 = &kv[(2 * jp) * KPAD];
        const float* k1 = &kv[(2 * jp + 1) * KPAD];
        #pragma unroll
        for (int d = 0; d < DHEAD; ++d) {
            float x0 = q0[d], x1 = q1[d], y0 = k0[d], y1 = k1[d];
            a00 += x0 * y0; a01 += x0 * y1;
            a10 += x1 * y0; a11 += x1 * y1;
        }
        const int j0 = c * CHUNK + 2 * jp;
        sc[2 * rp][j0]     = a00 * 0.125f;
        sc[2 * rp][j0 + 1] = a01 * 0.125f;
        sc[2 * rp + 1][j0]     = a10 * 0.125f;
        sc[2 * rp + 1][j0 + 1] = a11 * 0.125f;
    }
    __syncthreads();

    const int wv = tid >> 6, lane = tid & 63;
    float alpha = alpha_l[0];
    alpha = fminf(fmaxf(alpha, 0.f), 1.f);
    for (int rr = 0; rr < 4; ++rr) {
        const int row = wv * 4 + rr;
        float o[9], vv[9];
        #pragma unroll
        for (int t = 0; t < 9; ++t) { o[t] = sc[row][t * 64 + lane]; vv[t] = o[t]; }
        unsigned mask = 0; float M = 0.f;
        for (int k = 0; k < TOPK; ++k) {
            float bv = vv[0]; int bt = 0;
            #pragma unroll
            for (int t = 1; t < 9; ++t)
                if (vv[t] > bv) { bv = vv[t]; bt = t; }
            int bj = bt * 64 + lane;
            #pragma unroll
            for (int off = 1; off < 64; off <<= 1) {
                float ov = __shfl_xor(bv, off);
                int   oj = __shfl_xor(bj, off);
                if (ov > bv || (ov == bv && oj < bj)) { bv = ov; bj = oj; }
            }
            if (k == 0) M = bv;
            if ((bj & 63) == lane) { vv[bj >> 6] = -FLT_MAX; mask |= 1u << (bj >> 6); }
        }
        float e[9], gsl = 0.f, ssl = 0.f;
        #pragma unroll
        for (int t = 0; t < 9; ++t) {
            e[t] = expf(o[t] - M);
            gsl += e[t];
            if ((mask >> t) & 1u) ssl += e[t];
        }
        #pragma unroll
        for (int off = 1; off < 64; off <<= 1) {
            gsl += __shfl_xor(gsl, off);
            ssl += __shfl_xor(ssl, off);
        }
        const float ca = alpha / gsl, cs = (1.f - alpha) / ssl;
        #pragma unroll
        for (int t = 0; t < 9; ++t)
            sc[row][t * 64 + lane] = e[t] * (ca + (((mask >> t) & 1u) ? cs : 0.f));
    }

    const int rp2 = tid >> 5;
    const int jq  = (tid >> 3) & 3;
    const int dg  = tid & 7;
    float4 acc0a = {0,0,0,0}, acc0b = {0,0,0,0};
    float4 acc1a = {0,0,0,0}, acc1b = {0,0,0,0};
    for (int c = 0; c < NCHUNK; ++c) {
        __syncthreads();
        #pragma unroll
        for (int rep = 0; rep < 4; ++rep) {
            int idx = rep * 256 + tid;
            int jj = idx >> 4, dq = idx & 15;
            const float4 v = *reinterpret_cast<const float4*>(
                &qkv[((size_t)(b * NTOK + c * CHUNK + jj)) * DQKV + 2 * DMODEL + h * DHEAD + dq * 4]);
            *reinterpret_cast<float4*>(&kv[jj * VPAD + dq * 4]) = v;
        }
        __syncthreads();
        const int r0 = 2 * rp2, r1 = r0 + 1;
        #pragma unroll
        for (int t = 0; t < 16; ++t) {
            const int jj = jq + 4 * t;
            const float w0 = sc[r0][c * CHUNK + jj];
            const float w1 = sc[r1][c * CHUNK + jj];
            const float4 va = *reinterpret_cast<const float4*>(&kv[jj * VPAD + dg * 8]);
            const float4 vb = *reinterpret_cast<const float4*>(&kv[jj * VPAD + dg * 8 + 4]);
            acc0a.x += w0 * va.x; acc0a.y += w0 * va.y; acc0a.z += w0 * va.z; acc0a.w += w0 * va.w;
            acc0b.x += w0 * vb.x; acc0b.y += w0 * vb.y; acc0b.z += w0 * vb.z; acc0b.w += w0 * vb.w;
            acc1a.x += w1 * va.x; acc1a.y += w1 * va.y; acc1a.z += w1 * va.z; acc1a.w += w1 * va.w;
            acc1b.x += w1 * vb.x; acc1b.y += w1 * vb.y; acc1b.z += w1 * vb.z; acc1b.w += w1 * vb.w;
        }
    }
    #pragma unroll
    for (int off = 8; off <= 16; off <<= 1) {
        acc0a.x += __shfl_xor(acc0a.x, off); acc0a.y += __shfl_xor(acc0a.y, off);
        acc0a.z += __shfl_xor(acc0a.z, off); acc0a.w += __shfl_xor(acc0a.w, off);
        acc0b.x += __shfl_xor(acc0b.x, off); acc0b.y += __shfl_xor(acc0b.y, off);
        acc0b.z += __shfl_xor(acc0b.z, off); acc0b.w += __shfl_xor(acc0b.w, off);
        acc1a.x += __shfl_xor(acc1a.x, off); acc1a.y += __shfl_xor(acc1a.y, off);
        acc1a.z += __shfl_xor(acc1a.z, off); acc1a.w += __shfl_xor(acc1a.w, off);
        acc1b.x += __shfl_xor(acc1b.x, off); acc1b.y += __shfl_xor(acc1b.y, off);
        acc1b.z += __shfl_xor(acc1b.z, off); acc1b.w += __shfl_xor(acc1b.w, off);
    }
    if (jq == 0) {
        const int r0 = 2 * rp2, r1 = r0 + 1;
        bf16x8 o0, o1;
        o0[0] = f2bf(acc0a.x); o0[1] = f2bf(acc0a.y); o0[2] = f2bf(acc0a.z); o0[3] = f2bf(acc0a.w);
        o0[4] = f2bf(acc0b.x); o0[5] = f2bf(acc0b.y); o0[6] = f2bf(acc0b.z); o0[7] = f2bf(acc0b.w);
        o1[0] = f2bf(acc1a.x); o1[1] = f2bf(acc1a.y); o1[2] = f2bf(acc1a.z); o1[3] = f2bf(acc1a.w);
        o1[4] = f2bf(acc1b.x); o1[5] = f2bf(acc1b.y); o1[6] = f2bf(acc1b.z); o1[7] = f2bf(acc1b.w);
        *(bf16x8*)(ao + ((size_t)(b * NTOK + i0 + r0)) * DMODEL + h * DHEAD + dg * 8) = o0;
        *(bf16x8*)(ao + ((size_t)(b * NTOK + i0 + r1)) * DMODEL + h * DHEAD + dg * 8) = o1;
    }
}

// ---------------- bilinear helpers (jax.image.resize half-pixel) ------------
__device__ __forceinline__ void bilin_axis(float sF, int H, int& i0, int& i1, float& f) {
    float fl = floorf(sF);
    f = sF - fl;
    int lo = (int)fl;
    i0 = lo < 0 ? 0 : (lo > H - 1 ? H - 1 : lo);
    int hi = lo + 1;
    i1 = hi < 0 ? 0 : (hi > H - 1 ? H - 1 : hi);
}

// NHWC bf16 2x bilinear upsample
__global__ __launch_bounds__(256) void k_up2n(const unsigned short* __restrict__ in,
                                              unsigned short* __restrict__ outp,
                                              int Hin, int C) {
    const int Ho = 2 * Hin;
    const int CG = C / 8;
    const int total = NB * Ho * Ho * CG;
    int t = blockIdx.x * 256 + threadIdx.x;
    if (t >= total) return;
    int cg = t % CG; int r = t / CG;
    int x = r % Ho; r /= Ho;
    int y = r % Ho; int b = r / Ho;
    int i0, i1, j0, j1; float fy, fx;
    bilin_axis(0.5f * y - 0.25f, Hin, i0, i1, fy);
    bilin_axis(0.5f * x - 0.25f, Hin, j0, j1, fx);
    const unsigned short* base = in + (size_t)b * Hin * Hin * C + cg * 8;
    const bf16x8 p00 = *(const bf16x8*)(base + (size_t)(i0 * Hin + j0) * C);
    const bf16x8 p01 = *(const bf16x8*)(base + (size_t)(i0 * Hin + j1) * C);
    const bf16x8 p10 = *(const bf16x8*)(base + (size_t)(i1 * Hin + j0) * C);
    const bf16x8 p11 = *(const bf16x8*)(base + (size_t)(i1 * Hin + j1) * C);
    bf16x8 o;
    #pragma unroll
    for (int e = 0; e < 8; ++e) {
        float v = (1.f - fy) * ((1.f - fx) * bf2f((unsigned short)p00[e]) + fx * bf2f((unsigned short)p01[e]))
                + fy        * ((1.f - fx) * bf2f((unsigned short)p10[e]) + fx * bf2f((unsigned short)p11[e]));
        o[e] = (short)f2bf(v);
    }
    *(bf16x8*)(outp + (size_t)t * 8) = o;
}

// ---------------- conv3: 1x1, 64->21, NHWC bf16 in -> NCHW f32 out ----------
__global__ __launch_bounds__(256) void k_conv3n(const unsigned short* __restrict__ in,
                                                const float* __restrict__ w,
                                                const float* __restrict__ bias,
                                                float* __restrict__ outp) {
    __shared__ float ws_[NCLS * 64];
    for (int i = threadIdx.x; i < NCLS * 64; i += 256) ws_[i] = w[i];
    __syncthreads();
    int t = blockIdx.x * 256 + threadIdx.x;
    if (t >= NB * 9216) return;
    int pix = t % 9216, b = t / 9216;
    float xv[64];
    const unsigned short* p = in + (size_t)t * 64;
    #pragma unroll
    for (int c = 0; c < 8; ++c) {
        bf16x8 v = *(const bf16x8*)(p + c * 8);
        #pragma unroll
        for (int e = 0; e < 8; ++e) xv[c * 8 + e] = bf2f((unsigned short)v[e]);
    }
    float* op = outp + (size_t)b * NCLS * 9216 + pix;
    #pragma unroll
    for (int o = 0; o < NCLS; ++o) {
        float acc = bias[o];
        #pragma unroll
        for (int ic = 0; ic < 64; ++ic) acc += ws_[o * 64 + ic] * xv[ic];
        op[(size_t)o * 9216] = acc;
    }
}

// ---------------- final resize 96 -> 384 (4x bilinear), f32 NCHW ------------
__global__ __launch_bounds__(256) void k_resize4(const float* __restrict__ in,
                                                 float* __restrict__ outp) {
    int t = blockIdx.x * 256 + threadIdx.x;
    if (t >= OUT_TOTAL) return;
    int x = t % IMGSZ; int r = t / IMGSZ; int y = r % IMGSZ; int bc = r / IMGSZ;
    int i0, i1, j0, j1; float fy, fx;
    bilin_axis(0.25f * y - 0.375f, 96, i0, i1, fy);
    bilin_axis(0.25f * x - 0.375f, 96, j0, j1, fx);
    const float* p = in + (size_t)bc * 9216;
    outp[t] = (1.f - fy) * ((1.f - fx) * p[i0 * 96 + j0] + fx * p[i0 * 96 + j1])
            + fy        * ((1.f - fx) * p[i1 * 96 + j0] + fx * p[i1 * 96 + j1]);
}

// ---------------- orchestration ----------------
extern "C" void kernel_launch(void* const* d_in, const int* in_sizes, int n_in,
                              void* d_out, int out_size, void* d_ws, size_t ws_size,
                              hipStream_t stream) {
    const float* img     = (const float*)d_in[0];
    const float* patch_w = (const float*)d_in[1];
    const float* patch_b = (const float*)d_in[2];
    const float* pos_emb = (const float*)d_in[3];
    const float* ln1_g   = (const float*)d_in[4];
    const float* ln1_b   = (const float*)d_in[5];
    const float* qkv_w   = (const float*)d_in[6];
    const float* out_w   = (const float*)d_in[7];
    const float* out_b   = (const float*)d_in[8];
    const float* alpha   = (const float*)d_in[9];
    const float* ln2_g   = (const float*)d_in[10];
    const float* ln2_b   = (const float*)d_in[11];
    const float* ff_w1   = (const float*)d_in[12];
    const float* ff_b1   = (const float*)d_in[13];
    const float* ff_w2   = (const float*)d_in[14];
    const float* ff_b2   = (const float*)d_in[15];
    const float* lnf_g   = (const float*)d_in[16];
    const float* lnf_b   = (const float*)d_in[17];
    const float* conv1_w = (const float*)d_in[18];
    const float* conv1_b = (const float*)d_in[19];
    const float* conv2_w = (const float*)d_in[20];
    const float* conv2_b = (const float*)d_in[21];
    const float* conv3_w = (const float*)d_in[22];
    const float* conv3_b = (const float*)d_in[23];

    // ---- workspace layout (~78.2 MB) ----
    float* x    = (float*)d_ws;                                  // [9216][256] f32
    float* qkvb = x + (size_t)NROWS * DMODEL;                    // [9216][768] f32
    unsigned short* xn_bf = (unsigned short*)(qkvb + (size_t)NROWS * DQKV); // [9216][256]
    unsigned short* ao_bf = xn_bf + (size_t)NROWS * DMODEL;      // [9216][256]
    unsigned short* h_bf  = ao_bf + (size_t)NROWS * DMODEL;      // [9216][512]
    unsigned short* pA    = h_bf + (size_t)NROWS * DMLP;         // [9216][768]
    unsigned short* wts   = pA + (size_t)NROWS * NPD;
    unsigned short* pwt  = wts;                       // [256][768]
    unsigned short* qwt  = pwt  + 768 * 256;          // [6][768][256]
    unsigned short* owt  = qwt  + 6 * 768 * 256;      // [6][256][256]
    unsigned short* f1wt = owt  + 6 * 256 * 256;      // [6][512][256]
    unsigned short* f2wt = f1wt + 6 * 256 * 512;      // [6][256][512]
    unsigned short* c1wt = f2wt + 6 * 512 * 256;      // [128][9*256]
    unsigned short* c2wt = c1wt + 128 * 9 * 256;      // [64][9*128]
    // conv-stage aliases (transformer buffers free by then)
    unsigned short* c1n = ao_bf;            // [16][24][24][128]
    unsigned short* u1n = h_bf;             // [16][48][48][128]
    unsigned short* c2n = xn_bf;            // [16][48][48][64]
    unsigned short* u2n = (unsigned short*)qkvb; // [16][96][96][64]
    float* c3 = (float*)pA;                 // [16][21][96][96] f32

    // ---- weight casts ----
    k_castT<<<dim3(768, 1), 256, 0, stream>>>(patch_w, pwt, NPD, DMODEL);
    k_castT<<<dim3(768, 6), 256, 0, stream>>>(qkv_w, qwt, DMODEL, DQKV);
    k_castT<<<dim3(256, 6), 256, 0, stream>>>(out_w, owt, DMODEL, DMODEL);
    k_castT<<<dim3(512, 6), 256, 0, stream>>>(ff_w1, f1wt, DMODEL, DMLP);
    k_castT<<<dim3(512, 6), 256, 0, stream>>>(ff_w2, f2wt, DMLP, DMODEL);
    k_castConv<256><<<1152, 256, 0, stream>>>(conv1_w, c1wt, 128);
    k_castConv<128><<<288, 256, 0, stream>>>(conv2_w, c2wt, 64);

    // ---- patch embed ----
    k_patchify<<<(NROWS * NPD + 255) / 256, 256, 0, stream>>>(img, pA);
    k_mm<128, 64, 3, 0><<<dim3(4, 72), 256, 0, stream>>>(
        pA, pwt, patch_b, pos_emb, x, nullptr, NROWS, DMODEL, NPD, 0, 0);

    // ---- transformer layers ----
    for (int l = 0; l < DEPTH; ++l) {
        k_ln<<<NROWS, 256, 0, stream>>>(x, ln1_g + l * DMODEL, ln1_b + l * DMODEL, xn_bf);
        k_mm<128, 128, 0, 0><<<dim3(6, 72), 256, 0, stream>>>(
            xn_bf, qwt + (size_t)l * DQKV * DMODEL, nullptr, nullptr,
            qkvb, nullptr, NROWS, DQKV, DMODEL, 0, 0);
        k_attn<<<dim3(NTOK / RPB, NHEAD, NB), 256, 0, stream>>>(qkvb, alpha + l, ao_bf);
        k_mm<128, 64, 1, 0><<<dim3(4, 72), 256, 0, stream>>>(
            ao_bf, owt + (size_t)l * DMODEL * DMODEL, out_b + l * DMODEL, nullptr,
            x, nullptr, NROWS, DMODEL, DMODEL, 0, 0);
        k_ln<<<NROWS, 256, 0, stream>>>(x, ln2_g + l * DMODEL, ln2_b + l * DMODEL, xn_bf);
        k_mm<128, 128, 2, 0><<<dim3(4, 72), 256, 0, stream>>>(
            xn_bf, f1wt + (size_t)l * DMLP * DMODEL, ff_b1 + l * DMLP, nullptr,
            nullptr, h_bf, NROWS, DMLP, DMODEL, 0, 0);
        k_mm<128, 64, 1, 0><<<dim3(4, 72), 256, 0, stream>>>(
            h_bf, f2wt + (size_t)l * DMODEL * DMLP, ff_b2 + l * DMODEL, nullptr,
            x, nullptr, NROWS, DMODEL, DMLP, 0, 0);
    }

    // ---- head ----
    k_ln<<<NROWS, 256, 0, stream>>>(x, lnf_g, lnf_b, xn_bf);
    // conv1: implicit GEMM over NHWC tokens [16][24][24][256]
    k_mm<64, 128, 4, 256><<<dim3(1, 144), 256, 0, stream>>>(
        xn_bf, c1wt, conv1_b, nullptr, nullptr, c1n, NROWS, 128, 9 * 256, 24, 24);
    k_up2n<<<(NB * 48 * 48 * 16 + 255) / 256, 256, 0, stream>>>(c1n, u1n, 24, 128);
    // conv2: implicit GEMM over NHWC [16][48][48][128]
    k_mm<128, 64, 4, 128><<<dim3(1, 288), 256, 0, stream>>>(
        u1n, c2wt, conv2_b, nullptr, nullptr, c2n, NB * 48 * 48, 64, 9 * 128, 48, 48);
    k_up2n<<<(NB * 96 * 96 * 8 + 255) / 256, 256, 0, stream>>>(c2n, u2n, 48, 64);
    k_conv3n<<<(NB * 9216 + 255) / 256, 256, 0, stream>>>(u2n, conv3_w, conv3_b, c3);
    k_resize4<<<(OUT_TOTAL + 255) / 256, 256, 0, stream>>>(c3, (float*)d_out);
}

// Round 4
// 2899.792 us; speedup vs baseline: 4.2251x; 1.1985x over previous
//
#include <hip/hip_runtime.h>
#include <cfloat>
#include <cmath>

// ---------------- problem constants ----------------
constexpr int NB    = 16;    // batch
constexpr int IMGSZ = 384;
constexpr int PSZ   = 16;
constexpr int NCH   = 3;
constexpr int DMODEL= 256;
constexpr int DEPTH = 6;
constexpr int NHEAD = 4;
constexpr int DHEAD = 64;
constexpr int DQKV  = 768;   // 3*INNER
constexpr int DMLP  = 512;
constexpr int NCLS  = 21;
constexpr int HPATCH= 24;    // IMG/P
constexpr int NTOK  = 576;   // HP*HP
constexpr int NPD   = 768;   // C*P*P
constexpr int TOPK  = 16;
constexpr int NROWS = NB * NTOK;          // 9216
constexpr int OUT_TOTAL = NB * NCLS * IMGSZ * IMGSZ; // 49545216

// attention tiling
constexpr int RPB    = 32;           // query rows per block
constexpr int CHUNK  = 64;           // key/value chunk
constexpr int NCHUNK = NTOK / CHUNK; // 9
constexpr int SCP    = 577;          // score row stride (f32)
constexpr int PP     = 584;          // P row stride (bf16)

typedef __attribute__((ext_vector_type(8))) short bf16x8;
typedef __attribute__((ext_vector_type(4))) float f32x4;

__device__ __forceinline__ unsigned short f2bf(float f) {
    unsigned u = __builtin_bit_cast(unsigned, f);
    unsigned r = (u + 0x7FFFu + ((u >> 16) & 1u)) >> 16;
    return (unsigned short)r;
}
__device__ __forceinline__ float bf2f(unsigned short h) {
    unsigned u = ((unsigned)h) << 16;
    return __builtin_bit_cast(float, u);
}

// ---------------- weight cast+transpose: W[L][K][N] f32 -> Wt[L][N][K] bf16 --
__global__ __launch_bounds__(256) void k_castT(const float* __restrict__ src,
                                               unsigned short* __restrict__ dst,
                                               int K, int N) {
    int t = blockIdx.x * 256 + threadIdx.x;
    if (t >= K * N) return;
    size_t base = (size_t)blockIdx.y * K * N;
    int n = t / K, k = t - n * K;
    dst[base + t] = f2bf(src[base + (size_t)k * N + n]);
}

// conv w [OC][IC][3][3] f32 -> [OC][9][IC] bf16 (tap-major K)
template <int IC>
__global__ __launch_bounds__(256) void k_castConv(const float* __restrict__ src,
                                                  unsigned short* __restrict__ dst,
                                                  int OC) {
    int t = blockIdx.x * 256 + threadIdx.x;
    if (t >= OC * 9 * IC) return;
    int oc = t / (9 * IC);
    int r = t - oc * 9 * IC;
    int tap = r / IC, ic = r - tap * IC;
    dst[t] = f2bf(src[((size_t)(oc * IC + ic)) * 9 + tap]);
}

// ---------------- patchify: img[B,3,384,384] -> A[9216,768] bf16 ------------
__global__ __launch_bounds__(256) void k_patchify(const float* __restrict__ img,
                                                  unsigned short* __restrict__ A) {
    int t = blockIdx.x * 256 + threadIdx.x;
    if (t >= NROWS * NPD) return;
    int r  = t / NPD, pd = t - r * NPD;
    int b  = r / NTOK, n = r - b * NTOK;
    int hy = n / HPATCH, hx = n - hy * HPATCH;
    int c  = pd % NCH;  int q = pd / NCH;
    int p2 = q % PSZ;   int p1 = q / PSZ;
    A[t] = f2bf(img[(((size_t)(b * NCH + c)) * IMGSZ + hy * PSZ + p1) * IMGSZ + hx * PSZ + p2]);
}

// ---------------- unified bf16 MFMA GEMM / implicit conv --------------------
// out[M,N] = A[M,K](bf16) @ Wt[N,K]^T(bf16), fp32 accumulate.
// EPI: 0 none->f32 | 1 bias+residual->f32 | 2 bias+gelu->bf16
//      3 bias+posemb->f32 | 4 bias+relu->bf16 | 5 none->bf16 hi/lo pair
// CIN>0: gather A from NHWC [NB][H][W][CIN] with 3x3 taps (K = 9*CIN, tap-major)
template <int BM, int BN, int EPI, int CIN>
__global__ __launch_bounds__(256) void k_mm(
    const unsigned short* __restrict__ Abf,
    const unsigned short* __restrict__ Wt,
    const float* __restrict__ bias,
    const float* __restrict__ extra,
    float* __restrict__ outf,
    unsigned short* __restrict__ outb,
    unsigned short* __restrict__ outb2,
    int M, int Nn, int K, int H, int Wd)
{
    constexpr int MF = BM / 32;
    constexpr int NF = BN / 32;
    constexpr bool GATHER = (CIN > 0);
    constexpr int AREP = BM * 4 / 256;
    constexpr int BREP = BN * 4 / 256;
    __shared__ __align__(16) short As[4][BM][8];
    __shared__ __align__(16) short Bs[4][BN][8];
    const int tid = threadIdx.x;
    const int bn = blockIdx.x * BN, bm = blockIdx.y * BM;
    const int lane = tid & 63, wid = tid >> 6;
    const int wm = wid >> 1, wn = wid & 1;

    int pb_[AREP], py_[AREP], px_[AREP];
    if (GATHER) {
        #pragma unroll
        for (int rep = 0; rep < AREP; ++rep) {
            int idx = rep * 256 + tid;
            int m = idx >> 2;
            int pix = bm + m;
            px_[rep] = pix % Wd;
            int r = pix / Wd;
            py_[rep] = r % H;
            pb_[rep] = r / H;
        }
    }

    f32x4 acc[MF][NF];
    #pragma unroll
    for (int i = 0; i < MF; ++i)
        #pragma unroll
        for (int j = 0; j < NF; ++j)
            acc[i][j] = (f32x4){0.f, 0.f, 0.f, 0.f};

    for (int k0 = 0; k0 < K; k0 += 32) {
        #pragma unroll
        for (int rep = 0; rep < AREP; ++rep) {
            int idx = rep * 256 + tid;
            int m = idx >> 2, kg = idx & 3;
            if (!GATHER) {
                *(bf16x8*)As[kg][m] =
                    *(const bf16x8*)(Abf + (size_t)(bm + m) * K + k0 + kg * 8);
            } else {
                int k = k0 + kg * 8;
                int tap = k / CIN;
                int ic = k - tap * CIN;
                int dy = tap / 3 - 1, dx = tap % 3 - 1;
                int yy = py_[rep] + dy, xx = px_[rep] + dx;
                bf16x8 v = (bf16x8){0, 0, 0, 0, 0, 0, 0, 0};
                if ((unsigned)yy < (unsigned)H && (unsigned)xx < (unsigned)Wd)
                    v = *(const bf16x8*)(Abf +
                        ((size_t)((pb_[rep] * H + yy) * Wd + xx)) * CIN + ic);
                *(bf16x8*)As[kg][m] = v;
            }
        }
        #pragma unroll
        for (int rep = 0; rep < BREP; ++rep) {
            int idx = rep * 256 + tid;
            int n = idx >> 2, kg = idx & 3;
            *(bf16x8*)Bs[kg][n] =
                *(const bf16x8*)(Wt + (size_t)(bn + n) * K + k0 + kg * 8);
        }
        __syncthreads();
        bf16x8 af[MF], bfv[NF];
        #pragma unroll
        for (int i = 0; i < MF; ++i)
            af[i] = *(const bf16x8*)As[lane >> 4][wm * (BM / 2) + i * 16 + (lane & 15)];
        #pragma unroll
        for (int j = 0; j < NF; ++j)
            bfv[j] = *(const bf16x8*)Bs[lane >> 4][wn * (BN / 2) + j * 16 + (lane & 15)];
        #pragma unroll
        for (int i = 0; i < MF; ++i)
            #pragma unroll
            for (int j = 0; j < NF; ++j)
                acc[i][j] = __builtin_amdgcn_mfma_f32_16x16x32_bf16(
                    af[i], bfv[j], acc[i][j], 0, 0, 0);
        __syncthreads();
    }

    #pragma unroll
    for (int i = 0; i < MF; ++i) {
        const int row0 = bm + wm * (BM / 2) + i * 16 + (lane >> 4) * 4;
        #pragma unroll
        for (int j = 0; j < NF; ++j) {
            const int col = bn + wn * (BN / 2) + j * 16 + (lane & 15);
            #pragma unroll
            for (int r = 0; r < 4; ++r) {
                const int rr = row0 + r;
                float v = acc[i][j][r];
                if (EPI >= 1 && EPI <= 4) v += bias[col];
                if (EPI == 1) v += outf[(size_t)rr * Nn + col];
                if (EPI == 2) v = 0.5f * v * (1.0f + erff(v * 0.70710678118f));
                if (EPI == 3) v += extra[(size_t)(rr % NTOK) * Nn + col];
                if (EPI == 4) v = fmaxf(v, 0.f);
                if (EPI == 2 || EPI == 4) {
                    outb[(size_t)rr * Nn + col] = f2bf(v);
                } else if (EPI == 5) {
                    unsigned short hi = f2bf(v);
                    outb[(size_t)rr * Nn + col] = hi;
                    outb2[(size_t)rr * Nn + col] = f2bf(v - bf2f(hi));
                } else {
                    outf[(size_t)rr * Nn + col] = v;
                }
            }
        }
    }
}

// ---------------- LayerNorm over last dim (256), bf16 out -------------------
__global__ __launch_bounds__(256) void k_ln(const float* __restrict__ x,
                                            const float* __restrict__ g,
                                            const float* __restrict__ bb,
                                            unsigned short* __restrict__ y) {
    const int row = blockIdx.x, tid = threadIdx.x;
    float v = x[(size_t)row * DMODEL + tid];
    float s = v;
    #pragma unroll
    for (int off = 32; off; off >>= 1) s += __shfl_xor(s, off);
    __shared__ float ls[4], ls2[4];
    if ((tid & 63) == 0) ls[tid >> 6] = s;
    __syncthreads();
    float mu = (ls[0] + ls[1] + ls[2] + ls[3]) * (1.0f / DMODEL);
    float d = v - mu;
    float qq = d * d;
    #pragma unroll
    for (int off = 32; off; off >>= 1) qq += __shfl_xor(qq, off);
    if ((tid & 63) == 0) ls2[tid >> 6] = qq;
    __syncthreads();
    float var = (ls2[0] + ls2[1] + ls2[2] + ls2[3]) * (1.0f / DMODEL);
    y[(size_t)row * DMODEL + tid] = f2bf(d * rsqrtf(var + 1e-5f) * g[tid] + bb[tid]);
}

// ---------------- MFMA hybrid attention, 32 rows/block, 512 threads ---------
// Scores: 3-pass split-bf16 MFMA (Qh*Kh + Qh*Kl + Ql*Kh) == fp32 to ~1e-5.
// Top-16: exact register/butterfly argmax (lax.top_k tie semantics).
// PV: 3-pass split-bf16 MFMA with P split post-softmax, V transposed in LDS.
__global__ __launch_bounds__(512, 1) void k_attn(
    const unsigned short* __restrict__ qhi,
    const unsigned short* __restrict__ qlo,
    const float* __restrict__ alpha_l,
    unsigned short* __restrict__ ao) {
    __shared__ __align__(16) short qsb[2][RPB][72];      // Q hi/lo
    __shared__ __align__(16) short kvb[2][CHUNK][72];    // K (then V^T) hi/lo
    __shared__ __align__(16) unsigned char ub[74752];    // sc f32 [32][577] | P hi/lo [2][32][584]

    float* scp = (float*)ub;
    short* php = (short*)ub;            // hi at [0, 32*584), lo at [32*584, 2*32*584)

    const int tid = threadIdx.x;
    const int lane = tid & 63, w = tid >> 6;
    const int rt = w >> 2, ct = w & 3;
    const int h = blockIdx.y, b = blockIdx.z;
    const int i0 = blockIdx.x * RPB;

    // ---- stage Q hi/lo: 2*32*8 bf16x8 loads over 512 threads ----
    {
        int hl = tid >> 8, rem = tid & 255;
        int rr = rem >> 3, dg = rem & 7;
        const unsigned short* src = (hl ? qlo : qhi) +
            (size_t)(b * NTOK + i0 + rr) * DQKV + h * DHEAD + dg * 8;
        *(bf16x8*)&qsb[hl][rr][dg * 8] = *(const bf16x8*)src;
    }

    // ---- score phase: per chunk, stage K then MFMA into scp ----
    for (int c = 0; c < NCHUNK; ++c) {
        __syncthreads();   // prev chunk frag reads done (c=0: Q stage + nothing)
        #pragma unroll
        for (int rep = 0; rep < 2; ++rep) {
            int idx = rep * 512 + tid;
            int hl = idx >> 9, rem = idx & 511;
            int jj = rem >> 3, dg = rem & 7;
            const unsigned short* src = (hl ? qlo : qhi) +
                (size_t)(b * NTOK + c * CHUNK + jj) * DQKV + DMODEL + h * DHEAD + dg * 8;
            *(bf16x8*)&kvb[hl][jj][dg * 8] = *(const bf16x8*)src;
        }
        __syncthreads();
        f32x4 sD = (f32x4){0.f, 0.f, 0.f, 0.f};
        #pragma unroll
        for (int ksl = 0; ksl < 2; ++ksl) {
            const int ko = ksl * 32 + (lane >> 4) * 8;
            bf16x8 aqh = *(const bf16x8*)&qsb[0][rt * 16 + (lane & 15)][ko];
            bf16x8 aql = *(const bf16x8*)&qsb[1][rt * 16 + (lane & 15)][ko];
            bf16x8 bkh = *(const bf16x8*)&kvb[0][ct * 16 + (lane & 15)][ko];
            bf16x8 bkl = *(const bf16x8*)&kvb[1][ct * 16 + (lane & 15)][ko];
            sD = __builtin_amdgcn_mfma_f32_16x16x32_bf16(aqh, bkh, sD, 0, 0, 0);
            sD = __builtin_amdgcn_mfma_f32_16x16x32_bf16(aqh, bkl, sD, 0, 0, 0);
            sD = __builtin_amdgcn_mfma_f32_16x16x32_bf16(aql, bkh, sD, 0, 0, 0);
        }
        {
            const int row = rt * 16 + (lane >> 4) * 4;
            const int col = c * CHUNK + ct * 16 + (lane & 15);
            #pragma unroll
            for (int r = 0; r < 4; ++r)
                scp[(row + r) * SCP + col] = sD[r] * 0.125f;
        }
    }
    __syncthreads();   // all scores written

    // ---- load scores for topk (before P overwrites the union buffer) ----
    float o_[4][9];
    #pragma unroll
    for (int rr = 0; rr < 4; ++rr)
        #pragma unroll
        for (int t = 0; t < 9; ++t)
            o_[rr][t] = scp[(4 * w + rr) * SCP + t * 64 + lane];
    __syncthreads();   // every lane's score reads complete

    // ---- top-16 + combined softmax weights -> P hi/lo (wave per 4 rows) ----
    float al = alpha_l[0];
    al = fminf(fmaxf(al, 0.f), 1.f);
    #pragma unroll
    for (int rr = 0; rr < 4; ++rr) {
        const int row = 4 * w + rr;
        float vv[9];
        #pragma unroll
        for (int t = 0; t < 9; ++t) vv[t] = o_[rr][t];
        unsigned mask = 0; float M = 0.f;
        for (int k = 0; k < TOPK; ++k) {
            float bv = vv[0]; int bt = 0;
            #pragma unroll
            for (int t = 1; t < 9; ++t)
                if (vv[t] > bv) { bv = vv[t]; bt = t; }   // strict > keeps min j
            int bj = bt * 64 + lane;
            #pragma unroll
            for (int off = 1; off < 64; off <<= 1) {
                float ov = __shfl_xor(bv, off);
                int   oj = __shfl_xor(bj, off);
                if (ov > bv || (ov == bv && oj < bj)) { bv = ov; bj = oj; }
            }
            if (k == 0) M = bv;
            if ((bj & 63) == lane) {
                const int wt = bj >> 6;
                #pragma unroll
                for (int t = 0; t < 9; ++t)
                    if (t == wt) { vv[t] = -FLT_MAX; mask |= 1u << t; }
            }
        }
        float e[9], gsl = 0.f, ssl = 0.f;
        #pragma unroll
        for (int t = 0; t < 9; ++t) {
            e[t] = expf(o_[rr][t] - M);
            gsl += e[t];
            if ((mask >> t) & 1u) ssl += e[t];
        }
        #pragma unroll
        for (int off = 1; off < 64; off <<= 1) {
            gsl += __shfl_xor(gsl, off);
            ssl += __shfl_xor(ssl, off);
        }
        const float ca = al / gsl, cs = (1.f - al) / ssl;
        #pragma unroll
        for (int t = 0; t < 9; ++t) {
            float wv = e[t] * (ca + (((mask >> t) & 1u) ? cs : 0.f));
            unsigned short hi = f2bf(wv);
            php[row * PP + t * 64 + lane] = hi;
            php[RPB * PP + row * PP + t * 64 + lane] = f2bf(wv - bf2f(hi));
        }
    }

    // ---- PV phase: per chunk, stage V^T then MFMA accumulate ----
    f32x4 acc = (f32x4){0.f, 0.f, 0.f, 0.f};
    for (int c = 0; c < NCHUNK; ++c) {
        __syncthreads();   // P writes visible (c=0) / prev frag reads done
        #pragma unroll
        for (int rep = 0; rep < 2; ++rep) {
            int idx = rep * 512 + tid;
            int hl = idx >> 9, rem = idx & 511;
            int jj = rem >> 3, dg = rem & 7;
            const unsigned short* src = (hl ? qlo : qhi) +
                (size_t)(b * NTOK + c * CHUNK + jj) * DQKV + 2 * DMODEL + h * DHEAD + dg * 8;
            bf16x8 v = *(const bf16x8*)src;
            #pragma unroll
            for (int e2 = 0; e2 < 8; ++e2)
                kvb[hl][dg * 8 + e2][jj] = v[e2];
        }
        __syncthreads();
        #pragma unroll
        for (int ksl = 0; ksl < 2; ++ksl) {
            const int ko = ksl * 32 + (lane >> 4) * 8;
            bf16x8 aph = *(const bf16x8*)&php[(rt * 16 + (lane & 15)) * PP + c * CHUNK + ko];
            bf16x8 apl = *(const bf16x8*)&php[RPB * PP + (rt * 16 + (lane & 15)) * PP + c * CHUNK + ko];
            bf16x8 bvh = *(const bf16x8*)&kvb[0][ct * 16 + (lane & 15)][ko];
            bf16x8 bvl = *(const bf16x8*)&kvb[1][ct * 16 + (lane & 15)][ko];
            acc = __builtin_amdgcn_mfma_f32_16x16x32_bf16(aph, bvh, acc, 0, 0, 0);
            acc = __builtin_amdgcn_mfma_f32_16x16x32_bf16(aph, bvl, acc, 0, 0, 0);
            acc = __builtin_amdgcn_mfma_f32_16x16x32_bf16(apl, bvh, acc, 0, 0, 0);
        }
    }
    {
        const int qrow = i0 + rt * 16 + (lane >> 4) * 4;
        const int dcol = h * DHEAD + ct * 16 + (lane & 15);
        #pragma unroll
        for (int r = 0; r < 4; ++r)
            ao[(size_t)(b * NTOK + qrow + r) * DMODEL + dcol] = f2bf(acc[r]);
    }
}

// ---------------- bilinear helpers (jax.image.resize half-pixel) ------------
__device__ __forceinline__ void bilin_axis(float sF, int H, int& i0, int& i1, float& f) {
    float fl = floorf(sF);
    f = sF - fl;
    int lo = (int)fl;
    i0 = lo < 0 ? 0 : (lo > H - 1 ? H - 1 : lo);
    int hi = lo + 1;
    i1 = hi < 0 ? 0 : (hi > H - 1 ? H - 1 : hi);
}

// NHWC bf16 2x bilinear upsample
__global__ __launch_bounds__(256) void k_up2n(const unsigned short* __restrict__ in,
                                              unsigned short* __restrict__ outp,
                                              int Hin, int C) {
    const int Ho = 2 * Hin;
    const int CG = C / 8;
    const int total = NB * Ho * Ho * CG;
    int t = blockIdx.x * 256 + threadIdx.x;
    if (t >= total) return;
    int cg = t % CG; int r = t / CG;
    int x = r % Ho; r /= Ho;
    int y = r % Ho; int b = r / Ho;
    int i0, i1, j0, j1; float fy, fx;
    bilin_axis(0.5f * y - 0.25f, Hin, i0, i1, fy);
    bilin_axis(0.5f * x - 0.25f, Hin, j0, j1, fx);
    const unsigned short* base = in + (size_t)b * Hin * Hin * C + cg * 8;
    const bf16x8 p00 = *(const bf16x8*)(base + (size_t)(i0 * Hin + j0) * C);
    const bf16x8 p01 = *(const bf16x8*)(base + (size_t)(i0 * Hin + j1) * C);
    const bf16x8 p10 = *(const bf16x8*)(base + (size_t)(i1 * Hin + j0) * C);
    const bf16x8 p11 = *(const bf16x8*)(base + (size_t)(i1 * Hin + j1) * C);
    bf16x8 o;
    #pragma unroll
    for (int e = 0; e < 8; ++e) {
        float v = (1.f - fy) * ((1.f - fx) * bf2f((unsigned short)p00[e]) + fx * bf2f((unsigned short)p01[e]))
                + fy        * ((1.f - fx) * bf2f((unsigned short)p10[e]) + fx * bf2f((unsigned short)p11[e]));
        o[e] = (short)f2bf(v);
    }
    *(bf16x8*)(outp + (size_t)t * 8) = o;
}

// ---------------- conv3: 1x1, 64->21, NHWC bf16 in -> NCHW f32 out ----------
__global__ __launch_bounds__(256) void k_conv3n(const unsigned short* __restrict__ in,
                                                const float* __restrict__ w,
                                                const float* __restrict__ bias,
                                                float* __restrict__ outp) {
    __shared__ float ws_[NCLS * 64];
    for (int i = threadIdx.x; i < NCLS * 64; i += 256) ws_[i] = w[i];
    __syncthreads();
    int t = blockIdx.x * 256 + threadIdx.x;
    if (t >= NB * 9216) return;
    int pix = t % 9216, b = t / 9216;
    float xv[64];
    const unsigned short* p = in + (size_t)t * 64;
    #pragma unroll
    for (int c = 0; c < 8; ++c) {
        bf16x8 v = *(const bf16x8*)(p + c * 8);
        #pragma unroll
        for (int e = 0; e < 8; ++e) xv[c * 8 + e] = bf2f((unsigned short)v[e]);
    }
    float* op = outp + (size_t)b * NCLS * 9216 + pix;
    #pragma unroll
    for (int o = 0; o < NCLS; ++o) {
        float acc = bias[o];
        #pragma unroll
        for (int ic = 0; ic < 64; ++ic) acc += ws_[o * 64 + ic] * xv[ic];
        op[(size_t)o * 9216] = acc;
    }
}

// ---------------- final resize 96 -> 384 (4x bilinear), f32 NCHW ------------
__global__ __launch_bounds__(256) void k_resize4(const float* __restrict__ in,
                                                 float* __restrict__ outp) {
    int t = blockIdx.x * 256 + threadIdx.x;
    if (t >= OUT_TOTAL) return;
    int x = t % IMGSZ; int r = t / IMGSZ; int y = r % IMGSZ; int bc = r / IMGSZ;
    int i0, i1, j0, j1; float fy, fx;
    bilin_axis(0.25f * y - 0.375f, 96, i0, i1, fy);
    bilin_axis(0.25f * x - 0.375f, 96, j0, j1, fx);
    const float* p = in + (size_t)bc * 9216;
    outp[t] = (1.f - fy) * ((1.f - fx) * p[i0 * 96 + j0] + fx * p[i0 * 96 + j1])
            + fy        * ((1.f - fx) * p[i1 * 96 + j0] + fx * p[i1 * 96 + j1]);
}

// ---------------- orchestration ----------------
extern "C" void kernel_launch(void* const* d_in, const int* in_sizes, int n_in,
                              void* d_out, int out_size, void* d_ws, size_t ws_size,
                              hipStream_t stream) {
    const float* img     = (const float*)d_in[0];
    const float* patch_w = (const float*)d_in[1];
    const float* patch_b = (const float*)d_in[2];
    const float* pos_emb = (const float*)d_in[3];
    const float* ln1_g   = (const float*)d_in[4];
    const float* ln1_b   = (const float*)d_in[5];
    const float* qkv_w   = (const float*)d_in[6];
    const float* out_w   = (const float*)d_in[7];
    const float* out_b   = (const float*)d_in[8];
    const float* alpha   = (const float*)d_in[9];
    const float* ln2_g   = (const float*)d_in[10];
    const float* ln2_b   = (const float*)d_in[11];
    const float* ff_w1   = (const float*)d_in[12];
    const float* ff_b1   = (const float*)d_in[13];
    const float* ff_w2   = (const float*)d_in[14];
    const float* ff_b2   = (const float*)d_in[15];
    const float* lnf_g   = (const float*)d_in[16];
    const float* lnf_b   = (const float*)d_in[17];
    const float* conv1_w = (const float*)d_in[18];
    const float* conv1_b = (const float*)d_in[19];
    const float* conv2_w = (const float*)d_in[20];
    const float* conv2_b = (const float*)d_in[21];
    const float* conv3_w = (const float*)d_in[22];
    const float* conv3_b = (const float*)d_in[23];

    // ---- workspace layout (~78 MB) ----
    float* x = (float*)d_ws;                                         // [9216][256] f32
    unsigned short* qkv_hi = (unsigned short*)(x + (size_t)NROWS * DMODEL); // [9216][768]
    unsigned short* qkv_lo = qkv_hi + (size_t)NROWS * DQKV;          // [9216][768]
    unsigned short* xn_bf  = qkv_lo + (size_t)NROWS * DQKV;          // [9216][256]
    unsigned short* ao_bf  = xn_bf + (size_t)NROWS * DMODEL;         // [9216][256]
    unsigned short* h_bf   = ao_bf + (size_t)NROWS * DMODEL;         // [9216][512]
    unsigned short* pA     = h_bf + (size_t)NROWS * DMLP;            // [9216][768]
    unsigned short* wts    = pA + (size_t)NROWS * NPD;
    unsigned short* pwt  = wts;                       // [256][768]
    unsigned short* qwt  = pwt  + 768 * 256;          // [6][768][256]
    unsigned short* owt  = qwt  + 6 * 768 * 256;      // [6][256][256]
    unsigned short* f1wt = owt  + 6 * 256 * 256;      // [6][512][256]
    unsigned short* f2wt = f1wt + 6 * 256 * 512;      // [6][256][512]
    unsigned short* c1wt = f2wt + 6 * 512 * 256;      // [128][9*256]
    unsigned short* c2wt = c1wt + 128 * 9 * 256;      // [64][9*128]
    // conv-stage aliases (transformer buffers free by then)
    unsigned short* c1n = ao_bf;            // [16][24][24][128]
    unsigned short* u1n = h_bf;             // [16][48][48][128]
    unsigned short* c2n = xn_bf;            // [16][48][48][64]
    unsigned short* u2n = qkv_hi;           // [16][96][96][64] (spans hi+lo)
    float* c3 = (float*)pA;                 // [16][21][96][96] f32

    // ---- weight casts ----
    k_castT<<<dim3(768, 1), 256, 0, stream>>>(patch_w, pwt, NPD, DMODEL);
    k_castT<<<dim3(768, 6), 256, 0, stream>>>(qkv_w, qwt, DMODEL, DQKV);
    k_castT<<<dim3(256, 6), 256, 0, stream>>>(out_w, owt, DMODEL, DMODEL);
    k_castT<<<dim3(512, 6), 256, 0, stream>>>(ff_w1, f1wt, DMODEL, DMLP);
    k_castT<<<dim3(512, 6), 256, 0, stream>>>(ff_w2, f2wt, DMLP, DMODEL);
    k_castConv<256><<<1152, 256, 0, stream>>>(conv1_w, c1wt, 128);
    k_castConv<128><<<288, 256, 0, stream>>>(conv2_w, c2wt, 64);

    // ---- patch embed ----
    k_patchify<<<(NROWS * NPD + 255) / 256, 256, 0, stream>>>(img, pA);
    k_mm<128, 64, 3, 0><<<dim3(4, 72), 256, 0, stream>>>(
        pA, pwt, patch_b, pos_emb, x, nullptr, nullptr, NROWS, DMODEL, NPD, 0, 0);

    // ---- transformer layers ----
    for (int l = 0; l < DEPTH; ++l) {
        k_ln<<<NROWS, 256, 0, stream>>>(x, ln1_g + l * DMODEL, ln1_b + l * DMODEL, xn_bf);
        k_mm<128, 128, 5, 0><<<dim3(6, 72), 256, 0, stream>>>(
            xn_bf, qwt + (size_t)l * DQKV * DMODEL, nullptr, nullptr,
            nullptr, qkv_hi, qkv_lo, NROWS, DQKV, DMODEL, 0, 0);
        k_attn<<<dim3(NTOK / RPB, NHEAD, NB), 512, 0, stream>>>(
            qkv_hi, qkv_lo, alpha + l, ao_bf);
        k_mm<128, 64, 1, 0><<<dim3(4, 72), 256, 0, stream>>>(
            ao_bf, owt + (size_t)l * DMODEL * DMODEL, out_b + l * DMODEL, nullptr,
            x, nullptr, nullptr, NROWS, DMODEL, DMODEL, 0, 0);
        k_ln<<<NROWS, 256, 0, stream>>>(x, ln2_g + l * DMODEL, ln2_b + l * DMODEL, xn_bf);
        k_mm<128, 128, 2, 0><<<dim3(4, 72), 256, 0, stream>>>(
            xn_bf, f1wt + (size_t)l * DMLP * DMODEL, ff_b1 + l * DMLP, nullptr,
            nullptr, h_bf, nullptr, NROWS, DMLP, DMODEL, 0, 0);
        k_mm<128, 64, 1, 0><<<dim3(4, 72), 256, 0, stream>>>(
            h_bf, f2wt + (size_t)l * DMODEL * DMLP, ff_b2 + l * DMODEL, nullptr,
            x, nullptr, nullptr, NROWS, DMODEL, DMLP, 0, 0);
    }

    // ---- head ----
    k_ln<<<NROWS, 256, 0, stream>>>(x, lnf_g, lnf_b, xn_bf);
    // conv1: implicit GEMM over NHWC tokens [16][24][24][256]
    k_mm<64, 128, 4, 256><<<dim3(1, 144), 256, 0, stream>>>(
        xn_bf, c1wt, conv1_b, nullptr, nullptr, c1n, nullptr, NROWS, 128, 9 * 256, 24, 24);
    k_up2n<<<(NB * 48 * 48 * 16 + 255) / 256, 256, 0, stream>>>(c1n, u1n, 24, 128);
    // conv2: implicit GEMM over NHWC [16][48][48][128]
    k_mm<128, 64, 4, 128><<<dim3(1, 288), 256, 0, stream>>>(
        u1n, c2wt, conv2_b, nullptr, nullptr, c2n, nullptr, NB * 48 * 48, 64, 9 * 128, 48, 48);
    k_up2n<<<(NB * 96 * 96 * 8 + 255) / 256, 256, 0, stream>>>(c2n, u2n, 48, 64);
    k_conv3n<<<(NB * 9216 + 255) / 256, 256, 0, stream>>>(u2n, conv3_w, conv3_b, c3);
    k_resize4<<<(OUT_TOTAL + 255) / 256, 256, 0, stream>>>(c3, (float*)d_out);
}

// Round 5
// 2115.661 us; speedup vs baseline: 5.7911x; 1.3706x over previous
//
#include <hip/hip_runtime.h>
#include <cfloat>
#include <cmath>

// ---------------- problem constants ----------------
constexpr int NB    = 16;    // batch
constexpr int IMGSZ = 384;
constexpr int PSZ   = 16;
constexpr int NCH   = 3;
constexpr int DMODEL= 256;
constexpr int DEPTH = 6;
constexpr int NHEAD = 4;
constexpr int DHEAD = 64;
constexpr int DQKV  = 768;   // 3*INNER
constexpr int DMLP  = 512;
constexpr int NCLS  = 21;
constexpr int HPATCH= 24;    // IMG/P
constexpr int NTOK  = 576;   // HP*HP
constexpr int NPD   = 768;   // C*P*P
constexpr int TOPK  = 16;
constexpr int NROWS = NB * NTOK;          // 9216
constexpr int OUT_TOTAL = NB * NCLS * IMGSZ * IMGSZ; // 49545216

// attention tiling
constexpr int RPB    = 16;           // query rows per block
constexpr int CHUNK  = 64;           // key/value chunk
constexpr int NCHUNK = NTOK / CHUNK; // 9
constexpr int SCP    = 577;          // score row stride (f32)
constexpr int PP     = 584;          // P row stride (bf16)

typedef __attribute__((ext_vector_type(8))) short bf16x8;
typedef __attribute__((ext_vector_type(4))) float f32x4;

__device__ __forceinline__ unsigned short f2bf(float f) {
    unsigned u = __builtin_bit_cast(unsigned, f);
    unsigned r = (u + 0x7FFFu + ((u >> 16) & 1u)) >> 16;
    return (unsigned short)r;
}
__device__ __forceinline__ float bf2f(unsigned short h) {
    unsigned u = ((unsigned)h) << 16;
    return __builtin_bit_cast(float, u);
}

// ---------------- weight cast+transpose: W[L][K][N] f32 -> Wt[L][N][K] bf16 --
__global__ __launch_bounds__(256) void k_castT(const float* __restrict__ src,
                                               unsigned short* __restrict__ dst,
                                               int K, int N) {
    int t = blockIdx.x * 256 + threadIdx.x;
    if (t >= K * N) return;
    size_t base = (size_t)blockIdx.y * K * N;
    int n = t / K, k = t - n * K;
    dst[base + t] = f2bf(src[base + (size_t)k * N + n]);
}

// conv w [OC][IC][3][3] f32 -> [OC][9][IC] bf16 (tap-major K)
template <int IC>
__global__ __launch_bounds__(256) void k_castConv(const float* __restrict__ src,
                                                  unsigned short* __restrict__ dst,
                                                  int OC) {
    int t = blockIdx.x * 256 + threadIdx.x;
    if (t >= OC * 9 * IC) return;
    int oc = t / (9 * IC);
    int r = t - oc * 9 * IC;
    int tap = r / IC, ic = r - tap * IC;
    dst[t] = f2bf(src[((size_t)(oc * IC + ic)) * 9 + tap]);
}

// ---------------- patchify: img[B,3,384,384] -> A[9216,768] bf16 ------------
__global__ __launch_bounds__(256) void k_patchify(const float* __restrict__ img,
                                                  unsigned short* __restrict__ A) {
    int t = blockIdx.x * 256 + threadIdx.x;
    if (t >= NROWS * NPD) return;
    int r  = t / NPD, pd = t - r * NPD;
    int b  = r / NTOK, n = r - b * NTOK;
    int hy = n / HPATCH, hx = n - hy * HPATCH;
    int c  = pd % NCH;  int q = pd / NCH;
    int p2 = q % PSZ;   int p1 = q / PSZ;
    A[t] = f2bf(img[(((size_t)(b * NCH + c)) * IMGSZ + hy * PSZ + p1) * IMGSZ + hx * PSZ + p2]);
}

// ---------------- unified bf16 MFMA GEMM / implicit conv --------------------
// out[M,N] = A[M,K](bf16) @ Wt[N,K]^T(bf16), fp32 accumulate.
// EPI: 0 none->f32 | 1 bias+residual->f32 | 2 bias+gelu->bf16
//      3 bias+posemb->f32 | 4 bias+relu->bf16 | 5 none->bf16 hi/lo pair
// CIN>0: gather A from NHWC [NB][H][W][CIN] with 3x3 taps (K = 9*CIN, tap-major)
template <int BM, int BN, int EPI, int CIN>
__global__ __launch_bounds__(256) void k_mm(
    const unsigned short* __restrict__ Abf,
    const unsigned short* __restrict__ Wt,
    const float* __restrict__ bias,
    const float* __restrict__ extra,
    float* __restrict__ outf,
    unsigned short* __restrict__ outb,
    unsigned short* __restrict__ outb2,
    int M, int Nn, int K, int H, int Wd)
{
    constexpr int MF = BM / 32;
    constexpr int NF = BN / 32;
    constexpr bool GATHER = (CIN > 0);
    constexpr int AREP = BM * 4 / 256;
    constexpr int BREP = BN * 4 / 256;
    __shared__ __align__(16) short As[4][BM][8];
    __shared__ __align__(16) short Bs[4][BN][8];
    const int tid = threadIdx.x;
    const int bn = blockIdx.x * BN, bm = blockIdx.y * BM;
    const int lane = tid & 63, wid = tid >> 6;
    const int wm = wid >> 1, wn = wid & 1;

    int pb_[AREP], py_[AREP], px_[AREP];
    if (GATHER) {
        #pragma unroll
        for (int rep = 0; rep < AREP; ++rep) {
            int idx = rep * 256 + tid;
            int m = idx >> 2;
            int pix = bm + m;
            px_[rep] = pix % Wd;
            int r = pix / Wd;
            py_[rep] = r % H;
            pb_[rep] = r / H;
        }
    }

    f32x4 acc[MF][NF];
    #pragma unroll
    for (int i = 0; i < MF; ++i)
        #pragma unroll
        for (int j = 0; j < NF; ++j)
            acc[i][j] = (f32x4){0.f, 0.f, 0.f, 0.f};

    for (int k0 = 0; k0 < K; k0 += 32) {
        #pragma unroll
        for (int rep = 0; rep < AREP; ++rep) {
            int idx = rep * 256 + tid;
            int m = idx >> 2, kg = idx & 3;
            if (!GATHER) {
                *(bf16x8*)As[kg][m] =
                    *(const bf16x8*)(Abf + (size_t)(bm + m) * K + k0 + kg * 8);
            } else {
                int k = k0 + kg * 8;
                int tap = k / CIN;
                int ic = k - tap * CIN;
                int dy = tap / 3 - 1, dx = tap % 3 - 1;
                int yy = py_[rep] + dy, xx = px_[rep] + dx;
                bf16x8 v = (bf16x8){0, 0, 0, 0, 0, 0, 0, 0};
                if ((unsigned)yy < (unsigned)H && (unsigned)xx < (unsigned)Wd)
                    v = *(const bf16x8*)(Abf +
                        ((size_t)((pb_[rep] * H + yy) * Wd + xx)) * CIN + ic);
                *(bf16x8*)As[kg][m] = v;
            }
        }
        #pragma unroll
        for (int rep = 0; rep < BREP; ++rep) {
            int idx = rep * 256 + tid;
            int n = idx >> 2, kg = idx & 3;
            *(bf16x8*)Bs[kg][n] =
                *(const bf16x8*)(Wt + (size_t)(bn + n) * K + k0 + kg * 8);
        }
        __syncthreads();
        bf16x8 af[MF], bfv[NF];
        #pragma unroll
        for (int i = 0; i < MF; ++i)
            af[i] = *(const bf16x8*)As[lane >> 4][wm * (BM / 2) + i * 16 + (lane & 15)];
        #pragma unroll
        for (int j = 0; j < NF; ++j)
            bfv[j] = *(const bf16x8*)Bs[lane >> 4][wn * (BN / 2) + j * 16 + (lane & 15)];
        #pragma unroll
        for (int i = 0; i < MF; ++i)
            #pragma unroll
            for (int j = 0; j < NF; ++j)
                acc[i][j] = __builtin_amdgcn_mfma_f32_16x16x32_bf16(
                    af[i], bfv[j], acc[i][j], 0, 0, 0);
        __syncthreads();
    }

    #pragma unroll
    for (int i = 0; i < MF; ++i) {
        const int row0 = bm + wm * (BM / 2) + i * 16 + (lane >> 4) * 4;
        #pragma unroll
        for (int j = 0; j < NF; ++j) {
            const int col = bn + wn * (BN / 2) + j * 16 + (lane & 15);
            #pragma unroll
            for (int r = 0; r < 4; ++r) {
                const int rr = row0 + r;
                float v = acc[i][j][r];
                if (EPI >= 1 && EPI <= 4) v += bias[col];
                if (EPI == 1) v += outf[(size_t)rr * Nn + col];
                if (EPI == 2) v = 0.5f * v * (1.0f + erff(v * 0.70710678118f));
                if (EPI == 3) v += extra[(size_t)(rr % NTOK) * Nn + col];
                if (EPI == 4) v = fmaxf(v, 0.f);
                if (EPI == 2 || EPI == 4) {
                    outb[(size_t)rr * Nn + col] = f2bf(v);
                } else if (EPI == 5) {
                    unsigned short hi = f2bf(v);
                    outb[(size_t)rr * Nn + col] = hi;
                    outb2[(size_t)rr * Nn + col] = f2bf(v - bf2f(hi));
                } else {
                    outf[(size_t)rr * Nn + col] = v;
                }
            }
        }
    }
}

// ---------------- LayerNorm over last dim (256), bf16 out -------------------
__global__ __launch_bounds__(256) void k_ln(const float* __restrict__ x,
                                            const float* __restrict__ g,
                                            const float* __restrict__ bb,
                                            unsigned short* __restrict__ y) {
    const int row = blockIdx.x, tid = threadIdx.x;
    float v = x[(size_t)row * DMODEL + tid];
    float s = v;
    #pragma unroll
    for (int off = 32; off; off >>= 1) s += __shfl_xor(s, off);
    __shared__ float ls[4], ls2[4];
    if ((tid & 63) == 0) ls[tid >> 6] = s;
    __syncthreads();
    float mu = (ls[0] + ls[1] + ls[2] + ls[3]) * (1.0f / DMODEL);
    float d = v - mu;
    float qq = d * d;
    #pragma unroll
    for (int off = 32; off; off >>= 1) qq += __shfl_xor(qq, off);
    if ((tid & 63) == 0) ls2[tid >> 6] = qq;
    __syncthreads();
    float var = (ls2[0] + ls2[1] + ls2[2] + ls2[3]) * (1.0f / DMODEL);
    y[(size_t)row * DMODEL + tid] = f2bf(d * rsqrtf(var + 1e-5f) * g[tid] + bb[tid]);
}

// ---------------- V transpose: qkv V-part -> vT[(b*4+h)*64 + d][576] --------
__global__ __launch_bounds__(256) void k_vT(const unsigned short* __restrict__ qhi,
                                            const unsigned short* __restrict__ qlo,
                                            unsigned short* __restrict__ vthi,
                                            unsigned short* __restrict__ vtlo) {
    __shared__ short tile[2][64][66];   // [hl][d][n], stride 66 (2-way-max reads)
    const int c = blockIdx.x, h = blockIdx.y, b = blockIdx.z;
    const int tid = threadIdx.x;
    #pragma unroll
    for (int rep = 0; rep < 4; ++rep) {
        int idx = rep * 256 + tid;
        int hl = idx >> 9, rem = idx & 511, n = rem >> 3, dg = rem & 7;
        const unsigned short* src = (hl ? qlo : qhi) +
            (size_t)(b * NTOK + c * CHUNK + n) * DQKV + 2 * DMODEL + h * DHEAD + dg * 8;
        bf16x8 v = *(const bf16x8*)src;
        #pragma unroll
        for (int e = 0; e < 8; ++e) tile[hl][dg * 8 + e][n] = v[e];
    }
    __syncthreads();
    #pragma unroll
    for (int rep = 0; rep < 4; ++rep) {
        int idx = rep * 256 + tid;
        int hl = idx >> 9, rem = idx & 511, d = rem >> 3, np = rem & 7;
        bf16x8 o;
        #pragma unroll
        for (int e = 0; e < 8; ++e) o[e] = tile[hl][d][np * 8 + e];
        *(bf16x8*)((hl ? vtlo : vthi) +
                   (size_t)((b * NHEAD + h) * DHEAD + d) * NTOK + c * CHUNK + np * 8) = o;
    }
}

// ---------------- chunk load/store helpers for k_attn ----------------
__device__ __forceinline__ void ldchunk(bf16x8 (&r)[4],
                                        const unsigned short* __restrict__ ph,
                                        const unsigned short* __restrict__ pl,
                                        size_t base, int rstride, int tid) {
    #pragma unroll
    for (int rep = 0; rep < 4; ++rep) {
        int idx = rep * 256 + tid;
        int hl = idx >> 9, rem = idx & 511, row = rem >> 3, dg = rem & 7;
        r[rep] = *(const bf16x8*)((hl ? pl : ph) + base + (size_t)row * rstride + dg * 8);
    }
}
__device__ __forceinline__ void stchunk(const bf16x8 (&r)[4],
                                        short (*kv)[CHUNK][72], int tid) {
    #pragma unroll
    for (int rep = 0; rep < 4; ++rep) {
        int idx = rep * 256 + tid;
        int hl = idx >> 9, rem = idx & 511, row = rem >> 3, dg = rem & 7;
        *(bf16x8*)&kv[hl][row][dg * 8] = r[rep];
    }
}

// ---------------- MFMA hybrid attention, 16 rows/block, 256 threads ---------
// Scores: 3-pass split-bf16 MFMA (Qh*Kh + Qh*Kl + Ql*Kh) == fp32 to ~1e-5.
// Top-16: value-max butterfly + ballot/ctz min-index (exact lax.top_k tie order).
// PV: 3-pass split-bf16 MFMA, V pre-transposed in global (linear LDS staging).
__global__ __launch_bounds__(256, 2) void k_attn(
    const unsigned short* __restrict__ qhi,
    const unsigned short* __restrict__ qlo,
    const unsigned short* __restrict__ vthi,
    const unsigned short* __restrict__ vtlo,
    const float* __restrict__ alpha_l,
    unsigned short* __restrict__ ao) {
    __shared__ __align__(16) short qsb[2][RPB][72];        // 4608 B
    __shared__ __align__(16) short kvb[2][2][CHUNK][72];   // [buf][hl] 36864 B
    __shared__ __align__(16) unsigned char ub[37376];      // sc f32[16][577] | P hi/lo [2][16][584]

    float* scp = (float*)ub;
    short* php = (short*)ub;

    const int tid = threadIdx.x;
    const int lane = tid & 63;
    const int ct = tid >> 6;                  // wave id = output col tile
    const int h = blockIdx.y, b = blockIdx.z;
    const int i0 = blockIdx.x * RPB;
    const size_t qbase = (size_t)(b * NTOK) * DQKV;
    const size_t kb0 = qbase + DMODEL + h * DHEAD;          // K base (add c*CHUNK*DQKV)
    const size_t vb0 = (size_t)((b * NHEAD + h) * DHEAD) * NTOK; // vT base (add c*CHUNK)

    // ---- stage Q hi/lo ----
    {
        int hl = tid >> 7, rem = tid & 127, row = rem >> 3, dg = rem & 7;
        bf16x8 qv = *(const bf16x8*)((hl ? qlo : qhi) + qbase +
                                     (size_t)(i0 + row) * DQKV + h * DHEAD + dg * 8);
        *(bf16x8*)&qsb[hl][row][dg * 8] = qv;
    }

    bf16x8 rk[4];
    // ---- score phase: double-buffered chunks ----
    ldchunk(rk, qhi, qlo, kb0, DQKV, tid);
    stchunk(rk, kvb[0], tid);
    ldchunk(rk, qhi, qlo, kb0 + (size_t)CHUNK * DQKV, DQKV, tid);
    __syncthreads();
    for (int c = 0; c < NCHUNK; ++c) {
        if (c + 1 < NCHUNK) {
            stchunk(rk, kvb[(c + 1) & 1], tid);
            if (c + 2 < NCHUNK)
                ldchunk(rk, qhi, qlo, kb0 + (size_t)(c + 2) * CHUNK * DQKV, DQKV, tid);
        }
        f32x4 sD = (f32x4){0.f, 0.f, 0.f, 0.f};
        #pragma unroll
        for (int ksl = 0; ksl < 2; ++ksl) {
            const int ko = ksl * 32 + (lane >> 4) * 8;
            bf16x8 aqh = *(const bf16x8*)&qsb[0][lane & 15][ko];
            bf16x8 aql = *(const bf16x8*)&qsb[1][lane & 15][ko];
            bf16x8 bkh = *(const bf16x8*)&kvb[c & 1][0][ct * 16 + (lane & 15)][ko];
            bf16x8 bkl = *(const bf16x8*)&kvb[c & 1][1][ct * 16 + (lane & 15)][ko];
            sD = __builtin_amdgcn_mfma_f32_16x16x32_bf16(aqh, bkh, sD, 0, 0, 0);
            sD = __builtin_amdgcn_mfma_f32_16x16x32_bf16(aqh, bkl, sD, 0, 0, 0);
            sD = __builtin_amdgcn_mfma_f32_16x16x32_bf16(aql, bkh, sD, 0, 0, 0);
        }
        {
            const int row = (lane >> 4) * 4;
            const int col = c * CHUNK + ct * 16 + (lane & 15);
            #pragma unroll
            for (int r = 0; r < 4; ++r)
                scp[(row + r) * SCP + col] = sD[r] * 0.125f;
        }
        __syncthreads();
    }

    // ---- pull scores to regs (each wave: rows 4*ct .. 4*ct+3) ----
    float o_[4][9];
    const int wrow = ct * 4;
    #pragma unroll
    for (int rr = 0; rr < 4; ++rr)
        #pragma unroll
        for (int t = 0; t < 9; ++t)
            o_[rr][t] = scp[(wrow + rr) * SCP + t * 64 + lane];
    ldchunk(rk, vthi, vtlo, vb0, NTOK, tid);    // V chunk 0 in flight under topk
    __syncthreads();   // all score reads done -> P buffer may be written

    // ---- top-16 + combined softmax weights -> P hi/lo ----
    const float al = fminf(fmaxf(alpha_l[0], 0.f), 1.f);
    #pragma unroll
    for (int rr = 0; rr < 4; ++rr) {
        const int row = wrow + rr;
        float vv[9];
        #pragma unroll
        for (int t = 0; t < 9; ++t) vv[t] = o_[rr][t];
        unsigned mask = 0; float M = 0.f;
        for (int k = 0; k < TOPK; ++k) {
            float lm = vv[0];
            #pragma unroll
            for (int t = 1; t < 9; ++t) lm = fmaxf(lm, vv[t]);
            #pragma unroll
            for (int off = 1; off < 64; off <<= 1) lm = fmaxf(lm, __shfl_xor(lm, off));
            if (k == 0) M = lm;
            int jstar = 0;
            #pragma unroll
            for (int t = 0; t < 9; ++t) {
                unsigned long long bal = __ballot(vv[t] == lm);
                if (bal) { jstar = t * 64 + (int)__builtin_ctzll(bal); break; }
            }
            const int ts = jstar >> 6, ls = jstar & 63;
            if (lane == ls) {
                #pragma unroll
                for (int t = 0; t < 9; ++t)
                    if (t == ts) { vv[t] = -FLT_MAX; mask |= 1u << t; }
            }
        }
        float e[9], gsl = 0.f, ssl = 0.f;
        #pragma unroll
        for (int t = 0; t < 9; ++t) {
            e[t] = __expf(o_[rr][t] - M);
            gsl += e[t];
            if ((mask >> t) & 1u) ssl += e[t];
        }
        #pragma unroll
        for (int off = 1; off < 64; off <<= 1) {
            gsl += __shfl_xor(gsl, off);
            ssl += __shfl_xor(ssl, off);
        }
        const float ca = al / gsl, cs = (1.f - al) / ssl;
        #pragma unroll
        for (int t = 0; t < 9; ++t) {
            float wv = e[t] * (ca + (((mask >> t) & 1u) ? cs : 0.f));
            unsigned short hi = f2bf(wv);
            php[row * PP + t * 64 + lane] = hi;
            php[RPB * PP + row * PP + t * 64 + lane] = f2bf(wv - bf2f(hi));
        }
    }

    // ---- PV phase: double-buffered vT chunks ----
    stchunk(rk, kvb[0], tid);
    ldchunk(rk, vthi, vtlo, vb0 + CHUNK, NTOK, tid);
    __syncthreads();   // P writes + V buf0 visible
    f32x4 acc = (f32x4){0.f, 0.f, 0.f, 0.f};
    for (int c = 0; c < NCHUNK; ++c) {
        if (c + 1 < NCHUNK) {
            stchunk(rk, kvb[(c + 1) & 1], tid);
            if (c + 2 < NCHUNK)
                ldchunk(rk, vthi, vtlo, vb0 + (size_t)(c + 2) * CHUNK, NTOK, tid);
        }
        #pragma unroll
        for (int ksl = 0; ksl < 2; ++ksl) {
            const int ko = ksl * 32 + (lane >> 4) * 8;
            bf16x8 aph = *(const bf16x8*)&php[(lane & 15) * PP + c * CHUNK + ko];
            bf16x8 apl = *(const bf16x8*)&php[RPB * PP + (lane & 15) * PP + c * CHUNK + ko];
            bf16x8 bvh = *(const bf16x8*)&kvb[c & 1][0][ct * 16 + (lane & 15)][ko];
            bf16x8 bvl = *(const bf16x8*)&kvb[c & 1][1][ct * 16 + (lane & 15)][ko];
            acc = __builtin_amdgcn_mfma_f32_16x16x32_bf16(aph, bvh, acc, 0, 0, 0);
            acc = __builtin_amdgcn_mfma_f32_16x16x32_bf16(aph, bvl, acc, 0, 0, 0);
            acc = __builtin_amdgcn_mfma_f32_16x16x32_bf16(apl, bvh, acc, 0, 0, 0);
        }
        __syncthreads();
    }
    {
        const int qrow = i0 + (lane >> 4) * 4;
        const int dcol = h * DHEAD + ct * 16 + (lane & 15);
        #pragma unroll
        for (int r = 0; r < 4; ++r)
            ao[(size_t)(b * NTOK + qrow + r) * DMODEL + dcol] = f2bf(acc[r]);
    }
}

// ---------------- bilinear helpers (jax.image.resize half-pixel) ------------
__device__ __forceinline__ void bilin_axis(float sF, int H, int& i0, int& i1, float& f) {
    float fl = floorf(sF);
    f = sF - fl;
    int lo = (int)fl;
    i0 = lo < 0 ? 0 : (lo > H - 1 ? H - 1 : lo);
    int hi = lo + 1;
    i1 = hi < 0 ? 0 : (hi > H - 1 ? H - 1 : hi);
}

// NHWC bf16 2x bilinear upsample
__global__ __launch_bounds__(256) void k_up2n(const unsigned short* __restrict__ in,
                                              unsigned short* __restrict__ outp,
                                              int Hin, int C) {
    const int Ho = 2 * Hin;
    const int CG = C / 8;
    const int total = NB * Ho * Ho * CG;
    int t = blockIdx.x * 256 + threadIdx.x;
    if (t >= total) return;
    int cg = t % CG; int r = t / CG;
    int x = r % Ho; r /= Ho;
    int y = r % Ho; int b = r / Ho;
    int i0, i1, j0, j1; float fy, fx;
    bilin_axis(0.5f * y - 0.25f, Hin, i0, i1, fy);
    bilin_axis(0.5f * x - 0.25f, Hin, j0, j1, fx);
    const unsigned short* base = in + (size_t)b * Hin * Hin * C + cg * 8;
    const bf16x8 p00 = *(const bf16x8*)(base + (size_t)(i0 * Hin + j0) * C);
    const bf16x8 p01 = *(const bf16x8*)(base + (size_t)(i0 * Hin + j1) * C);
    const bf16x8 p10 = *(const bf16x8*)(base + (size_t)(i1 * Hin + j0) * C);
    const bf16x8 p11 = *(const bf16x8*)(base + (size_t)(i1 * Hin + j1) * C);
    bf16x8 o;
    #pragma unroll
    for (int e = 0; e < 8; ++e) {
        float v = (1.f - fy) * ((1.f - fx) * bf2f((unsigned short)p00[e]) + fx * bf2f((unsigned short)p01[e]))
                + fy        * ((1.f - fx) * bf2f((unsigned short)p10[e]) + fx * bf2f((unsigned short)p11[e]));
        o[e] = (short)f2bf(v);
    }
    *(bf16x8*)(outp + (size_t)t * 8) = o;
}

// ---------------- conv3: 1x1, 64->21, NHWC bf16 in -> NCHW f32 out ----------
__global__ __launch_bounds__(256) void k_conv3n(const unsigned short* __restrict__ in,
                                                const float* __restrict__ w,
                                                const float* __restrict__ bias,
                                                float* __restrict__ outp) {
    __shared__ float ws_[NCLS * 64];
    for (int i = threadIdx.x; i < NCLS * 64; i += 256) ws_[i] = w[i];
    __syncthreads();
    int t = blockIdx.x * 256 + threadIdx.x;
    if (t >= NB * 9216) return;
    int pix = t % 9216, b = t / 9216;
    float xv[64];
    const unsigned short* p = in + (size_t)t * 64;
    #pragma unroll
    for (int c = 0; c < 8; ++c) {
        bf16x8 v = *(const bf16x8*)(p + c * 8);
        #pragma unroll
        for (int e = 0; e < 8; ++e) xv[c * 8 + e] = bf2f((unsigned short)v[e]);
    }
    float* op = outp + (size_t)b * NCLS * 9216 + pix;
    #pragma unroll
    for (int o = 0; o < NCLS; ++o) {
        float acc = bias[o];
        #pragma unroll
        for (int ic = 0; ic < 64; ++ic) acc += ws_[o * 64 + ic] * xv[ic];
        op[(size_t)o * 9216] = acc;
    }
}

// ---------------- final resize 96 -> 384 (4x bilinear), f32 NCHW ------------
__global__ __launch_bounds__(256) void k_resize4(const float* __restrict__ in,
                                                 float* __restrict__ outp) {
    int t = blockIdx.x * 256 + threadIdx.x;
    if (t >= OUT_TOTAL) return;
    int x = t % IMGSZ; int r = t / IMGSZ; int y = r % IMGSZ; int bc = r / IMGSZ;
    int i0, i1, j0, j1; float fy, fx;
    bilin_axis(0.25f * y - 0.375f, 96, i0, i1, fy);
    bilin_axis(0.25f * x - 0.375f, 96, j0, j1, fx);
    const float* p = in + (size_t)bc * 9216;
    outp[t] = (1.f - fy) * ((1.f - fx) * p[i0 * 96 + j0] + fx * p[i0 * 96 + j1])
            + fy        * ((1.f - fx) * p[i1 * 96 + j0] + fx * p[i1 * 96 + j1]);
}

// ---------------- orchestration ----------------
extern "C" void kernel_launch(void* const* d_in, const int* in_sizes, int n_in,
                              void* d_out, int out_size, void* d_ws, size_t ws_size,
                              hipStream_t stream) {
    const float* img     = (const float*)d_in[0];
    const float* patch_w = (const float*)d_in[1];
    const float* patch_b = (const float*)d_in[2];
    const float* pos_emb = (const float*)d_in[3];
    const float* ln1_g   = (const float*)d_in[4];
    const float* ln1_b   = (const float*)d_in[5];
    const float* qkv_w   = (const float*)d_in[6];
    const float* out_w   = (const float*)d_in[7];
    const float* out_b   = (const float*)d_in[8];
    const float* alpha   = (const float*)d_in[9];
    const float* ln2_g   = (const float*)d_in[10];
    const float* ln2_b   = (const float*)d_in[11];
    const float* ff_w1   = (const float*)d_in[12];
    const float* ff_b1   = (const float*)d_in[13];
    const float* ff_w2   = (const float*)d_in[14];
    const float* ff_b2   = (const float*)d_in[15];
    const float* lnf_g   = (const float*)d_in[16];
    const float* lnf_b   = (const float*)d_in[17];
    const float* conv1_w = (const float*)d_in[18];
    const float* conv1_b = (const float*)d_in[19];
    const float* conv2_w = (const float*)d_in[20];
    const float* conv2_b = (const float*)d_in[21];
    const float* conv3_w = (const float*)d_in[22];
    const float* conv3_b = (const float*)d_in[23];

    // ---- workspace layout (~88 MB) ----
    float* x = (float*)d_ws;                                         // [9216][256] f32
    unsigned short* qkv_hi = (unsigned short*)(x + (size_t)NROWS * DMODEL); // [9216][768]
    unsigned short* qkv_lo = qkv_hi + (size_t)NROWS * DQKV;          // [9216][768]
    unsigned short* xn_bf  = qkv_lo + (size_t)NROWS * DQKV;          // [9216][256]
    unsigned short* ao_bf  = xn_bf + (size_t)NROWS * DMODEL;         // [9216][256]
    unsigned short* h_bf   = ao_bf + (size_t)NROWS * DMODEL;         // [9216][512]
    unsigned short* pA     = h_bf + (size_t)NROWS * DMLP;            // [9216][768]
    unsigned short* wts    = pA + (size_t)NROWS * NPD;
    unsigned short* pwt  = wts;                       // [256][768]
    unsigned short* qwt  = pwt  + 768 * 256;          // [6][768][256]
    unsigned short* owt  = qwt  + 6 * 768 * 256;      // [6][256][256]
    unsigned short* f1wt = owt  + 6 * 256 * 256;      // [6][512][256]
    unsigned short* f2wt = f1wt + 6 * 256 * 512;      // [6][256][512]
    unsigned short* c1wt = f2wt + 6 * 512 * 256;      // [128][9*256]
    unsigned short* c2wt = c1wt + 128 * 9 * 256;      // [64][9*128]
    unsigned short* vthi = c2wt + 64 * 9 * 128;       // [64*64][576]
    unsigned short* vtlo = vthi + (size_t)64 * 64 * NTOK;
    // conv-stage aliases (transformer buffers free by then)
    unsigned short* c1n = ao_bf;            // [16][24][24][128]
    unsigned short* u1n = h_bf;             // [16][48][48][128]
    unsigned short* c2n = xn_bf;            // [16][48][48][64]
    unsigned short* u2n = qkv_hi;           // [16][96][96][64] (spans hi+lo)
    float* c3 = (float*)pA;                 // [16][21][96][96] f32

    // ---- weight casts ----
    k_castT<<<dim3(768, 1), 256, 0, stream>>>(patch_w, pwt, NPD, DMODEL);
    k_castT<<<dim3(768, 6), 256, 0, stream>>>(qkv_w, qwt, DMODEL, DQKV);
    k_castT<<<dim3(256, 6), 256, 0, stream>>>(out_w, owt, DMODEL, DMODEL);
    k_castT<<<dim3(512, 6), 256, 0, stream>>>(ff_w1, f1wt, DMODEL, DMLP);
    k_castT<<<dim3(512, 6), 256, 0, stream>>>(ff_w2, f2wt, DMLP, DMODEL);
    k_castConv<256><<<1152, 256, 0, stream>>>(conv1_w, c1wt, 128);
    k_castConv<128><<<288, 256, 0, stream>>>(conv2_w, c2wt, 64);

    // ---- patch embed ----
    k_patchify<<<(NROWS * NPD + 255) / 256, 256, 0, stream>>>(img, pA);
    k_mm<128, 64, 3, 0><<<dim3(4, 72), 256, 0, stream>>>(
        pA, pwt, patch_b, pos_emb, x, nullptr, nullptr, NROWS, DMODEL, NPD, 0, 0);

    // ---- transformer layers ----
    for (int l = 0; l < DEPTH; ++l) {
        k_ln<<<NROWS, 256, 0, stream>>>(x, ln1_g + l * DMODEL, ln1_b + l * DMODEL, xn_bf);
        k_mm<128, 128, 5, 0><<<dim3(6, 72), 256, 0, stream>>>(
            xn_bf, qwt + (size_t)l * DQKV * DMODEL, nullptr, nullptr,
            nullptr, qkv_hi, qkv_lo, NROWS, DQKV, DMODEL, 0, 0);
        k_vT<<<dim3(NCHUNK, NHEAD, NB), 256, 0, stream>>>(qkv_hi, qkv_lo, vthi, vtlo);
        k_attn<<<dim3(NTOK / RPB, NHEAD, NB), 256, 0, stream>>>(
            qkv_hi, qkv_lo, vthi, vtlo, alpha + l, ao_bf);
        k_mm<128, 64, 1, 0><<<dim3(4, 72), 256, 0, stream>>>(
            ao_bf, owt + (size_t)l * DMODEL * DMODEL, out_b + l * DMODEL, nullptr,
            x, nullptr, nullptr, NROWS, DMODEL, DMODEL, 0, 0);
        k_ln<<<NROWS, 256, 0, stream>>>(x, ln2_g + l * DMODEL, ln2_b + l * DMODEL, xn_bf);
        k_mm<128, 128, 2, 0><<<dim3(4, 72), 256, 0, stream>>>(
            xn_bf, f1wt + (size_t)l * DMLP * DMODEL, ff_b1 + l * DMLP, nullptr,
            nullptr, h_bf, nullptr, NROWS, DMLP, DMODEL, 0, 0);
        k_mm<128, 64, 1, 0><<<dim3(4, 72), 256, 0, stream>>>(
            h_bf, f2wt + (size_t)l * DMODEL * DMLP, ff_b2 + l * DMODEL, nullptr,
            x, nullptr, nullptr, NROWS, DMODEL, DMLP, 0, 0);
    }

    // ---- head ----
    k_ln<<<NROWS, 256, 0, stream>>>(x, lnf_g, lnf_b, xn_bf);
    // conv1: implicit GEMM over NHWC tokens [16][24][24][256]
    k_mm<64, 128, 4, 256><<<dim3(1, 144), 256, 0, stream>>>(
        xn_bf, c1wt, conv1_b, nullptr, nullptr, c1n, nullptr, NROWS, 128, 9 * 256, 24, 24);
    k_up2n<<<(NB * 48 * 48 * 16 + 255) / 256, 256, 0, stream>>>(c1n, u1n, 24, 128);
    // conv2: implicit GEMM over NHWC [16][48][48][128]
    k_mm<128, 64, 4, 128><<<dim3(1, 288), 256, 0, stream>>>(
        u1n, c2wt, conv2_b, nullptr, nullptr, c2n, nullptr, NB * 48 * 48, 64, 9 * 128, 48, 48);
    k_up2n<<<(NB * 96 * 96 * 8 + 255) / 256, 256, 0, stream>>>(c2n, u2n, 48, 64);
    k_conv3n<<<(NB * 9216 + 255) / 256, 256, 0, stream>>>(u2n, conv3_w, conv3_b, c3);
    k_resize4<<<(OUT_TOTAL + 255) / 256, 256, 0, stream>>>(c3, (float*)d_out);
}

// Round 6
// 2101.889 us; speedup vs baseline: 5.8290x; 1.0066x over previous
//
#include <hip/hip_runtime.h>
#include <cfloat>
#include <cmath>

// ---------------- problem constants ----------------
constexpr int NB    = 16;    // batch
constexpr int IMGSZ = 384;
constexpr int PSZ   = 16;
constexpr int NCH   = 3;
constexpr int DMODEL= 256;
constexpr int DEPTH = 6;
constexpr int NHEAD = 4;
constexpr int DHEAD = 64;
constexpr int DQKV  = 768;   // 3*INNER
constexpr int DMLP  = 512;
constexpr int NCLS  = 21;
constexpr int HPATCH= 24;    // IMG/P
constexpr int NTOK  = 576;   // HP*HP
constexpr int NPD   = 768;   // C*P*P
constexpr int TOPK  = 16;
constexpr int NROWS = NB * NTOK;          // 9216
constexpr int OUT_TOTAL = NB * NCLS * IMGSZ * IMGSZ; // 49545216

// attention tiling
constexpr int RPB    = 16;           // query rows per block
constexpr int NBLK   = NTOK / RPB;   // 36 blocks per (b,h)
constexpr int CHUNK  = 64;           // key/value chunk
constexpr int NCHUNK = NTOK / CHUNK; // 9
constexpr int SCP    = 577;          // score row stride (f32)
constexpr int PP     = 584;          // P row stride (bf16)

typedef __attribute__((ext_vector_type(8))) short bf16x8;
typedef __attribute__((ext_vector_type(4))) float f32x4;

__device__ __forceinline__ unsigned short f2bf(float f) {
    unsigned u = __builtin_bit_cast(unsigned, f);
    unsigned r = (u + 0x7FFFu + ((u >> 16) & 1u)) >> 16;
    return (unsigned short)r;
}
__device__ __forceinline__ float bf2f(unsigned short h) {
    unsigned u = ((unsigned)h) << 16;
    return __builtin_bit_cast(float, u);
}

// ---------------- weight cast+transpose: W[L][K][N] f32 -> Wt[L][N][K] bf16 --
__global__ __launch_bounds__(256) void k_castT(const float* __restrict__ src,
                                               unsigned short* __restrict__ dst,
                                               int K, int N) {
    int t = blockIdx.x * 256 + threadIdx.x;
    if (t >= K * N) return;
    size_t base = (size_t)blockIdx.y * K * N;
    int n = t / K, k = t - n * K;
    dst[base + t] = f2bf(src[base + (size_t)k * N + n]);
}

// conv w [OC][IC][3][3] f32 -> [OC][9][IC] bf16 (tap-major K)
template <int IC>
__global__ __launch_bounds__(256) void k_castConv(const float* __restrict__ src,
                                                  unsigned short* __restrict__ dst,
                                                  int OC) {
    int t = blockIdx.x * 256 + threadIdx.x;
    if (t >= OC * 9 * IC) return;
    int oc = t / (9 * IC);
    int r = t - oc * 9 * IC;
    int tap = r / IC, ic = r - tap * IC;
    dst[t] = f2bf(src[((size_t)(oc * IC + ic)) * 9 + tap]);
}

// ---------------- patchify: img[B,3,384,384] -> A[9216,768] bf16 ------------
__global__ __launch_bounds__(256) void k_patchify(const float* __restrict__ img,
                                                  unsigned short* __restrict__ A) {
    int t = blockIdx.x * 256 + threadIdx.x;
    if (t >= NROWS * NPD) return;
    int r  = t / NPD, pd = t - r * NPD;
    int b  = r / NTOK, n = r - b * NTOK;
    int hy = n / HPATCH, hx = n - hy * HPATCH;
    int c  = pd % NCH;  int q = pd / NCH;
    int p2 = q % PSZ;   int p1 = q / PSZ;
    A[t] = f2bf(img[(((size_t)(b * NCH + c)) * IMGSZ + hy * PSZ + p1) * IMGSZ + hx * PSZ + p2]);
}

// ---------------- unified bf16 MFMA GEMM / implicit conv --------------------
// out[M,N] = A[M,K](bf16) @ Wt[N,K]^T(bf16), fp32 accumulate.
// EPI: 0 none->f32 | 1 bias+residual->f32 | 2 bias+gelu->bf16
//      3 bias+posemb->f32 | 4 bias+relu->bf16 | 5 none->bf16 hi/lo pair
// CIN>0: gather A from NHWC [NB][H][W][CIN] with 3x3 taps (K = 9*CIN, tap-major)
// Flat grid of gxd*gyd blocks; XCD-aware swizzle keyed on M-tile (gyd%8==0).
template <int BM, int BN, int EPI, int CIN>
__global__ __launch_bounds__(256) void k_mm(
    const unsigned short* __restrict__ Abf,
    const unsigned short* __restrict__ Wt,
    const float* __restrict__ bias,
    const float* __restrict__ extra,
    float* __restrict__ outf,
    unsigned short* __restrict__ outb,
    unsigned short* __restrict__ outb2,
    int M, int Nn, int K, int H, int Wd, int gxd, int gyd)
{
    constexpr int MF = BM / 32;
    constexpr int NF = BN / 32;
    constexpr bool GATHER = (CIN > 0);
    constexpr int AREP = BM * 4 / 256;
    constexpr int BREP = BN * 4 / 256;
    __shared__ __align__(16) short As[4][BM][8];
    __shared__ __align__(16) short Bs[4][BN][8];
    const int tid = threadIdx.x;
    // XCD swizzle: all blocks sharing an M-tile window land on one XCD
    const int p = blockIdx.x;
    const int xr = p & 7, xq = p >> 3;
    const int bm = (xr * (gyd >> 3) + xq / gxd) * BM;
    const int bn = (xq % gxd) * BN;
    const int lane = tid & 63, wid = tid >> 6;
    const int wm = wid >> 1, wn = wid & 1;

    int pb_[AREP], py_[AREP], px_[AREP];
    if (GATHER) {
        #pragma unroll
        for (int rep = 0; rep < AREP; ++rep) {
            int idx = rep * 256 + tid;
            int m = idx >> 2;
            int pix = bm + m;
            px_[rep] = pix % Wd;
            int r = pix / Wd;
            py_[rep] = r % H;
            pb_[rep] = r / H;
        }
    }

    f32x4 acc[MF][NF];
    #pragma unroll
    for (int i = 0; i < MF; ++i)
        #pragma unroll
        for (int j = 0; j < NF; ++j)
            acc[i][j] = (f32x4){0.f, 0.f, 0.f, 0.f};

    for (int k0 = 0; k0 < K; k0 += 32) {
        #pragma unroll
        for (int rep = 0; rep < AREP; ++rep) {
            int idx = rep * 256 + tid;
            int m = idx >> 2, kg = idx & 3;
            if (!GATHER) {
                *(bf16x8*)As[kg][m] =
                    *(const bf16x8*)(Abf + (size_t)(bm + m) * K + k0 + kg * 8);
            } else {
                int k = k0 + kg * 8;
                int tap = k / CIN;
                int ic = k - tap * CIN;
                int dy = tap / 3 - 1, dx = tap % 3 - 1;
                int yy = py_[rep] + dy, xx = px_[rep] + dx;
                bf16x8 v = (bf16x8){0, 0, 0, 0, 0, 0, 0, 0};
                if ((unsigned)yy < (unsigned)H && (unsigned)xx < (unsigned)Wd)
                    v = *(const bf16x8*)(Abf +
                        ((size_t)((pb_[rep] * H + yy) * Wd + xx)) * CIN + ic);
                *(bf16x8*)As[kg][m] = v;
            }
        }
        #pragma unroll
        for (int rep = 0; rep < BREP; ++rep) {
            int idx = rep * 256 + tid;
            int n = idx >> 2, kg = idx & 3;
            *(bf16x8*)Bs[kg][n] =
                *(const bf16x8*)(Wt + (size_t)(bn + n) * K + k0 + kg * 8);
        }
        __syncthreads();
        bf16x8 af[MF], bfv[NF];
        #pragma unroll
        for (int i = 0; i < MF; ++i)
            af[i] = *(const bf16x8*)As[lane >> 4][wm * (BM / 2) + i * 16 + (lane & 15)];
        #pragma unroll
        for (int j = 0; j < NF; ++j)
            bfv[j] = *(const bf16x8*)Bs[lane >> 4][wn * (BN / 2) + j * 16 + (lane & 15)];
        #pragma unroll
        for (int i = 0; i < MF; ++i)
            #pragma unroll
            for (int j = 0; j < NF; ++j)
                acc[i][j] = __builtin_amdgcn_mfma_f32_16x16x32_bf16(
                    af[i], bfv[j], acc[i][j], 0, 0, 0);
        __syncthreads();
    }

    #pragma unroll
    for (int i = 0; i < MF; ++i) {
        const int row0 = bm + wm * (BM / 2) + i * 16 + (lane >> 4) * 4;
        #pragma unroll
        for (int j = 0; j < NF; ++j) {
            const int col = bn + wn * (BN / 2) + j * 16 + (lane & 15);
            #pragma unroll
            for (int r = 0; r < 4; ++r) {
                const int rr = row0 + r;
                float v = acc[i][j][r];
                if (EPI >= 1 && EPI <= 4) v += bias[col];
                if (EPI == 1) v += outf[(size_t)rr * Nn + col];
                if (EPI == 2) v = 0.5f * v * (1.0f + erff(v * 0.70710678118f));
                if (EPI == 3) v += extra[(size_t)(rr % NTOK) * Nn + col];
                if (EPI == 4) v = fmaxf(v, 0.f);
                if (EPI == 2 || EPI == 4) {
                    outb[(size_t)rr * Nn + col] = f2bf(v);
                } else if (EPI == 5) {
                    unsigned short hi = f2bf(v);
                    outb[(size_t)rr * Nn + col] = hi;
                    outb2[(size_t)rr * Nn + col] = f2bf(v - bf2f(hi));
                } else {
                    outf[(size_t)rr * Nn + col] = v;
                }
            }
        }
    }
}

// ---------------- LayerNorm over last dim (256), bf16 out -------------------
__global__ __launch_bounds__(256) void k_ln(const float* __restrict__ x,
                                            const float* __restrict__ g,
                                            const float* __restrict__ bb,
                                            unsigned short* __restrict__ y) {
    const int row = blockIdx.x, tid = threadIdx.x;
    float v = x[(size_t)row * DMODEL + tid];
    float s = v;
    #pragma unroll
    for (int off = 32; off; off >>= 1) s += __shfl_xor(s, off);
    __shared__ float ls[4], ls2[4];
    if ((tid & 63) == 0) ls[tid >> 6] = s;
    __syncthreads();
    float mu = (ls[0] + ls[1] + ls[2] + ls[3]) * (1.0f / DMODEL);
    float d = v - mu;
    float qq = d * d;
    #pragma unroll
    for (int off = 32; off; off >>= 1) qq += __shfl_xor(qq, off);
    if ((tid & 63) == 0) ls2[tid >> 6] = qq;
    __syncthreads();
    float var = (ls2[0] + ls2[1] + ls2[2] + ls2[3]) * (1.0f / DMODEL);
    y[(size_t)row * DMODEL + tid] = f2bf(d * rsqrtf(var + 1e-5f) * g[tid] + bb[tid]);
}

// ---------------- V transpose: qkv V-part -> vT[(b*4+h)*64 + d][576] --------
__global__ __launch_bounds__(256) void k_vT(const unsigned short* __restrict__ qhi,
                                            const unsigned short* __restrict__ qlo,
                                            unsigned short* __restrict__ vthi,
                                            unsigned short* __restrict__ vtlo) {
    __shared__ short tile[2][64][66];   // [hl][d][n], stride 66 (2-way-max reads)
    const int c = blockIdx.x, h = blockIdx.y, b = blockIdx.z;
    const int tid = threadIdx.x;
    #pragma unroll
    for (int rep = 0; rep < 4; ++rep) {
        int idx = rep * 256 + tid;
        int hl = idx >> 9, rem = idx & 511, n = rem >> 3, dg = rem & 7;
        const unsigned short* src = (hl ? qlo : qhi) +
            (size_t)(b * NTOK + c * CHUNK + n) * DQKV + 2 * DMODEL + h * DHEAD + dg * 8;
        bf16x8 v = *(const bf16x8*)src;
        #pragma unroll
        for (int e = 0; e < 8; ++e) tile[hl][dg * 8 + e][n] = v[e];
    }
    __syncthreads();
    #pragma unroll
    for (int rep = 0; rep < 4; ++rep) {
        int idx = rep * 256 + tid;
        int hl = idx >> 9, rem = idx & 511, d = rem >> 3, np = rem & 7;
        bf16x8 o;
        #pragma unroll
        for (int e = 0; e < 8; ++e) o[e] = tile[hl][d][np * 8 + e];
        *(bf16x8*)((hl ? vtlo : vthi) +
                   (size_t)((b * NHEAD + h) * DHEAD + d) * NTOK + c * CHUNK + np * 8) = o;
    }
}

// ---------------- chunk load/store helpers for k_attn ----------------
__device__ __forceinline__ void ldchunk(bf16x8 (&r)[4],
                                        const unsigned short* __restrict__ ph,
                                        const unsigned short* __restrict__ pl,
                                        size_t base, int rstride, int tid) {
    #pragma unroll
    for (int rep = 0; rep < 4; ++rep) {
        int idx = rep * 256 + tid;
        int hl = idx >> 9, rem = idx & 511, row = rem >> 3, dg = rem & 7;
        r[rep] = *(const bf16x8*)((hl ? pl : ph) + base + (size_t)row * rstride + dg * 8);
    }
}
__device__ __forceinline__ void stchunk(const bf16x8 (&r)[4],
                                        short (*kv)[CHUNK][72], int tid) {
    #pragma unroll
    for (int rep = 0; rep < 4; ++rep) {
        int idx = rep * 256 + tid;
        int hl = idx >> 9, rem = idx & 511, row = rem >> 3, dg = rem & 7;
        *(bf16x8*)&kv[hl][row][dg * 8] = r[rep];
    }
}

// ---------------- MFMA hybrid attention, 16 rows/block, 256 threads ---------
// Scores: 3-pass split-bf16 MFMA (Qh*Kh + Qh*Kl + Ql*Kh) == fp32 to ~1e-5.
// Top-16: value-max butterfly + ballot/ctz min-index (exact lax.top_k tie order).
// PV: 3-pass split-bf16 MFMA, V pre-transposed in global (linear LDS staging).
// Flat grid 2304 with XCD swizzle: all 36 blocks of one (b,h) on one XCD.
__global__ __launch_bounds__(256, 2) void k_attn(
    const unsigned short* __restrict__ qhi,
    const unsigned short* __restrict__ qlo,
    const unsigned short* __restrict__ vthi,
    const unsigned short* __restrict__ vtlo,
    const float* __restrict__ alpha_l,
    unsigned short* __restrict__ ao) {
    __shared__ __align__(16) short qsb[2][RPB][72];        // 4608 B
    __shared__ __align__(16) short kvb[2][2][CHUNK][72];   // [buf][hl] 36864 B
    __shared__ __align__(16) unsigned char ub[37376];      // sc f32[16][577] | P hi/lo [2][16][584]

    float* scp = (float*)ub;
    short* php = (short*)ub;

    const int tid = threadIdx.x;
    const int lane = tid & 63;
    const int ct = tid >> 6;                  // wave id = output col tile
    // XCD swizzle decode: bid%8 selects XCD; same (b,h) group stays on one XCD
    const int xr = blockIdx.x & 7, xq = blockIdx.x >> 3;
    const int g = xr + 8 * (xq / NBLK);       // group = b*4+h
    const int b = g >> 2, h = g & 3;
    const int i0 = (xq % NBLK) * RPB;
    const size_t qbase = (size_t)(b * NTOK) * DQKV;
    const size_t kb0 = qbase + DMODEL + h * DHEAD;          // K base (add c*CHUNK*DQKV)
    const size_t vb0 = (size_t)((b * NHEAD + h) * DHEAD) * NTOK; // vT base (add c*CHUNK)

    // ---- stage Q hi/lo ----
    {
        int hl = tid >> 7, rem = tid & 127, row = rem >> 3, dg = rem & 7;
        bf16x8 qv = *(const bf16x8*)((hl ? qlo : qhi) + qbase +
                                     (size_t)(i0 + row) * DQKV + h * DHEAD + dg * 8);
        *(bf16x8*)&qsb[hl][row][dg * 8] = qv;
    }

    bf16x8 rk[4];
    // ---- score phase: double-buffered chunks ----
    ldchunk(rk, qhi, qlo, kb0, DQKV, tid);
    stchunk(rk, kvb[0], tid);
    ldchunk(rk, qhi, qlo, kb0 + (size_t)CHUNK * DQKV, DQKV, tid);
    __syncthreads();
    for (int c = 0; c < NCHUNK; ++c) {
        if (c + 1 < NCHUNK) {
            stchunk(rk, kvb[(c + 1) & 1], tid);
            if (c + 2 < NCHUNK)
                ldchunk(rk, qhi, qlo, kb0 + (size_t)(c + 2) * CHUNK * DQKV, DQKV, tid);
        }
        f32x4 sD = (f32x4){0.f, 0.f, 0.f, 0.f};
        #pragma unroll
        for (int ksl = 0; ksl < 2; ++ksl) {
            const int ko = ksl * 32 + (lane >> 4) * 8;
            bf16x8 aqh = *(const bf16x8*)&qsb[0][lane & 15][ko];
            bf16x8 aql = *(const bf16x8*)&qsb[1][lane & 15][ko];
            bf16x8 bkh = *(const bf16x8*)&kvb[c & 1][0][ct * 16 + (lane & 15)][ko];
            bf16x8 bkl = *(const bf16x8*)&kvb[c & 1][1][ct * 16 + (lane & 15)][ko];
            sD = __builtin_amdgcn_mfma_f32_16x16x32_bf16(aqh, bkh, sD, 0, 0, 0);
            sD = __builtin_amdgcn_mfma_f32_16x16x32_bf16(aqh, bkl, sD, 0, 0, 0);
            sD = __builtin_amdgcn_mfma_f32_16x16x32_bf16(aql, bkh, sD, 0, 0, 0);
        }
        {
            const int row = (lane >> 4) * 4;
            const int col = c * CHUNK + ct * 16 + (lane & 15);
            #pragma unroll
            for (int r = 0; r < 4; ++r)
                scp[(row + r) * SCP + col] = sD[r] * 0.125f;
        }
        __syncthreads();
    }

    // ---- pull scores to regs (each wave: rows 4*ct .. 4*ct+3) ----
    float o_[4][9];
    const int wrow = ct * 4;
    #pragma unroll
    for (int rr = 0; rr < 4; ++rr)
        #pragma unroll
        for (int t = 0; t < 9; ++t)
            o_[rr][t] = scp[(wrow + rr) * SCP + t * 64 + lane];
    ldchunk(rk, vthi, vtlo, vb0, NTOK, tid);    // V chunk 0 in flight under topk
    __syncthreads();   // all score reads done -> P buffer may be written

    // ---- top-16 + combined softmax weights -> P hi/lo ----
    const float al = fminf(fmaxf(alpha_l[0], 0.f), 1.f);
    #pragma unroll
    for (int rr = 0; rr < 4; ++rr) {
        const int row = wrow + rr;
        float vv[9];
        #pragma unroll
        for (int t = 0; t < 9; ++t) vv[t] = o_[rr][t];
        unsigned mask = 0; float M = 0.f;
        for (int k = 0; k < TOPK; ++k) {
            float lm = vv[0];
            #pragma unroll
            for (int t = 1; t < 9; ++t) lm = fmaxf(lm, vv[t]);
            #pragma unroll
            for (int off = 1; off < 64; off <<= 1) lm = fmaxf(lm, __shfl_xor(lm, off));
            if (k == 0) M = lm;
            int jstar = 0;
            #pragma unroll
            for (int t = 0; t < 9; ++t) {
                unsigned long long bal = __ballot(vv[t] == lm);
                if (bal) { jstar = t * 64 + (int)__builtin_ctzll(bal); break; }
            }
            const int ts = jstar >> 6, ls = jstar & 63;
            if (lane == ls) {
                #pragma unroll
                for (int t = 0; t < 9; ++t)
                    if (t == ts) { vv[t] = -FLT_MAX; mask |= 1u << t; }
            }
        }
        float e[9], gsl = 0.f, ssl = 0.f;
        #pragma unroll
        for (int t = 0; t < 9; ++t) {
            e[t] = __expf(o_[rr][t] - M);
            gsl += e[t];
            if ((mask >> t) & 1u) ssl += e[t];
        }
        #pragma unroll
        for (int off = 1; off < 64; off <<= 1) {
            gsl += __shfl_xor(gsl, off);
            ssl += __shfl_xor(ssl, off);
        }
        const float ca = al / gsl, cs = (1.f - al) / ssl;
        #pragma unroll
        for (int t = 0; t < 9; ++t) {
            float wv = e[t] * (ca + (((mask >> t) & 1u) ? cs : 0.f));
            unsigned short hi = f2bf(wv);
            php[row * PP + t * 64 + lane] = hi;
            php[RPB * PP + row * PP + t * 64 + lane] = f2bf(wv - bf2f(hi));
        }
    }

    // ---- PV phase: double-buffered vT chunks ----
    stchunk(rk, kvb[0], tid);
    ldchunk(rk, vthi, vtlo, vb0 + CHUNK, NTOK, tid);
    __syncthreads();   // P writes + V buf0 visible
    f32x4 acc = (f32x4){0.f, 0.f, 0.f, 0.f};
    for (int c = 0; c < NCHUNK; ++c) {
        if (c + 1 < NCHUNK) {
            stchunk(rk, kvb[(c + 1) & 1], tid);
            if (c + 2 < NCHUNK)
                ldchunk(rk, vthi, vtlo, vb0 + (size_t)(c + 2) * CHUNK, NTOK, tid);
        }
        #pragma unroll
        for (int ksl = 0; ksl < 2; ++ksl) {
            const int ko = ksl * 32 + (lane >> 4) * 8;
            bf16x8 aph = *(const bf16x8*)&php[(lane & 15) * PP + c * CHUNK + ko];
            bf16x8 apl = *(const bf16x8*)&php[RPB * PP + (lane & 15) * PP + c * CHUNK + ko];
            bf16x8 bvh = *(const bf16x8*)&kvb[c & 1][0][ct * 16 + (lane & 15)][ko];
            bf16x8 bvl = *(const bf16x8*)&kvb[c & 1][1][ct * 16 + (lane & 15)][ko];
            acc = __builtin_amdgcn_mfma_f32_16x16x32_bf16(aph, bvh, acc, 0, 0, 0);
            acc = __builtin_amdgcn_mfma_f32_16x16x32_bf16(aph, bvl, acc, 0, 0, 0);
            acc = __builtin_amdgcn_mfma_f32_16x16x32_bf16(apl, bvh, acc, 0, 0, 0);
        }
        __syncthreads();
    }
    {
        const int qrow = i0 + (lane >> 4) * 4;
        const int dcol = h * DHEAD + ct * 16 + (lane & 15);
        #pragma unroll
        for (int r = 0; r < 4; ++r)
            ao[(size_t)(b * NTOK + qrow + r) * DMODEL + dcol] = f2bf(acc[r]);
    }
}

// ---------------- bilinear helpers (jax.image.resize half-pixel) ------------
__device__ __forceinline__ void bilin_axis(float sF, int H, int& i0, int& i1, float& f) {
    float fl = floorf(sF);
    f = sF - fl;
    int lo = (int)fl;
    i0 = lo < 0 ? 0 : (lo > H - 1 ? H - 1 : lo);
    int hi = lo + 1;
    i1 = hi < 0 ? 0 : (hi > H - 1 ? H - 1 : hi);
}

// NHWC bf16 2x bilinear upsample
__global__ __launch_bounds__(256) void k_up2n(const unsigned short* __restrict__ in,
                                              unsigned short* __restrict__ outp,
                                              int Hin, int C) {
    const int Ho = 2 * Hin;
    const int CG = C / 8;
    const int total = NB * Ho * Ho * CG;
    int t = blockIdx.x * 256 + threadIdx.x;
    if (t >= total) return;
    int cg = t % CG; int r = t / CG;
    int x = r % Ho; r /= Ho;
    int y = r % Ho; int b = r / Ho;
    int i0, i1, j0, j1; float fy, fx;
    bilin_axis(0.5f * y - 0.25f, Hin, i0, i1, fy);
    bilin_axis(0.5f * x - 0.25f, Hin, j0, j1, fx);
    const unsigned short* base = in + (size_t)b * Hin * Hin * C + cg * 8;
    const bf16x8 p00 = *(const bf16x8*)(base + (size_t)(i0 * Hin + j0) * C);
    const bf16x8 p01 = *(const bf16x8*)(base + (size_t)(i0 * Hin + j1) * C);
    const bf16x8 p10 = *(const bf16x8*)(base + (size_t)(i1 * Hin + j0) * C);
    const bf16x8 p11 = *(const bf16x8*)(base + (size_t)(i1 * Hin + j1) * C);
    bf16x8 o;
    #pragma unroll
    for (int e = 0; e < 8; ++e) {
        float v = (1.f - fy) * ((1.f - fx) * bf2f((unsigned short)p00[e]) + fx * bf2f((unsigned short)p01[e]))
                + fy        * ((1.f - fx) * bf2f((unsigned short)p10[e]) + fx * bf2f((unsigned short)p11[e]));
        o[e] = (short)f2bf(v);
    }
    *(bf16x8*)(outp + (size_t)t * 8) = o;
}

// ---------------- conv3: 1x1, 64->21, NHWC bf16 in -> NCHW f32 out ----------
__global__ __launch_bounds__(256) void k_conv3n(const unsigned short* __restrict__ in,
                                                const float* __restrict__ w,
                                                const float* __restrict__ bias,
                                                float* __restrict__ outp) {
    __shared__ float ws_[NCLS * 64];
    for (int i = threadIdx.x; i < NCLS * 64; i += 256) ws_[i] = w[i];
    __syncthreads();
    int t = blockIdx.x * 256 + threadIdx.x;
    if (t >= NB * 9216) return;
    int pix = t % 9216, b = t / 9216;
    float xv[64];
    const unsigned short* p = in + (size_t)t * 64;
    #pragma unroll
    for (int c = 0; c < 8; ++c) {
        bf16x8 v = *(const bf16x8*)(p + c * 8);
        #pragma unroll
        for (int e = 0; e < 8; ++e) xv[c * 8 + e] = bf2f((unsigned short)v[e]);
    }
    float* op = outp + (size_t)b * NCLS * 9216 + pix;
    #pragma unroll
    for (int o = 0; o < NCLS; ++o) {
        float acc = bias[o];
        #pragma unroll
        for (int ic = 0; ic < 64; ++ic) acc += ws_[o * 64 + ic] * xv[ic];
        op[(size_t)o * 9216] = acc;
    }
}

// ---------------- final resize 96 -> 384 (4x bilinear), f32 NCHW ------------
__global__ __launch_bounds__(256) void k_resize4(const float* __restrict__ in,
                                                 float* __restrict__ outp) {
    int t = blockIdx.x * 256 + threadIdx.x;
    if (t >= OUT_TOTAL) return;
    int x = t % IMGSZ; int r = t / IMGSZ; int y = r % IMGSZ; int bc = r / IMGSZ;
    int i0, i1, j0, j1; float fy, fx;
    bilin_axis(0.25f * y - 0.375f, 96, i0, i1, fy);
    bilin_axis(0.25f * x - 0.375f, 96, j0, j1, fx);
    const float* p = in + (size_t)bc * 9216;
    outp[t] = (1.f - fy) * ((1.f - fx) * p[i0 * 96 + j0] + fx * p[i0 * 96 + j1])
            + fy        * ((1.f - fx) * p[i1 * 96 + j0] + fx * p[i1 * 96 + j1]);
}

// ---------------- orchestration ----------------
extern "C" void kernel_launch(void* const* d_in, const int* in_sizes, int n_in,
                              void* d_out, int out_size, void* d_ws, size_t ws_size,
                              hipStream_t stream) {
    const float* img     = (const float*)d_in[0];
    const float* patch_w = (const float*)d_in[1];
    const float* patch_b = (const float*)d_in[2];
    const float* pos_emb = (const float*)d_in[3];
    const float* ln1_g   = (const float*)d_in[4];
    const float* ln1_b   = (const float*)d_in[5];
    const float* qkv_w   = (const float*)d_in[6];
    const float* out_w   = (const float*)d_in[7];
    const float* out_b   = (const float*)d_in[8];
    const float* alpha   = (const float*)d_in[9];
    const float* ln2_g   = (const float*)d_in[10];
    const float* ln2_b   = (const float*)d_in[11];
    const float* ff_w1   = (const float*)d_in[12];
    const float* ff_b1   = (const float*)d_in[13];
    const float* ff_w2   = (const float*)d_in[14];
    const float* ff_b2   = (const float*)d_in[15];
    const float* lnf_g   = (const float*)d_in[16];
    const float* lnf_b   = (const float*)d_in[17];
    const float* conv1_w = (const float*)d_in[18];
    const float* conv1_b = (const float*)d_in[19];
    const float* conv2_w = (const float*)d_in[20];
    const float* conv2_b = (const float*)d_in[21];
    const float* conv3_w = (const float*)d_in[22];
    const float* conv3_b = (const float*)d_in[23];

    // ---- workspace layout (~88 MB) ----
    float* x = (float*)d_ws;                                         // [9216][256] f32
    unsigned short* qkv_hi = (unsigned short*)(x + (size_t)NROWS * DMODEL); // [9216][768]
    unsigned short* qkv_lo = qkv_hi + (size_t)NROWS * DQKV;          // [9216][768]
    unsigned short* xn_bf  = qkv_lo + (size_t)NROWS * DQKV;          // [9216][256]
    unsigned short* ao_bf  = xn_bf + (size_t)NROWS * DMODEL;         // [9216][256]
    unsigned short* h_bf   = ao_bf + (size_t)NROWS * DMODEL;         // [9216][512]
    unsigned short* pA     = h_bf + (size_t)NROWS * DMLP;            // [9216][768]
    unsigned short* wts    = pA + (size_t)NROWS * NPD;
    unsigned short* pwt  = wts;                       // [256][768]
    unsigned short* qwt  = pwt  + 768 * 256;          // [6][768][256]
    unsigned short* owt  = qwt  + 6 * 768 * 256;      // [6][256][256]
    unsigned short* f1wt = owt  + 6 * 256 * 256;      // [6][512][256]
    unsigned short* f2wt = f1wt + 6 * 256 * 512;      // [6][256][512]
    unsigned short* c1wt = f2wt + 6 * 512 * 256;      // [128][9*256]
    unsigned short* c2wt = c1wt + 128 * 9 * 256;      // [64][9*128]
    unsigned short* vthi = c2wt + 64 * 9 * 128;       // [64*64][576]
    unsigned short* vtlo = vthi + (size_t)64 * 64 * NTOK;
    // conv-stage aliases (transformer buffers free by then)
    unsigned short* c1n = ao_bf;            // [16][24][24][128]
    unsigned short* u1n = h_bf;             // [16][48][48][128]
    unsigned short* c2n = xn_bf;            // [16][48][48][64]
    unsigned short* u2n = qkv_hi;           // [16][96][96][64] (spans hi+lo)
    float* c3 = (float*)pA;                 // [16][21][96][96] f32

    // ---- weight casts ----
    k_castT<<<dim3(768, 1), 256, 0, stream>>>(patch_w, pwt, NPD, DMODEL);
    k_castT<<<dim3(768, 6), 256, 0, stream>>>(qkv_w, qwt, DMODEL, DQKV);
    k_castT<<<dim3(256, 6), 256, 0, stream>>>(out_w, owt, DMODEL, DMODEL);
    k_castT<<<dim3(512, 6), 256, 0, stream>>>(ff_w1, f1wt, DMODEL, DMLP);
    k_castT<<<dim3(512, 6), 256, 0, stream>>>(ff_w2, f2wt, DMLP, DMODEL);
    k_castConv<256><<<1152, 256, 0, stream>>>(conv1_w, c1wt, 128);
    k_castConv<128><<<288, 256, 0, stream>>>(conv2_w, c2wt, 64);

    // ---- patch embed ----
    k_patchify<<<(NROWS * NPD + 255) / 256, 256, 0, stream>>>(img, pA);
    k_mm<128, 64, 3, 0><<<4 * 72, 256, 0, stream>>>(
        pA, pwt, patch_b, pos_emb, x, nullptr, nullptr, NROWS, DMODEL, NPD, 0, 0, 4, 72);

    // ---- transformer layers ----
    for (int l = 0; l < DEPTH; ++l) {
        k_ln<<<NROWS, 256, 0, stream>>>(x, ln1_g + l * DMODEL, ln1_b + l * DMODEL, xn_bf);
        k_mm<128, 128, 5, 0><<<6 * 72, 256, 0, stream>>>(
            xn_bf, qwt + (size_t)l * DQKV * DMODEL, nullptr, nullptr,
            nullptr, qkv_hi, qkv_lo, NROWS, DQKV, DMODEL, 0, 0, 6, 72);
        k_vT<<<dim3(NCHUNK, NHEAD, NB), 256, 0, stream>>>(qkv_hi, qkv_lo, vthi, vtlo);
        k_attn<<<NBLK * NHEAD * NB, 256, 0, stream>>>(
            qkv_hi, qkv_lo, vthi, vtlo, alpha + l, ao_bf);
        k_mm<128, 64, 1, 0><<<4 * 72, 256, 0, stream>>>(
            ao_bf, owt + (size_t)l * DMODEL * DMODEL, out_b + l * DMODEL, nullptr,
            x, nullptr, nullptr, NROWS, DMODEL, DMODEL, 0, 0, 4, 72);
        k_ln<<<NROWS, 256, 0, stream>>>(x, ln2_g + l * DMODEL, ln2_b + l * DMODEL, xn_bf);
        k_mm<128, 128, 2, 0><<<4 * 72, 256, 0, stream>>>(
            xn_bf, f1wt + (size_t)l * DMLP * DMODEL, ff_b1 + l * DMLP, nullptr,
            nullptr, h_bf, nullptr, NROWS, DMLP, DMODEL, 0, 0, 4, 72);
        k_mm<128, 64, 1, 0><<<4 * 72, 256, 0, stream>>>(
            h_bf, f2wt + (size_t)l * DMODEL * DMLP, ff_b2 + l * DMODEL, nullptr,
            x, nullptr, nullptr, NROWS, DMODEL, DMLP, 0, 0, 4, 72);
    }

    // ---- head ----
    k_ln<<<NROWS, 256, 0, stream>>>(x, lnf_g, lnf_b, xn_bf);
    // conv1: implicit GEMM over NHWC tokens [16][24][24][256]
    k_mm<64, 128, 4, 256><<<1 * 144, 256, 0, stream>>>(
        xn_bf, c1wt, conv1_b, nullptr, nullptr, c1n, nullptr, NROWS, 128, 9 * 256, 24, 24, 1, 144);
    k_up2n<<<(NB * 48 * 48 * 16 + 255) / 256, 256, 0, stream>>>(c1n, u1n, 24, 128);
    // conv2: implicit GEMM over NHWC [16][48][48][128]
    k_mm<128, 64, 4, 128><<<1 * 288, 256, 0, stream>>>(
        u1n, c2wt, conv2_b, nullptr, nullptr, c2n, nullptr, NB * 48 * 48, 64, 9 * 128, 48, 48, 1, 288);
    k_up2n<<<(NB * 96 * 96 * 8 + 255) / 256, 256, 0, stream>>>(c2n, u2n, 48, 64);
    k_conv3n<<<(NB * 9216 + 255) / 256, 256, 0, stream>>>(u2n, conv3_w, conv3_b, c3);
    k_resize4<<<(OUT_TOTAL + 255) / 256, 256, 0, stream>>>(c3, (float*)d_out);
}

// Round 7
// 1500.355 us; speedup vs baseline: 8.1660x; 1.4009x over previous
//
#include <hip/hip_runtime.h>
#include <cfloat>
#include <cmath>

// ---------------- problem constants ----------------
constexpr int NB    = 16;    // batch
constexpr int IMGSZ = 384;
constexpr int PSZ   = 16;
constexpr int NCH   = 3;
constexpr int DMODEL= 256;
constexpr int DEPTH = 6;
constexpr int NHEAD = 4;
constexpr int DHEAD = 64;
constexpr int DQKV  = 768;   // 3*INNER
constexpr int DMLP  = 512;
constexpr int NCLS  = 21;
constexpr int HPATCH= 24;    // IMG/P
constexpr int NTOK  = 576;   // HP*HP
constexpr int NPD   = 768;   // C*P*P
constexpr int TOPK  = 16;
constexpr int NROWS = NB * NTOK;          // 9216
constexpr int OUT_TOTAL = NB * NCLS * IMGSZ * IMGSZ; // 49545216

// attention tiling
constexpr int RPB    = 16;           // query rows per block
constexpr int NBLK   = NTOK / RPB;   // 36 blocks per (b,h)
constexpr int CHUNK  = 64;           // key/value chunk
constexpr int NCHUNK = NTOK / CHUNK; // 9
constexpr int SCP    = 577;          // score row stride (f32)

typedef __attribute__((ext_vector_type(8))) short bf16x8;
typedef __attribute__((ext_vector_type(4))) float f32x4;

__device__ __forceinline__ unsigned short f2bf(float f) {
    unsigned u = __builtin_bit_cast(unsigned, f);
    unsigned r = (u + 0x7FFFu + ((u >> 16) & 1u)) >> 16;
    return (unsigned short)r;
}
__device__ __forceinline__ float bf2f(unsigned short h) {
    unsigned u = ((unsigned)h) << 16;
    return __builtin_bit_cast(float, u);
}

// ---------------- weight cast+transpose: W[L][K][N] f32 -> Wt[L][N][K] bf16 --
__global__ __launch_bounds__(256) void k_castT(const float* __restrict__ src,
                                               unsigned short* __restrict__ dst,
                                               int K, int N) {
    int t = blockIdx.x * 256 + threadIdx.x;
    if (t >= K * N) return;
    size_t base = (size_t)blockIdx.y * K * N;
    int n = t / K, k = t - n * K;
    dst[base + t] = f2bf(src[base + (size_t)k * N + n]);
}

// conv w [OC][IC][3][3] f32 -> [OC][9][IC] bf16 (tap-major K)
template <int IC>
__global__ __launch_bounds__(256) void k_castConv(const float* __restrict__ src,
                                                  unsigned short* __restrict__ dst,
                                                  int OC) {
    int t = blockIdx.x * 256 + threadIdx.x;
    if (t >= OC * 9 * IC) return;
    int oc = t / (9 * IC);
    int r = t - oc * 9 * IC;
    int tap = r / IC, ic = r - tap * IC;
    dst[t] = f2bf(src[((size_t)(oc * IC + ic)) * 9 + tap]);
}

// ---------------- patchify: img[B,3,384,384] -> A[9216,768] bf16 ------------
__global__ __launch_bounds__(256) void k_patchify(const float* __restrict__ img,
                                                  unsigned short* __restrict__ A) {
    int t = blockIdx.x * 256 + threadIdx.x;
    if (t >= NROWS * NPD) return;
    int r  = t / NPD, pd = t - r * NPD;
    int b  = r / NTOK, n = r - b * NTOK;
    int hy = n / HPATCH, hx = n - hy * HPATCH;
    int c  = pd % NCH;  int q = pd / NCH;
    int p2 = q % PSZ;   int p1 = q / PSZ;
    A[t] = f2bf(img[(((size_t)(b * NCH + c)) * IMGSZ + hy * PSZ + p1) * IMGSZ + hx * PSZ + p2]);
}

// ---------------- unified bf16 MFMA GEMM / implicit conv --------------------
// out[M,N] = A[M,K](bf16) @ Wt[N,K]^T(bf16), fp32 accumulate.
// EPI: 0 none->f32 | 1 bias+residual->f32 | 2 bias+gelu->bf16
//      3 bias+posemb->f32 | 4 bias+relu->bf16 | 5 none->bf16 hi/lo pair
// CIN>0: gather A from NHWC [NB][H][W][CIN] with 3x3 taps (K = 9*CIN, tap-major)
// Flat grid of gxd*gyd blocks; XCD-aware swizzle keyed on M-tile (gyd%8==0).
template <int BM, int BN, int EPI, int CIN>
__global__ __launch_bounds__(256) void k_mm(
    const unsigned short* __restrict__ Abf,
    const unsigned short* __restrict__ Wt,
    const float* __restrict__ bias,
    const float* __restrict__ extra,
    float* __restrict__ outf,
    unsigned short* __restrict__ outb,
    unsigned short* __restrict__ outb2,
    int M, int Nn, int K, int H, int Wd, int gxd, int gyd)
{
    constexpr int MF = BM / 32;
    constexpr int NF = BN / 32;
    constexpr bool GATHER = (CIN > 0);
    constexpr int AREP = BM * 4 / 256;
    constexpr int BREP = BN * 4 / 256;
    __shared__ __align__(16) short As[4][BM][8];
    __shared__ __align__(16) short Bs[4][BN][8];
    const int tid = threadIdx.x;
    // XCD swizzle: all blocks sharing an M-tile window land on one XCD
    const int p = blockIdx.x;
    const int xr = p & 7, xq = p >> 3;
    const int bm = (xr * (gyd >> 3) + xq / gxd) * BM;
    const int bn = (xq % gxd) * BN;
    const int lane = tid & 63, wid = tid >> 6;
    const int wm = wid >> 1, wn = wid & 1;

    int pb_[AREP], py_[AREP], px_[AREP];
    if (GATHER) {
        #pragma unroll
        for (int rep = 0; rep < AREP; ++rep) {
            int idx = rep * 256 + tid;
            int m = idx >> 2;
            int pix = bm + m;
            px_[rep] = pix % Wd;
            int r = pix / Wd;
            py_[rep] = r % H;
            pb_[rep] = r / H;
        }
    }

    f32x4 acc[MF][NF];
    #pragma unroll
    for (int i = 0; i < MF; ++i)
        #pragma unroll
        for (int j = 0; j < NF; ++j)
            acc[i][j] = (f32x4){0.f, 0.f, 0.f, 0.f};

    for (int k0 = 0; k0 < K; k0 += 32) {
        #pragma unroll
        for (int rep = 0; rep < AREP; ++rep) {
            int idx = rep * 256 + tid;
            int m = idx >> 2, kg = idx & 3;
            if (!GATHER) {
                *(bf16x8*)As[kg][m] =
                    *(const bf16x8*)(Abf + (size_t)(bm + m) * K + k0 + kg * 8);
            } else {
                int k = k0 + kg * 8;
                int tap = k / CIN;
                int ic = k - tap * CIN;
                int dy = tap / 3 - 1, dx = tap % 3 - 1;
                int yy = py_[rep] + dy, xx = px_[rep] + dx;
                bf16x8 v = (bf16x8){0, 0, 0, 0, 0, 0, 0, 0};
                if ((unsigned)yy < (unsigned)H && (unsigned)xx < (unsigned)Wd)
                    v = *(const bf16x8*)(Abf +
                        ((size_t)((pb_[rep] * H + yy) * Wd + xx)) * CIN + ic);
                *(bf16x8*)As[kg][m] = v;
            }
        }
        #pragma unroll
        for (int rep = 0; rep < BREP; ++rep) {
            int idx = rep * 256 + tid;
            int n = idx >> 2, kg = idx & 3;
            *(bf16x8*)Bs[kg][n] =
                *(const bf16x8*)(Wt + (size_t)(bn + n) * K + k0 + kg * 8);
        }
        __syncthreads();
        bf16x8 af[MF], bfv[NF];
        #pragma unroll
        for (int i = 0; i < MF; ++i)
            af[i] = *(const bf16x8*)As[lane >> 4][wm * (BM / 2) + i * 16 + (lane & 15)];
        #pragma unroll
        for (int j = 0; j < NF; ++j)
            bfv[j] = *(const bf16x8*)Bs[lane >> 4][wn * (BN / 2) + j * 16 + (lane & 15)];
        #pragma unroll
        for (int i = 0; i < MF; ++i)
            #pragma unroll
            for (int j = 0; j < NF; ++j)
                acc[i][j] = __builtin_amdgcn_mfma_f32_16x16x32_bf16(
                    af[i], bfv[j], acc[i][j], 0, 0, 0);
        __syncthreads();
    }

    #pragma unroll
    for (int i = 0; i < MF; ++i) {
        const int row0 = bm + wm * (BM / 2) + i * 16 + (lane >> 4) * 4;
        #pragma unroll
        for (int j = 0; j < NF; ++j) {
            const int col = bn + wn * (BN / 2) + j * 16 + (lane & 15);
            #pragma unroll
            for (int r = 0; r < 4; ++r) {
                const int rr = row0 + r;
                float v = acc[i][j][r];
                if (EPI >= 1 && EPI <= 4) v += bias[col];
                if (EPI == 1) v += outf[(size_t)rr * Nn + col];
                if (EPI == 2) v = 0.5f * v * (1.0f + erff(v * 0.70710678118f));
                if (EPI == 3) v += extra[(size_t)(rr % NTOK) * Nn + col];
                if (EPI == 4) v = fmaxf(v, 0.f);
                if (EPI == 2 || EPI == 4) {
                    outb[(size_t)rr * Nn + col] = f2bf(v);
                } else if (EPI == 5) {
                    unsigned short hi = f2bf(v);
                    outb[(size_t)rr * Nn + col] = hi;
                    outb2[(size_t)rr * Nn + col] = f2bf(v - bf2f(hi));
                } else {
                    outf[(size_t)rr * Nn + col] = v;
                }
            }
        }
    }
}

// ---------------- LayerNorm over last dim (256), bf16 out -------------------
__global__ __launch_bounds__(256) void k_ln(const float* __restrict__ x,
                                            const float* __restrict__ g,
                                            const float* __restrict__ bb,
                                            unsigned short* __restrict__ y) {
    const int row = blockIdx.x, tid = threadIdx.x;
    float v = x[(size_t)row * DMODEL + tid];
    float s = v;
    #pragma unroll
    for (int off = 32; off; off >>= 1) s += __shfl_xor(s, off);
    __shared__ float ls[4], ls2[4];
    if ((tid & 63) == 0) ls[tid >> 6] = s;
    __syncthreads();
    float mu = (ls[0] + ls[1] + ls[2] + ls[3]) * (1.0f / DMODEL);
    float d = v - mu;
    float qq = d * d;
    #pragma unroll
    for (int off = 32; off; off >>= 1) qq += __shfl_xor(qq, off);
    if ((tid & 63) == 0) ls2[tid >> 6] = qq;
    __syncthreads();
    float var = (ls2[0] + ls2[1] + ls2[2] + ls2[3]) * (1.0f / DMODEL);
    y[(size_t)row * DMODEL + tid] = f2bf(d * rsqrtf(var + 1e-5f) * g[tid] + bb[tid]);
}

// ---------------- V transpose: qkv V-part -> vT[(b*4+h)*64 + d][576] --------
__global__ __launch_bounds__(256) void k_vT(const unsigned short* __restrict__ qhi,
                                            const unsigned short* __restrict__ qlo,
                                            unsigned short* __restrict__ vthi,
                                            unsigned short* __restrict__ vtlo) {
    __shared__ short tile[2][64][66];   // [hl][d][n], stride 66 (2-way-max reads)
    const int c = blockIdx.x, h = blockIdx.y, b = blockIdx.z;
    const int tid = threadIdx.x;
    #pragma unroll
    for (int rep = 0; rep < 4; ++rep) {
        int idx = rep * 256 + tid;
        int hl = idx >> 9, rem = idx & 511, n = rem >> 3, dg = rem & 7;
        const unsigned short* src = (hl ? qlo : qhi) +
            (size_t)(b * NTOK + c * CHUNK + n) * DQKV + 2 * DMODEL + h * DHEAD + dg * 8;
        bf16x8 v = *(const bf16x8*)src;
        #pragma unroll
        for (int e = 0; e < 8; ++e) tile[hl][dg * 8 + e][n] = v[e];
    }
    __syncthreads();
    #pragma unroll
    for (int rep = 0; rep < 4; ++rep) {
        int idx = rep * 256 + tid;
        int hl = idx >> 9, rem = idx & 511, d = rem >> 3, np = rem & 7;
        bf16x8 o;
        #pragma unroll
        for (int e = 0; e < 8; ++e) o[e] = tile[hl][d][np * 8 + e];
        *(bf16x8*)((hl ? vtlo : vthi) +
                   (size_t)((b * NHEAD + h) * DHEAD + d) * NTOK + c * CHUNK + np * 8) = o;
    }
}

// ---------------- wave-private hi/lo fragment quad (2 ksl x hi/lo) ----------
struct KF { bf16x8 h0, h1, l0, l1; };
__device__ __forceinline__ KF ldkf(const unsigned short* __restrict__ hi,
                                   const unsigned short* __restrict__ lo,
                                   size_t off) {
    KF f;
    f.h0 = *(const bf16x8*)(hi + off);
    f.h1 = *(const bf16x8*)(hi + off + 32);
    f.l0 = *(const bf16x8*)(lo + off);
    f.l1 = *(const bf16x8*)(lo + off + 32);
    return f;
}

// ---------------- MFMA hybrid attention, 16 rows/block, 256 threads ---------
// K/V^T fragments are wave-private rows -> loaded DIRECTLY global->VGPR
// (no LDS staging, no staging barriers), prefetched one chunk ahead.
// LDS: score relay [16][577] f32, union-overlaid with JIT per-chunk P hi/lo
// slices [2buf][2hl][16][72] bf16. Top-k iteration-outer/row-inner so the
// 4 rows' shuffle chains pipeline. Numerics identical to previous round.
__global__ __launch_bounds__(256, 4) void k_attn(
    const unsigned short* __restrict__ qhi,
    const unsigned short* __restrict__ qlo,
    const unsigned short* __restrict__ vthi,
    const unsigned short* __restrict__ vtlo,
    const float* __restrict__ alpha_l,
    unsigned short* __restrict__ ao) {
    __shared__ __align__(16) unsigned char ub[16 * SCP * 4];  // 36928 B
    float* scp = (float*)ub;                 // [16][577] f32
    short* pj  = (short*)ub;                 // [2buf][2hl][16][72] bf16 (overlay)

    const int tid = threadIdx.x;
    const int lane = tid & 63;
    const int ct = tid >> 6;                 // wave id = column tile
    const int l15 = lane & 15, lg = lane >> 4;
    // XCD swizzle decode: bid%8 selects XCD; same (b,h) group stays on one XCD
    const int xr = blockIdx.x & 7, xq = blockIdx.x >> 3;
    const int g = xr + 8 * (xq / NBLK);      // group = b*4+h
    const int b = g >> 2, h = g & 3;
    const int i0 = (xq % NBLK) * RPB;

    // ---- Q fragments (A operand), wave-uniform: rows i0+l15 ----
    bf16x8 aqh0, aqh1, aql0, aql1;
    {
        const size_t qoff = (size_t)(b * NTOK + i0 + l15) * DQKV + h * DHEAD + lg * 8;
        aqh0 = *(const bf16x8*)(qhi + qoff);
        aqh1 = *(const bf16x8*)(qhi + qoff + 32);
        aql0 = *(const bf16x8*)(qlo + qoff);
        aql1 = *(const bf16x8*)(qlo + qoff + 32);
    }

    // ---- score phase: direct-global K frags, prefetch 1 chunk, no barriers --
    const size_t kRow = (size_t)(b * NTOK + ct * 16 + l15) * DQKV + DMODEL + h * DHEAD + lg * 8;
    KF kc = ldkf(qhi, qlo, kRow);
    #pragma unroll
    for (int c = 0; c < NCHUNK; ++c) {
        KF kn;
        if (c + 1 < NCHUNK)
            kn = ldkf(qhi, qlo, kRow + (size_t)(c + 1) * CHUNK * DQKV);
        f32x4 sD = (f32x4){0.f, 0.f, 0.f, 0.f};
        sD = __builtin_amdgcn_mfma_f32_16x16x32_bf16(aqh0, kc.h0, sD, 0, 0, 0);
        sD = __builtin_amdgcn_mfma_f32_16x16x32_bf16(aqh0, kc.l0, sD, 0, 0, 0);
        sD = __builtin_amdgcn_mfma_f32_16x16x32_bf16(aql0, kc.h0, sD, 0, 0, 0);
        sD = __builtin_amdgcn_mfma_f32_16x16x32_bf16(aqh1, kc.h1, sD, 0, 0, 0);
        sD = __builtin_amdgcn_mfma_f32_16x16x32_bf16(aqh1, kc.l1, sD, 0, 0, 0);
        sD = __builtin_amdgcn_mfma_f32_16x16x32_bf16(aql1, kc.h1, sD, 0, 0, 0);
        const int col = c * CHUNK + ct * 16 + l15;
        #pragma unroll
        for (int r = 0; r < 4; ++r)
            scp[(lg * 4 + r) * SCP + col] = sD[r] * 0.125f;
        if (c + 1 < NCHUNK) kc = kn;
    }
    __syncthreads();   // all scores written

    // ---- pull scores to regs (wave ct owns rows 4ct..4ct+3) ----
    float o_[4][9];
    const int wrow = ct * 4;
    #pragma unroll
    for (int rr = 0; rr < 4; ++rr)
        #pragma unroll
        for (int t = 0; t < 9; ++t)
            o_[rr][t] = scp[(wrow + rr) * SCP + t * 64 + lane];
    __syncthreads();   // score reads done -> P overlay region may be written

    // ---- top-16: iteration-outer, 4 rows interleaved (identical semantics) --
    unsigned msk[4] = {0u, 0u, 0u, 0u};
    float M_[4];
    for (int k = 0; k < TOPK; ++k) {
        float lm[4];
        #pragma unroll
        for (int rr = 0; rr < 4; ++rr) {
            float m0 = -FLT_MAX;
            #pragma unroll
            for (int t = 0; t < 9; ++t) {
                float v = ((msk[rr] >> t) & 1u) ? -FLT_MAX : o_[rr][t];
                m0 = fmaxf(m0, v);
            }
            lm[rr] = m0;
        }
        #pragma unroll
        for (int off = 1; off < 64; off <<= 1) {
            #pragma unroll
            for (int rr = 0; rr < 4; ++rr)
                lm[rr] = fmaxf(lm[rr], __shfl_xor(lm[rr], off));
        }
        if (k == 0) {
            #pragma unroll
            for (int rr = 0; rr < 4; ++rr) M_[rr] = lm[rr];
        }
        #pragma unroll
        for (int rr = 0; rr < 4; ++rr) {
            int js = -1;
            #pragma unroll
            for (int t = 0; t < 9; ++t) {
                if (js < 0) {   // wave-uniform guard
                    unsigned long long bal =
                        __ballot((((msk[rr] >> t) & 1u) == 0u) && (o_[rr][t] == lm[rr]));
                    if (bal) js = t * 64 + (int)__builtin_ctzll(bal);
                }
            }
            if ((js & 63) == lane) msk[rr] |= 1u << (js >> 6);
        }
    }

    // ---- softmax denominators + coefficients ----
    const float al = fminf(fmaxf(alpha_l[0], 0.f), 1.f);
    float gs[4], ss[4];
    #pragma unroll
    for (int rr = 0; rr < 4; ++rr) {
        float g_ = 0.f, s_ = 0.f;
        #pragma unroll
        for (int t = 0; t < 9; ++t) {
            float e = __expf(o_[rr][t] - M_[rr]);
            g_ += e;
            if ((msk[rr] >> t) & 1u) s_ += e;
        }
        gs[rr] = g_; ss[rr] = s_;
    }
    #pragma unroll
    for (int off = 1; off < 64; off <<= 1) {
        #pragma unroll
        for (int rr = 0; rr < 4; ++rr) {
            gs[rr] += __shfl_xor(gs[rr], off);
            ss[rr] += __shfl_xor(ss[rr], off);
        }
    }
    float ca[4], cs[4];
    #pragma unroll
    for (int rr = 0; rr < 4; ++rr) {
        ca[rr] = al / gs[rr];
        cs[rr] = (1.f - al) / ss[rr];
    }

    // ---- PV phase: JIT P slices in LDS dbuf, direct-global V^T frags --------
    const size_t vRow = (size_t)((b * NHEAD + h) * DHEAD + ct * 16 + l15) * NTOK + lg * 8;
    KF vc = ldkf(vthi, vtlo, vRow);
    f32x4 acc = (f32x4){0.f, 0.f, 0.f, 0.f};
    #pragma unroll
    for (int c = 0; c < NCHUNK; ++c) {
        KF vn;
        if (c + 1 < NCHUNK)
            vn = ldkf(vthi, vtlo, vRow + (size_t)(c + 1) * CHUNK);
        // write this chunk's P slice (hi/lo) for our 4 rows
        short* pb = pj + (c & 1) * (2 * 16 * 72);
        #pragma unroll
        for (int rr = 0; rr < 4; ++rr) {
            float e = __expf(o_[rr][c] - M_[rr]);
            float wv = e * (ca[rr] + (((msk[rr] >> c) & 1u) ? cs[rr] : 0.f));
            unsigned short hi = f2bf(wv);
            pb[(wrow + rr) * 72 + lane] = (short)hi;
            pb[16 * 72 + (wrow + rr) * 72 + lane] = (short)f2bf(wv - bf2f(hi));
        }
        __syncthreads();   // all rows' P slice visible
        const short* pr = pb + l15 * 72 + lg * 8;
        bf16x8 ah0 = *(const bf16x8*)(pr);
        bf16x8 ah1 = *(const bf16x8*)(pr + 32);
        bf16x8 al0 = *(const bf16x8*)(pr + 16 * 72);
        bf16x8 al1 = *(const bf16x8*)(pr + 16 * 72 + 32);
        acc = __builtin_amdgcn_mfma_f32_16x16x32_bf16(ah0, vc.h0, acc, 0, 0, 0);
        acc = __builtin_amdgcn_mfma_f32_16x16x32_bf16(ah0, vc.l0, acc, 0, 0, 0);
        acc = __builtin_amdgcn_mfma_f32_16x16x32_bf16(al0, vc.h0, acc, 0, 0, 0);
        acc = __builtin_amdgcn_mfma_f32_16x16x32_bf16(ah1, vc.h1, acc, 0, 0, 0);
        acc = __builtin_amdgcn_mfma_f32_16x16x32_bf16(ah1, vc.l1, acc, 0, 0, 0);
        acc = __builtin_amdgcn_mfma_f32_16x16x32_bf16(al1, vc.h1, acc, 0, 0, 0);
        if (c + 1 < NCHUNK) vc = vn;
    }
    {
        const int qrow = i0 + lg * 4;
        const int dcol = h * DHEAD + ct * 16 + l15;
        #pragma unroll
        for (int r = 0; r < 4; ++r)
            ao[(size_t)(b * NTOK + qrow + r) * DMODEL + dcol] = f2bf(acc[r]);
    }
}

// ---------------- bilinear helpers (jax.image.resize half-pixel) ------------
__device__ __forceinline__ void bilin_axis(float sF, int H, int& i0, int& i1, float& f) {
    float fl = floorf(sF);
    f = sF - fl;
    int lo = (int)fl;
    i0 = lo < 0 ? 0 : (lo > H - 1 ? H - 1 : lo);
    int hi = lo + 1;
    i1 = hi < 0 ? 0 : (hi > H - 1 ? H - 1 : hi);
}

// NHWC bf16 2x bilinear upsample
__global__ __launch_bounds__(256) void k_up2n(const unsigned short* __restrict__ in,
                                              unsigned short* __restrict__ outp,
                                              int Hin, int C) {
    const int Ho = 2 * Hin;
    const int CG = C / 8;
    const int total = NB * Ho * Ho * CG;
    int t = blockIdx.x * 256 + threadIdx.x;
    if (t >= total) return;
    int cg = t % CG; int r = t / CG;
    int x = r % Ho; r /= Ho;
    int y = r % Ho; int b = r / Ho;
    int i0, i1, j0, j1; float fy, fx;
    bilin_axis(0.5f * y - 0.25f, Hin, i0, i1, fy);
    bilin_axis(0.5f * x - 0.25f, Hin, j0, j1, fx);
    const unsigned short* base = in + (size_t)b * Hin * Hin * C + cg * 8;
    const bf16x8 p00 = *(const bf16x8*)(base + (size_t)(i0 * Hin + j0) * C);
    const bf16x8 p01 = *(const bf16x8*)(base + (size_t)(i0 * Hin + j1) * C);
    const bf16x8 p10 = *(const bf16x8*)(base + (size_t)(i1 * Hin + j0) * C);
    const bf16x8 p11 = *(const bf16x8*)(base + (size_t)(i1 * Hin + j1) * C);
    bf16x8 o;
    #pragma unroll
    for (int e = 0; e < 8; ++e) {
        float v = (1.f - fy) * ((1.f - fx) * bf2f((unsigned short)p00[e]) + fx * bf2f((unsigned short)p01[e]))
                + fy        * ((1.f - fx) * bf2f((unsigned short)p10[e]) + fx * bf2f((unsigned short)p11[e]));
        o[e] = (short)f2bf(v);
    }
    *(bf16x8*)(outp + (size_t)t * 8) = o;
}

// ---------------- conv3: 1x1, 64->21, NHWC bf16 in -> NCHW f32 out ----------
__global__ __launch_bounds__(256) void k_conv3n(const unsigned short* __restrict__ in,
                                                const float* __restrict__ w,
                                                const float* __restrict__ bias,
                                                float* __restrict__ outp) {
    __shared__ float ws_[NCLS * 64];
    for (int i = threadIdx.x; i < NCLS * 64; i += 256) ws_[i] = w[i];
    __syncthreads();
    int t = blockIdx.x * 256 + threadIdx.x;
    if (t >= NB * 9216) return;
    int pix = t % 9216, b = t / 9216;
    float xv[64];
    const unsigned short* p = in + (size_t)t * 64;
    #pragma unroll
    for (int c = 0; c < 8; ++c) {
        bf16x8 v = *(const bf16x8*)(p + c * 8);
        #pragma unroll
        for (int e = 0; e < 8; ++e) xv[c * 8 + e] = bf2f((unsigned short)v[e]);
    }
    float* op = outp + (size_t)b * NCLS * 9216 + pix;
    #pragma unroll
    for (int o = 0; o < NCLS; ++o) {
        float acc = bias[o];
        #pragma unroll
        for (int ic = 0; ic < 64; ++ic) acc += ws_[o * 64 + ic] * xv[ic];
        op[(size_t)o * 9216] = acc;
    }
}

// ---------------- final resize 96 -> 384 (4x bilinear), f32 NCHW ------------
__global__ __launch_bounds__(256) void k_resize4(const float* __restrict__ in,
                                                 float* __restrict__ outp) {
    int t = blockIdx.x * 256 + threadIdx.x;
    if (t >= OUT_TOTAL) return;
    int x = t % IMGSZ; int r = t / IMGSZ; int y = r % IMGSZ; int bc = r / IMGSZ;
    int i0, i1, j0, j1; float fy, fx;
    bilin_axis(0.25f * y - 0.375f, 96, i0, i1, fy);
    bilin_axis(0.25f * x - 0.375f, 96, j0, j1, fx);
    const float* p = in + (size_t)bc * 9216;
    outp[t] = (1.f - fy) * ((1.f - fx) * p[i0 * 96 + j0] + fx * p[i0 * 96 + j1])
            + fy        * ((1.f - fx) * p[i1 * 96 + j0] + fx * p[i1 * 96 + j1]);
}

// ---------------- orchestration ----------------
extern "C" void kernel_launch(void* const* d_in, const int* in_sizes, int n_in,
                              void* d_out, int out_size, void* d_ws, size_t ws_size,
                              hipStream_t stream) {
    const float* img     = (const float*)d_in[0];
    const float* patch_w = (const float*)d_in[1];
    const float* patch_b = (const float*)d_in[2];
    const float* pos_emb = (const float*)d_in[3];
    const float* ln1_g   = (const float*)d_in[4];
    const float* ln1_b   = (const float*)d_in[5];
    const float* qkv_w   = (const float*)d_in[6];
    const float* out_w   = (const float*)d_in[7];
    const float* out_b   = (const float*)d_in[8];
    const float* alpha   = (const float*)d_in[9];
    const float* ln2_g   = (const float*)d_in[10];
    const float* ln2_b   = (const float*)d_in[11];
    const float* ff_w1   = (const float*)d_in[12];
    const float* ff_b1   = (const float*)d_in[13];
    const float* ff_w2   = (const float*)d_in[14];
    const float* ff_b2   = (const float*)d_in[15];
    const float* lnf_g   = (const float*)d_in[16];
    const float* lnf_b   = (const float*)d_in[17];
    const float* conv1_w = (const float*)d_in[18];
    const float* conv1_b = (const float*)d_in[19];
    const float* conv2_w = (const float*)d_in[20];
    const float* conv2_b = (const float*)d_in[21];
    const float* conv3_w = (const float*)d_in[22];
    const float* conv3_b = (const float*)d_in[23];

    // ---- workspace layout (~88 MB) ----
    float* x = (float*)d_ws;                                         // [9216][256] f32
    unsigned short* qkv_hi = (unsigned short*)(x + (size_t)NROWS * DMODEL); // [9216][768]
    unsigned short* qkv_lo = qkv_hi + (size_t)NROWS * DQKV;          // [9216][768]
    unsigned short* xn_bf  = qkv_lo + (size_t)NROWS * DQKV;          // [9216][256]
    unsigned short* ao_bf  = xn_bf + (size_t)NROWS * DMODEL;         // [9216][256]
    unsigned short* h_bf   = ao_bf + (size_t)NROWS * DMODEL;         // [9216][512]
    unsigned short* pA     = h_bf + (size_t)NROWS * DMLP;            // [9216][768]
    unsigned short* wts    = pA + (size_t)NROWS * NPD;
    unsigned short* pwt  = wts;                       // [256][768]
    unsigned short* qwt  = pwt  + 768 * 256;          // [6][768][256]
    unsigned short* owt  = qwt  + 6 * 768 * 256;      // [6][256][256]
    unsigned short* f1wt = owt  + 6 * 256 * 256;      // [6][512][256]
    unsigned short* f2wt = f1wt + 6 * 256 * 512;      // [6][256][512]
    unsigned short* c1wt = f2wt + 6 * 512 * 256;      // [128][9*256]
    unsigned short* c2wt = c1wt + 128 * 9 * 256;      // [64][9*128]
    unsigned short* vthi = c2wt + 64 * 9 * 128;       // [64*64][576]
    unsigned short* vtlo = vthi + (size_t)64 * 64 * NTOK;
    // conv-stage aliases (transformer buffers free by then)
    unsigned short* c1n = ao_bf;            // [16][24][24][128]
    unsigned short* u1n = h_bf;             // [16][48][48][128]
    unsigned short* c2n = xn_bf;            // [16][48][48][64]
    unsigned short* u2n = qkv_hi;           // [16][96][96][64] (spans hi+lo)
    float* c3 = (float*)pA;                 // [16][21][96][96] f32

    // ---- weight casts ----
    k_castT<<<dim3(768, 1), 256, 0, stream>>>(patch_w, pwt, NPD, DMODEL);
    k_castT<<<dim3(768, 6), 256, 0, stream>>>(qkv_w, qwt, DMODEL, DQKV);
    k_castT<<<dim3(256, 6), 256, 0, stream>>>(out_w, owt, DMODEL, DMODEL);
    k_castT<<<dim3(512, 6), 256, 0, stream>>>(ff_w1, f1wt, DMODEL, DMLP);
    k_castT<<<dim3(512, 6), 256, 0, stream>>>(ff_w2, f2wt, DMLP, DMODEL);
    k_castConv<256><<<1152, 256, 0, stream>>>(conv1_w, c1wt, 128);
    k_castConv<128><<<288, 256, 0, stream>>>(conv2_w, c2wt, 64);

    // ---- patch embed ----
    k_patchify<<<(NROWS * NPD + 255) / 256, 256, 0, stream>>>(img, pA);
    k_mm<128, 64, 3, 0><<<4 * 72, 256, 0, stream>>>(
        pA, pwt, patch_b, pos_emb, x, nullptr, nullptr, NROWS, DMODEL, NPD, 0, 0, 4, 72);

    // ---- transformer layers ----
    for (int l = 0; l < DEPTH; ++l) {
        k_ln<<<NROWS, 256, 0, stream>>>(x, ln1_g + l * DMODEL, ln1_b + l * DMODEL, xn_bf);
        k_mm<128, 128, 5, 0><<<6 * 72, 256, 0, stream>>>(
            xn_bf, qwt + (size_t)l * DQKV * DMODEL, nullptr, nullptr,
            nullptr, qkv_hi, qkv_lo, NROWS, DQKV, DMODEL, 0, 0, 6, 72);
        k_vT<<<dim3(NCHUNK, NHEAD, NB), 256, 0, stream>>>(qkv_hi, qkv_lo, vthi, vtlo);
        k_attn<<<NBLK * NHEAD * NB, 256, 0, stream>>>(
            qkv_hi, qkv_lo, vthi, vtlo, alpha + l, ao_bf);
        k_mm<128, 64, 1, 0><<<4 * 72, 256, 0, stream>>>(
            ao_bf, owt + (size_t)l * DMODEL * DMODEL, out_b + l * DMODEL, nullptr,
            x, nullptr, nullptr, NROWS, DMODEL, DMODEL, 0, 0, 4, 72);
        k_ln<<<NROWS, 256, 0, stream>>>(x, ln2_g + l * DMODEL, ln2_b + l * DMODEL, xn_bf);
        k_mm<128, 128, 2, 0><<<4 * 72, 256, 0, stream>>>(
            xn_bf, f1wt + (size_t)l * DMLP * DMODEL, ff_b1 + l * DMLP, nullptr,
            nullptr, h_bf, nullptr, NROWS, DMLP, DMODEL, 0, 0, 4, 72);
        k_mm<128, 64, 1, 0><<<4 * 72, 256, 0, stream>>>(
            h_bf, f2wt + (size_t)l * DMODEL * DMLP, ff_b2 + l * DMODEL, nullptr,
            x, nullptr, nullptr, NROWS, DMODEL, DMLP, 0, 0, 4, 72);
    }

    // ---- head ----
    k_ln<<<NROWS, 256, 0, stream>>>(x, lnf_g, lnf_b, xn_bf);
    // conv1: implicit GEMM over NHWC tokens [16][24][24][256]
    k_mm<64, 128, 4, 256><<<1 * 144, 256, 0, stream>>>(
        xn_bf, c1wt, conv1_b, nullptr, nullptr, c1n, nullptr, NROWS, 128, 9 * 256, 24, 24, 1, 144);
    k_up2n<<<(NB * 48 * 48 * 16 + 255) / 256, 256, 0, stream>>>(c1n, u1n, 24, 128);
    // conv2: implicit GEMM over NHWC [16][48][48][128]
    k_mm<128, 64, 4, 128><<<1 * 288, 256, 0, stream>>>(
        u1n, c2wt, conv2_b, nullptr, nullptr, c2n, nullptr, NB * 48 * 48, 64, 9 * 128, 48, 48, 1, 288);
    k_up2n<<<(NB * 96 * 96 * 8 + 255) / 256, 256, 0, stream>>>(c2n, u2n, 48, 64);
    k_conv3n<<<(NB * 9216 + 255) / 256, 256, 0, stream>>>(u2n, conv3_w, conv3_b, c3);
    k_resize4<<<(OUT_TOTAL + 255) / 256, 256, 0, stream>>>(c3, (float*)d_out);
}

// Round 8
// 1368.116 us; speedup vs baseline: 8.9554x; 1.0967x over previous
//
#include <hip/hip_runtime.h>
#include <cfloat>
#include <cmath>

// ---------------- problem constants ----------------
constexpr int NB    = 16;    // batch
constexpr int IMGSZ = 384;
constexpr int PSZ   = 16;
constexpr int NCH   = 3;
constexpr int DMODEL= 256;
constexpr int DEPTH = 6;
constexpr int NHEAD = 4;
constexpr int DHEAD = 64;
constexpr int DQKV  = 768;   // 3*INNER
constexpr int QKS   = 512;   // Q,K row stride (V lives only in vT)
constexpr int DMLP  = 512;
constexpr int NCLS  = 21;
constexpr int HPATCH= 24;    // IMG/P
constexpr int NTOK  = 576;   // HP*HP
constexpr int NPD   = 768;   // C*P*P
constexpr int TOPK  = 16;
constexpr int NROWS = NB * NTOK;          // 9216
constexpr int OUT_TOTAL = NB * NCLS * IMGSZ * IMGSZ; // 49545216

// attention tiling
constexpr int RPB    = 16;           // query rows per block
constexpr int NBLK   = NTOK / RPB;   // 36 blocks per (b,h)
constexpr int CHUNK  = 64;           // key/value chunk
constexpr int NCHUNK = NTOK / CHUNK; // 9
constexpr int SCP    = 577;          // score row stride (f32)

typedef __attribute__((ext_vector_type(8))) short bf16x8;
typedef __attribute__((ext_vector_type(4))) float f32x4;

__device__ __forceinline__ unsigned short f2bf(float f) {
    unsigned u = __builtin_bit_cast(unsigned, f);
    unsigned r = (u + 0x7FFFu + ((u >> 16) & 1u)) >> 16;
    return (unsigned short)r;
}
__device__ __forceinline__ float bf2f(unsigned short h) {
    unsigned u = ((unsigned)h) << 16;
    return __builtin_bit_cast(float, u);
}

// ---------------- weight cast+transpose: W[L][K][N] f32 -> Wt[L][N][K] bf16 --
__global__ __launch_bounds__(256) void k_castT(const float* __restrict__ src,
                                               unsigned short* __restrict__ dst,
                                               int K, int N) {
    int t = blockIdx.x * 256 + threadIdx.x;
    if (t >= K * N) return;
    size_t base = (size_t)blockIdx.y * K * N;
    int n = t / K, k = t - n * K;
    dst[base + t] = f2bf(src[base + (size_t)k * N + n]);
}

// conv w [OC][IC][3][3] f32 -> [OC][9][IC] bf16 (tap-major K)
template <int IC>
__global__ __launch_bounds__(256) void k_castConv(const float* __restrict__ src,
                                                  unsigned short* __restrict__ dst,
                                                  int OC) {
    int t = blockIdx.x * 256 + threadIdx.x;
    if (t >= OC * 9 * IC) return;
    int oc = t / (9 * IC);
    int r = t - oc * 9 * IC;
    int tap = r / IC, ic = r - tap * IC;
    dst[t] = f2bf(src[((size_t)(oc * IC + ic)) * 9 + tap]);
}

// ---------------- patchify: img[B,3,384,384] -> A[9216,768] bf16 ------------
__global__ __launch_bounds__(256) void k_patchify(const float* __restrict__ img,
                                                  unsigned short* __restrict__ A) {
    int t = blockIdx.x * 256 + threadIdx.x;
    if (t >= NROWS * NPD) return;
    int r  = t / NPD, pd = t - r * NPD;
    int b  = r / NTOK, n = r - b * NTOK;
    int hy = n / HPATCH, hx = n - hy * HPATCH;
    int c  = pd % NCH;  int q = pd / NCH;
    int p2 = q % PSZ;   int p1 = q / PSZ;
    A[t] = f2bf(img[(((size_t)(b * NCH + c)) * IMGSZ + hy * PSZ + p1) * IMGSZ + hx * PSZ + p2]);
}

// ---------------- unified bf16 MFMA GEMM / implicit conv --------------------
// out[M,N] = A[M,K](bf16) @ Wt[N,K]^T(bf16), fp32 accumulate.
// EPI: 2 bias+gelu->bf16 | 4 bias+relu->bf16
//      8 qkv: cols<512 -> hi/lo @stride 512; cols>=512 -> vT hi/lo only
// CIN>0: gather A from NHWC [NB][H][W][CIN] with 3x3 taps (K = 9*CIN, tap-major)
// Flat grid of gxd*gyd blocks; XCD-aware swizzle keyed on M-tile (gyd%8==0).
template <int BM, int BN, int EPI, int CIN>
__global__ __launch_bounds__(256) void k_mm(
    const unsigned short* __restrict__ Abf,
    const unsigned short* __restrict__ Wt,
    const float* __restrict__ bias,
    float* __restrict__ outf,
    unsigned short* __restrict__ outb,
    unsigned short* __restrict__ outb2,
    unsigned short* __restrict__ vth,
    unsigned short* __restrict__ vtl,
    int M, int Nn, int K, int H, int Wd, int gxd, int gyd)
{
    constexpr int MF = BM / 32;
    constexpr int NF = BN / 32;
    constexpr bool GATHER = (CIN > 0);
    constexpr int AREP = BM * 4 / 256;
    constexpr int BREP = BN * 4 / 256;
    __shared__ __align__(16) short As[4][BM][8];
    __shared__ __align__(16) short Bs[4][BN][8];
    const int tid = threadIdx.x;
    // XCD swizzle: all blocks sharing an M-tile window land on one XCD
    const int p = blockIdx.x;
    const int xr = p & 7, xq = p >> 3;
    const int bm = (xr * (gyd >> 3) + xq / gxd) * BM;
    const int bn = (xq % gxd) * BN;
    const int lane = tid & 63, wid = tid >> 6;
    const int wm = wid >> 1, wn = wid & 1;
    const int l15 = lane & 15, lg = lane >> 4;

    int pb_[AREP], py_[AREP], px_[AREP];
    if (GATHER) {
        #pragma unroll
        for (int rep = 0; rep < AREP; ++rep) {
            int idx = rep * 256 + tid;
            int m = idx >> 2;
            int pix = bm + m;
            px_[rep] = pix % Wd;
            int r = pix / Wd;
            py_[rep] = r % H;
            pb_[rep] = r / H;
        }
    }

    f32x4 acc[MF][NF];
    #pragma unroll
    for (int i = 0; i < MF; ++i)
        #pragma unroll
        for (int j = 0; j < NF; ++j)
            acc[i][j] = (f32x4){0.f, 0.f, 0.f, 0.f};

    for (int k0 = 0; k0 < K; k0 += 32) {
        #pragma unroll
        for (int rep = 0; rep < AREP; ++rep) {
            int idx = rep * 256 + tid;
            int m = idx >> 2, kg = idx & 3;
            if (!GATHER) {
                *(bf16x8*)As[kg][m] =
                    *(const bf16x8*)(Abf + (size_t)(bm + m) * K + k0 + kg * 8);
            } else {
                int k = k0 + kg * 8;
                int tap = k / CIN;
                int ic = k - tap * CIN;
                int dy = tap / 3 - 1, dx = tap % 3 - 1;
                int yy = py_[rep] + dy, xx = px_[rep] + dx;
                bf16x8 v = (bf16x8){0, 0, 0, 0, 0, 0, 0, 0};
                if ((unsigned)yy < (unsigned)H && (unsigned)xx < (unsigned)Wd)
                    v = *(const bf16x8*)(Abf +
                        ((size_t)((pb_[rep] * H + yy) * Wd + xx)) * CIN + ic);
                *(bf16x8*)As[kg][m] = v;
            }
        }
        #pragma unroll
        for (int rep = 0; rep < BREP; ++rep) {
            int idx = rep * 256 + tid;
            int n = idx >> 2, kg = idx & 3;
            *(bf16x8*)Bs[kg][n] =
                *(const bf16x8*)(Wt + (size_t)(bn + n) * K + k0 + kg * 8);
        }
        __syncthreads();
        bf16x8 af[MF], bfv[NF];
        #pragma unroll
        for (int i = 0; i < MF; ++i)
            af[i] = *(const bf16x8*)As[lg][wm * (BM / 2) + i * 16 + l15];
        #pragma unroll
        for (int j = 0; j < NF; ++j)
            bfv[j] = *(const bf16x8*)Bs[lg][wn * (BN / 2) + j * 16 + l15];
        #pragma unroll
        for (int i = 0; i < MF; ++i)
            #pragma unroll
            for (int j = 0; j < NF; ++j)
                acc[i][j] = __builtin_amdgcn_mfma_f32_16x16x32_bf16(
                    af[i], bfv[j], acc[i][j], 0, 0, 0);
        __syncthreads();
    }

    if constexpr (EPI == 8) {
        #pragma unroll
        for (int i = 0; i < MF; ++i) {
            const int row0 = bm + wm * (BM / 2) + i * 16 + lg * 4;
            #pragma unroll
            for (int j = 0; j < NF; ++j) {
                const int col = bn + wn * (BN / 2) + j * 16 + l15;
                if (col < 512) {   // uniform per block (bn multiple of 128)
                    #pragma unroll
                    for (int r = 0; r < 4; ++r) {
                        float v = acc[i][j][r];
                        unsigned short hi = f2bf(v);
                        outb[(size_t)(row0 + r) * QKS + col] = hi;
                        outb2[(size_t)(row0 + r) * QKS + col] = f2bf(v - bf2f(hi));
                    }
                } else {
                    const int d = col - 512, hh = d >> 6, dd = d & 63;
                    const int bb = row0 / NTOK, n = row0 % NTOK;   // 4 rows same bb
                    unsigned long long ph = 0ull, pl = 0ull;
                    #pragma unroll
                    for (int r = 0; r < 4; ++r) {
                        float v = acc[i][j][r];
                        unsigned short hi = f2bf(v);
                        unsigned short lo = f2bf(v - bf2f(hi));
                        ph |= (unsigned long long)hi << (16 * r);
                        pl |= (unsigned long long)lo << (16 * r);
                    }
                    const size_t off = (size_t)((bb * NHEAD + hh) * DHEAD + dd) * NTOK + n;
                    *(unsigned long long*)(vth + off) = ph;
                    *(unsigned long long*)(vtl + off) = pl;
                }
            }
        }
    } else {
        #pragma unroll
        for (int i = 0; i < MF; ++i) {
            const int row0 = bm + wm * (BM / 2) + i * 16 + lg * 4;
            #pragma unroll
            for (int j = 0; j < NF; ++j) {
                const int col = bn + wn * (BN / 2) + j * 16 + l15;
                #pragma unroll
                for (int r = 0; r < 4; ++r) {
                    const int rr = row0 + r;
                    float v = acc[i][j][r] + bias[col];
                    if (EPI == 2) v = 0.5f * v * (1.0f + erff(v * 0.70710678118f));
                    if (EPI == 4) v = fmaxf(v, 0.f);
                    outb[(size_t)rr * Nn + col] = f2bf(v);
                }
            }
        }
    }
}

// ---------------- GEMM + bias(+residual/posemb) + LayerNorm fused -----------
// Nn == 256 (full row per block). BM=32, 4 waves each owning 64 cols.
// RES=1: v = acc + bias + x_old (residual). RES=0: v = acc + bias + pos_emb.
// Writes x (f32 residual stream) and xn (bf16 LN output).
template <int RES>
__global__ __launch_bounds__(256) void k_gemm_ln(
    const unsigned short* __restrict__ Abf,
    const unsigned short* __restrict__ Wt,
    const float* __restrict__ bias,
    const float* __restrict__ extra,
    const float* __restrict__ lng,
    const float* __restrict__ lnb,
    float* __restrict__ x,
    unsigned short* __restrict__ xn,
    int K, int gyd)
{
    constexpr int BM = 32;
    __shared__ __align__(16) short As[4][BM][8];
    __shared__ __align__(16) short Bs[4][256][8];
    __shared__ float redS[BM][4];
    __shared__ float redQ[BM][4];
    const int tid = threadIdx.x;
    const int p = blockIdx.x;
    const int xr = p & 7, xq = p >> 3;
    const int bm = (xr * (gyd >> 3) + xq) * BM;
    const int lane = tid & 63, wn = tid >> 6;
    const int l15 = lane & 15, lg = lane >> 4;

    f32x4 acc[2][4];
    #pragma unroll
    for (int i = 0; i < 2; ++i)
        #pragma unroll
        for (int j = 0; j < 4; ++j)
            acc[i][j] = (f32x4){0.f, 0.f, 0.f, 0.f};

    for (int k0 = 0; k0 < K; k0 += 32) {
        if (tid < BM * 4) {
            int m = tid >> 2, kg = tid & 3;
            *(bf16x8*)As[kg][m] = *(const bf16x8*)(Abf + (size_t)(bm + m) * K + k0 + kg * 8);
        }
        #pragma unroll
        for (int rep = 0; rep < 4; ++rep) {
            int idx = rep * 256 + tid;
            int n = idx >> 2, kg = idx & 3;
            *(bf16x8*)Bs[kg][n] = *(const bf16x8*)(Wt + (size_t)n * K + k0 + kg * 8);
        }
        __syncthreads();
        bf16x8 af[2], bfv[4];
        #pragma unroll
        for (int i = 0; i < 2; ++i)
            af[i] = *(const bf16x8*)As[lg][i * 16 + l15];
        #pragma unroll
        for (int j = 0; j < 4; ++j)
            bfv[j] = *(const bf16x8*)Bs[lg][wn * 64 + j * 16 + l15];
        #pragma unroll
        for (int i = 0; i < 2; ++i)
            #pragma unroll
            for (int j = 0; j < 4; ++j)
                acc[i][j] = __builtin_amdgcn_mfma_f32_16x16x32_bf16(
                    af[i], bfv[j], acc[i][j], 0, 0, 0);
        __syncthreads();
    }

    // ---- epilogue: bias (+res/pos), write x, keep v in acc ----
    #pragma unroll
    for (int i = 0; i < 2; ++i) {
        #pragma unroll
        for (int j = 0; j < 4; ++j) {
            const int col = wn * 64 + j * 16 + l15;
            #pragma unroll
            for (int r = 0; r < 4; ++r) {
                const int rr = bm + i * 16 + lg * 4 + r;
                float v = acc[i][j][r] + bias[col];
                if (RES) v += x[(size_t)rr * DMODEL + col];
                else     v += extra[(size_t)(rr % NTOK) * DMODEL + col];
                x[(size_t)rr * DMODEL + col] = v;
                acc[i][j][r] = v;
            }
        }
    }
    // ---- pass 1: mean ----
    float s[2][4];
    #pragma unroll
    for (int i = 0; i < 2; ++i)
        #pragma unroll
        for (int r = 0; r < 4; ++r)
            s[i][r] = ((acc[i][0][r] + acc[i][1][r]) + acc[i][2][r]) + acc[i][3][r];
    #pragma unroll
    for (int off = 1; off < 16; off <<= 1)
        #pragma unroll
        for (int i = 0; i < 2; ++i)
            #pragma unroll
            for (int r = 0; r < 4; ++r)
                s[i][r] += __shfl_xor(s[i][r], off);
    if (l15 == 0)
        #pragma unroll
        for (int i = 0; i < 2; ++i)
            #pragma unroll
            for (int r = 0; r < 4; ++r)
                redS[i * 16 + lg * 4 + r][wn] = s[i][r];
    __syncthreads();
    float mu[2][4];
    #pragma unroll
    for (int i = 0; i < 2; ++i)
        #pragma unroll
        for (int r = 0; r < 4; ++r) {
            const float* q = redS[i * 16 + lg * 4 + r];
            mu[i][r] = (((q[0] + q[1]) + q[2]) + q[3]) * (1.0f / DMODEL);
        }
    // ---- pass 2: variance ----
    float qq[2][4];
    #pragma unroll
    for (int i = 0; i < 2; ++i)
        #pragma unroll
        for (int r = 0; r < 4; ++r) {
            float d0 = acc[i][0][r] - mu[i][r], d1 = acc[i][1][r] - mu[i][r];
            float d2 = acc[i][2][r] - mu[i][r], d3 = acc[i][3][r] - mu[i][r];
            qq[i][r] = ((d0 * d0 + d1 * d1) + d2 * d2) + d3 * d3;
        }
    #pragma unroll
    for (int off = 1; off < 16; off <<= 1)
        #pragma unroll
        for (int i = 0; i < 2; ++i)
            #pragma unroll
            for (int r = 0; r < 4; ++r)
                qq[i][r] += __shfl_xor(qq[i][r], off);
    if (l15 == 0)
        #pragma unroll
        for (int i = 0; i < 2; ++i)
            #pragma unroll
            for (int r = 0; r < 4; ++r)
                redQ[i * 16 + lg * 4 + r][wn] = qq[i][r];
    __syncthreads();
    #pragma unroll
    for (int i = 0; i < 2; ++i) {
        #pragma unroll
        for (int r = 0; r < 4; ++r) {
            const float* q = redQ[i * 16 + lg * 4 + r];
            float var = (((q[0] + q[1]) + q[2]) + q[3]) * (1.0f / DMODEL);
            float rstd = rsqrtf(var + 1e-5f);
            const int rr = bm + i * 16 + lg * 4 + r;
            #pragma unroll
            for (int j = 0; j < 4; ++j) {
                const int col = wn * 64 + j * 16 + l15;
                float o = (acc[i][j][r] - mu[i][r]) * rstd * lng[col] + lnb[col];
                xn[(size_t)rr * DMODEL + col] = f2bf(o);
            }
        }
    }
}

// ---------------- wave-private hi/lo fragment quad (2 ksl x hi/lo) ----------
struct KF { bf16x8 h0, h1, l0, l1; };
__device__ __forceinline__ KF ldkf(const unsigned short* __restrict__ hi,
                                   const unsigned short* __restrict__ lo,
                                   size_t off) {
    KF f;
    f.h0 = *(const bf16x8*)(hi + off);
    f.h1 = *(const bf16x8*)(hi + off + 32);
    f.l0 = *(const bf16x8*)(lo + off);
    f.l1 = *(const bf16x8*)(lo + off + 32);
    return f;
}

// ---------------- MFMA hybrid attention, 16 rows/block, 256 threads ---------
// (unchanged from round 7 except Q/K stride 512)
__global__ __launch_bounds__(256, 4) void k_attn(
    const unsigned short* __restrict__ qhi,
    const unsigned short* __restrict__ qlo,
    const unsigned short* __restrict__ vthi,
    const unsigned short* __restrict__ vtlo,
    const float* __restrict__ alpha_l,
    unsigned short* __restrict__ ao) {
    __shared__ __align__(16) unsigned char ub[16 * SCP * 4];  // 36928 B
    float* scp = (float*)ub;                 // [16][577] f32
    short* pj  = (short*)ub;                 // [2buf][2hl][16][72] bf16 (overlay)

    const int tid = threadIdx.x;
    const int lane = tid & 63;
    const int ct = tid >> 6;                 // wave id = column tile
    const int l15 = lane & 15, lg = lane >> 4;
    const int xr = blockIdx.x & 7, xq = blockIdx.x >> 3;
    const int g = xr + 8 * (xq / NBLK);      // group = b*4+h
    const int b = g >> 2, h = g & 3;
    const int i0 = (xq % NBLK) * RPB;

    // ---- Q fragments (A operand), wave-uniform: rows i0+l15 ----
    bf16x8 aqh0, aqh1, aql0, aql1;
    {
        const size_t qoff = (size_t)(b * NTOK + i0 + l15) * QKS + h * DHEAD + lg * 8;
        aqh0 = *(const bf16x8*)(qhi + qoff);
        aqh1 = *(const bf16x8*)(qhi + qoff + 32);
        aql0 = *(const bf16x8*)(qlo + qoff);
        aql1 = *(const bf16x8*)(qlo + qoff + 32);
    }

    // ---- score phase: direct-global K frags, prefetch 1 chunk ----
    const size_t kRow = (size_t)(b * NTOK + ct * 16 + l15) * QKS + DMODEL + h * DHEAD + lg * 8;
    KF kc = ldkf(qhi, qlo, kRow);
    #pragma unroll
    for (int c = 0; c < NCHUNK; ++c) {
        KF kn;
        if (c + 1 < NCHUNK)
            kn = ldkf(qhi, qlo, kRow + (size_t)(c + 1) * CHUNK * QKS);
        f32x4 sD = (f32x4){0.f, 0.f, 0.f, 0.f};
        sD = __builtin_amdgcn_mfma_f32_16x16x32_bf16(aqh0, kc.h0, sD, 0, 0, 0);
        sD = __builtin_amdgcn_mfma_f32_16x16x32_bf16(aqh0, kc.l0, sD, 0, 0, 0);
        sD = __builtin_amdgcn_mfma_f32_16x16x32_bf16(aql0, kc.h0, sD, 0, 0, 0);
        sD = __builtin_amdgcn_mfma_f32_16x16x32_bf16(aqh1, kc.h1, sD, 0, 0, 0);
        sD = __builtin_amdgcn_mfma_f32_16x16x32_bf16(aqh1, kc.l1, sD, 0, 0, 0);
        sD = __builtin_amdgcn_mfma_f32_16x16x32_bf16(aql1, kc.h1, sD, 0, 0, 0);
        const int col = c * CHUNK + ct * 16 + l15;
        #pragma unroll
        for (int r = 0; r < 4; ++r)
            scp[(lg * 4 + r) * SCP + col] = sD[r] * 0.125f;
        if (c + 1 < NCHUNK) kc = kn;
    }
    __syncthreads();   // all scores written

    float o_[4][9];
    const int wrow = ct * 4;
    #pragma unroll
    for (int rr = 0; rr < 4; ++rr)
        #pragma unroll
        for (int t = 0; t < 9; ++t)
            o_[rr][t] = scp[(wrow + rr) * SCP + t * 64 + lane];
    __syncthreads();   // score reads done -> P overlay region may be written

    // ---- top-16: iteration-outer, 4 rows interleaved ----
    unsigned msk[4] = {0u, 0u, 0u, 0u};
    float M_[4];
    for (int k = 0; k < TOPK; ++k) {
        float lm[4];
        #pragma unroll
        for (int rr = 0; rr < 4; ++rr) {
            float m0 = -FLT_MAX;
            #pragma unroll
            for (int t = 0; t < 9; ++t) {
                float v = ((msk[rr] >> t) & 1u) ? -FLT_MAX : o_[rr][t];
                m0 = fmaxf(m0, v);
            }
            lm[rr] = m0;
        }
        #pragma unroll
        for (int off = 1; off < 64; off <<= 1) {
            #pragma unroll
            for (int rr = 0; rr < 4; ++rr)
                lm[rr] = fmaxf(lm[rr], __shfl_xor(lm[rr], off));
        }
        if (k == 0) {
            #pragma unroll
            for (int rr = 0; rr < 4; ++rr) M_[rr] = lm[rr];
        }
        #pragma unroll
        for (int rr = 0; rr < 4; ++rr) {
            int js = -1;
            #pragma unroll
            for (int t = 0; t < 9; ++t) {
                if (js < 0) {   // wave-uniform guard
                    unsigned long long bal =
                        __ballot((((msk[rr] >> t) & 1u) == 0u) && (o_[rr][t] == lm[rr]));
                    if (bal) js = t * 64 + (int)__builtin_ctzll(bal);
                }
            }
            if ((js & 63) == lane) msk[rr] |= 1u << (js >> 6);
        }
    }

    // ---- softmax denominators + coefficients ----
    const float al = fminf(fmaxf(alpha_l[0], 0.f), 1.f);
    float gs[4], ss[4];
    #pragma unroll
    for (int rr = 0; rr < 4; ++rr) {
        float g_ = 0.f, s_ = 0.f;
        #pragma unroll
        for (int t = 0; t < 9; ++t) {
            float e = __expf(o_[rr][t] - M_[rr]);
            g_ += e;
            if ((msk[rr] >> t) & 1u) s_ += e;
        }
        gs[rr] = g_; ss[rr] = s_;
    }
    #pragma unroll
    for (int off = 1; off < 64; off <<= 1) {
        #pragma unroll
        for (int rr = 0; rr < 4; ++rr) {
            gs[rr] += __shfl_xor(gs[rr], off);
            ss[rr] += __shfl_xor(ss[rr], off);
        }
    }
    float ca[4], cs[4];
    #pragma unroll
    for (int rr = 0; rr < 4; ++rr) {
        ca[rr] = al / gs[rr];
        cs[rr] = (1.f - al) / ss[rr];
    }

    // ---- PV phase: JIT P slices in LDS dbuf, direct-global V^T frags ----
    const size_t vRow = (size_t)((b * NHEAD + h) * DHEAD + ct * 16 + l15) * NTOK + lg * 8;
    KF vc = ldkf(vthi, vtlo, vRow);
    f32x4 acc = (f32x4){0.f, 0.f, 0.f, 0.f};
    #pragma unroll
    for (int c = 0; c < NCHUNK; ++c) {
        KF vn;
        if (c + 1 < NCHUNK)
            vn = ldkf(vthi, vtlo, vRow + (size_t)(c + 1) * CHUNK);
        short* pb = pj + (c & 1) * (2 * 16 * 72);
        #pragma unroll
        for (int rr = 0; rr < 4; ++rr) {
            float e = __expf(o_[rr][c] - M_[rr]);
            float wv = e * (ca[rr] + (((msk[rr] >> c) & 1u) ? cs[rr] : 0.f));
            unsigned short hi = f2bf(wv);
            pb[(wrow + rr) * 72 + lane] = (short)hi;
            pb[16 * 72 + (wrow + rr) * 72 + lane] = (short)f2bf(wv - bf2f(hi));
        }
        __syncthreads();   // all rows' P slice visible
        const short* pr = pb + l15 * 72 + lg * 8;
        bf16x8 ah0 = *(const bf16x8*)(pr);
        bf16x8 ah1 = *(const bf16x8*)(pr + 32);
        bf16x8 al0 = *(const bf16x8*)(pr + 16 * 72);
        bf16x8 al1 = *(const bf16x8*)(pr + 16 * 72 + 32);
        acc = __builtin_amdgcn_mfma_f32_16x16x32_bf16(ah0, vc.h0, acc, 0, 0, 0);
        acc = __builtin_amdgcn_mfma_f32_16x16x32_bf16(ah0, vc.l0, acc, 0, 0, 0);
        acc = __builtin_amdgcn_mfma_f32_16x16x32_bf16(al0, vc.h0, acc, 0, 0, 0);
        acc = __builtin_amdgcn_mfma_f32_16x16x32_bf16(ah1, vc.h1, acc, 0, 0, 0);
        acc = __builtin_amdgcn_mfma_f32_16x16x32_bf16(ah1, vc.l1, acc, 0, 0, 0);
        acc = __builtin_amdgcn_mfma_f32_16x16x32_bf16(al1, vc.h1, acc, 0, 0, 0);
        if (c + 1 < NCHUNK) vc = vn;
    }
    {
        const int qrow = i0 + lg * 4;
        const int dcol = h * DHEAD + ct * 16 + l15;
        #pragma unroll
        for (int r = 0; r < 4; ++r)
            ao[(size_t)(b * NTOK + qrow + r) * DMODEL + dcol] = f2bf(acc[r]);
    }
}

// ---------------- bilinear helpers (jax.image.resize half-pixel) ------------
__device__ __forceinline__ void bilin_axis(float sF, int H, int& i0, int& i1, float& f) {
    float fl = floorf(sF);
    f = sF - fl;
    int lo = (int)fl;
    i0 = lo < 0 ? 0 : (lo > H - 1 ? H - 1 : lo);
    int hi = lo + 1;
    i1 = hi < 0 ? 0 : (hi > H - 1 ? H - 1 : hi);
}

// NHWC bf16 2x bilinear upsample
__global__ __launch_bounds__(256) void k_up2n(const unsigned short* __restrict__ in,
                                              unsigned short* __restrict__ outp,
                                              int Hin, int C) {
    const int Ho = 2 * Hin;
    const int CG = C / 8;
    const int total = NB * Ho * Ho * CG;
    int t = blockIdx.x * 256 + threadIdx.x;
    if (t >= total) return;
    int cg = t % CG; int r = t / CG;
    int x = r % Ho; r /= Ho;
    int y = r % Ho; int b = r / Ho;
    int i0, i1, j0, j1; float fy, fx;
    bilin_axis(0.5f * y - 0.25f, Hin, i0, i1, fy);
    bilin_axis(0.5f * x - 0.25f, Hin, j0, j1, fx);
    const unsigned short* base = in + (size_t)b * Hin * Hin * C + cg * 8;
    const bf16x8 p00 = *(const bf16x8*)(base + (size_t)(i0 * Hin + j0) * C);
    const bf16x8 p01 = *(const bf16x8*)(base + (size_t)(i0 * Hin + j1) * C);
    const bf16x8 p10 = *(const bf16x8*)(base + (size_t)(i1 * Hin + j0) * C);
    const bf16x8 p11 = *(const bf16x8*)(base + (size_t)(i1 * Hin + j1) * C);
    bf16x8 o;
    #pragma unroll
    for (int e = 0; e < 8; ++e) {
        float v = (1.f - fy) * ((1.f - fx) * bf2f((unsigned short)p00[e]) + fx * bf2f((unsigned short)p01[e]))
                + fy        * ((1.f - fx) * bf2f((unsigned short)p10[e]) + fx * bf2f((unsigned short)p11[e]));
        o[e] = (short)f2bf(v);
    }
    *(bf16x8*)(outp + (size_t)t * 8) = o;
}

// ---------------- conv3: 1x1, 64->21, NHWC bf16 in -> NCHW f32 out ----------
__global__ __launch_bounds__(256) void k_conv3n(const unsigned short* __restrict__ in,
                                                const float* __restrict__ w,
                                                const float* __restrict__ bias,
                                                float* __restrict__ outp) {
    __shared__ float ws_[NCLS * 64];
    for (int i = threadIdx.x; i < NCLS * 64; i += 256) ws_[i] = w[i];
    __syncthreads();
    int t = blockIdx.x * 256 + threadIdx.x;
    if (t >= NB * 9216) return;
    int pix = t % 9216, b = t / 9216;
    float xv[64];
    const unsigned short* p = in + (size_t)t * 64;
    #pragma unroll
    for (int c = 0; c < 8; ++c) {
        bf16x8 v = *(const bf16x8*)(p + c * 8);
        #pragma unroll
        for (int e = 0; e < 8; ++e) xv[c * 8 + e] = bf2f((unsigned short)v[e]);
    }
    float* op = outp + (size_t)b * NCLS * 9216 + pix;
    #pragma unroll
    for (int o = 0; o < NCLS; ++o) {
        float acc = bias[o];
        #pragma unroll
        for (int ic = 0; ic < 64; ++ic) acc += ws_[o * 64 + ic] * xv[ic];
        op[(size_t)o * 9216] = acc;
    }
}

// ---------------- final resize 96 -> 384 (4x bilinear), f32 NCHW ------------
__global__ __launch_bounds__(256) void k_resize4(const float* __restrict__ in,
                                                 float* __restrict__ outp) {
    int t = blockIdx.x * 256 + threadIdx.x;
    if (t >= OUT_TOTAL) return;
    int x = t % IMGSZ; int r = t / IMGSZ; int y = r % IMGSZ; int bc = r / IMGSZ;
    int i0, i1, j0, j1; float fy, fx;
    bilin_axis(0.25f * y - 0.375f, 96, i0, i1, fy);
    bilin_axis(0.25f * x - 0.375f, 96, j0, j1, fx);
    const float* p = in + (size_t)bc * 9216;
    outp[t] = (1.f - fy) * ((1.f - fx) * p[i0 * 96 + j0] + fx * p[i0 * 96 + j1])
            + fy        * ((1.f - fx) * p[i1 * 96 + j0] + fx * p[i1 * 96 + j1]);
}

// ---------------- orchestration ----------------
extern "C" void kernel_launch(void* const* d_in, const int* in_sizes, int n_in,
                              void* d_out, int out_size, void* d_ws, size_t ws_size,
                              hipStream_t stream) {
    const float* img     = (const float*)d_in[0];
    const float* patch_w = (const float*)d_in[1];
    const float* patch_b = (const float*)d_in[2];
    const float* pos_emb = (const float*)d_in[3];
    const float* ln1_g   = (const float*)d_in[4];
    const float* ln1_b   = (const float*)d_in[5];
    const float* qkv_w   = (const float*)d_in[6];
    const float* out_w   = (const float*)d_in[7];
    const float* out_b   = (const float*)d_in[8];
    const float* alpha   = (const float*)d_in[9];
    const float* ln2_g   = (const float*)d_in[10];
    const float* ln2_b   = (const float*)d_in[11];
    const float* ff_w1   = (const float*)d_in[12];
    const float* ff_b1   = (const float*)d_in[13];
    const float* ff_w2   = (const float*)d_in[14];
    const float* ff_b2   = (const float*)d_in[15];
    const float* lnf_g   = (const float*)d_in[16];
    const float* lnf_b   = (const float*)d_in[17];
    const float* conv1_w = (const float*)d_in[18];
    const float* conv1_b = (const float*)d_in[19];
    const float* conv2_w = (const float*)d_in[20];
    const float* conv2_b = (const float*)d_in[21];
    const float* conv3_w = (const float*)d_in[22];
    const float* conv3_b = (const float*)d_in[23];

    // ---- workspace layout (~78 MB) ----
    float* x = (float*)d_ws;                                         // [9216][256] f32
    unsigned short* qkv_hi = (unsigned short*)(x + (size_t)NROWS * DMODEL); // [9216][512] (Q,K)
    unsigned short* qkv_lo = qkv_hi + (size_t)NROWS * QKS;           // [9216][512]
    unsigned short* xn_bf  = qkv_lo + (size_t)NROWS * QKS;           // [9216][256]
    unsigned short* ao_bf  = xn_bf + (size_t)NROWS * DMODEL;         // [9216][256]
    unsigned short* h_bf   = ao_bf + (size_t)NROWS * DMODEL;         // [9216][512]
    unsigned short* pA     = h_bf + (size_t)NROWS * DMLP;            // [9216][768]
    unsigned short* wts    = pA + (size_t)NROWS * NPD;
    unsigned short* pwt  = wts;                       // [256][768]
    unsigned short* qwt  = pwt  + 768 * 256;          // [6][768][256]
    unsigned short* owt  = qwt  + 6 * 768 * 256;      // [6][256][256]
    unsigned short* f1wt = owt  + 6 * 256 * 256;      // [6][512][256]
    unsigned short* f2wt = f1wt + 6 * 256 * 512;      // [6][256][512]
    unsigned short* c1wt = f2wt + 6 * 512 * 256;      // [128][9*256]
    unsigned short* c2wt = c1wt + 128 * 9 * 256;      // [64][9*128]
    unsigned short* vthi = c2wt + 64 * 9 * 128;       // [64*64][576]
    unsigned short* vtlo = vthi + (size_t)64 * 64 * NTOK;
    // conv-stage aliases (transformer buffers free by then)
    unsigned short* c1n = ao_bf;            // [16][24][24][128]
    unsigned short* u1n = h_bf;             // [16][48][48][128]
    unsigned short* c2n = xn_bf;            // [16][48][48][64]
    unsigned short* u2n = qkv_hi;           // [16][96][96][64] (spans hi+lo exactly)
    float* c3 = (float*)pA;                 // [16][21][96][96] f32

    // ---- weight casts ----
    k_castT<<<dim3(768, 1), 256, 0, stream>>>(patch_w, pwt, NPD, DMODEL);
    k_castT<<<dim3(768, 6), 256, 0, stream>>>(qkv_w, qwt, DMODEL, DQKV);
    k_castT<<<dim3(256, 6), 256, 0, stream>>>(out_w, owt, DMODEL, DMODEL);
    k_castT<<<dim3(512, 6), 256, 0, stream>>>(ff_w1, f1wt, DMODEL, DMLP);
    k_castT<<<dim3(512, 6), 256, 0, stream>>>(ff_w2, f2wt, DMLP, DMODEL);
    k_castConv<256><<<1152, 256, 0, stream>>>(conv1_w, c1wt, 128);
    k_castConv<128><<<288, 256, 0, stream>>>(conv2_w, c2wt, 64);

    // ---- patch embed + pos + LN1(layer0), fused ----
    k_patchify<<<(NROWS * NPD + 255) / 256, 256, 0, stream>>>(img, pA);
    k_gemm_ln<0><<<288, 256, 0, stream>>>(
        pA, pwt, patch_b, pos_emb, ln1_g, ln1_b, x, xn_bf, NPD, 288);

    // ---- transformer layers ----
    for (int l = 0; l < DEPTH; ++l) {
        // QKV GEMM: Q,K -> qkv hi/lo (stride 512); V -> vT hi/lo directly
        k_mm<128, 128, 8, 0><<<6 * 72, 256, 0, stream>>>(
            xn_bf, qwt + (size_t)l * DQKV * DMODEL, nullptr,
            nullptr, qkv_hi, qkv_lo, vthi, vtlo,
            NROWS, DQKV, DMODEL, 0, 0, 6, 72);
        k_attn<<<NBLK * NHEAD * NB, 256, 0, stream>>>(
            qkv_hi, qkv_lo, vthi, vtlo, alpha + l, ao_bf);
        // out-proj + bias + residual + LN2, fused
        k_gemm_ln<1><<<288, 256, 0, stream>>>(
            ao_bf, owt + (size_t)l * DMODEL * DMODEL, out_b + l * DMODEL, nullptr,
            ln2_g + l * DMODEL, ln2_b + l * DMODEL, x, xn_bf, DMODEL, 288);
        // ff1 + gelu
        k_mm<128, 128, 2, 0><<<4 * 72, 256, 0, stream>>>(
            xn_bf, f1wt + (size_t)l * DMLP * DMODEL, ff_b1 + l * DMLP,
            nullptr, h_bf, nullptr, nullptr, nullptr,
            NROWS, DMLP, DMODEL, 0, 0, 4, 72);
        // ff2 + bias + residual + LN(next layer's ln1, or lnf on last)
        const float* ng = (l + 1 < DEPTH) ? (ln1_g + (l + 1) * DMODEL) : lnf_g;
        const float* nb = (l + 1 < DEPTH) ? (ln1_b + (l + 1) * DMODEL) : lnf_b;
        k_gemm_ln<1><<<288, 256, 0, stream>>>(
            h_bf, f2wt + (size_t)l * DMODEL * DMLP, ff_b2 + l * DMODEL, nullptr,
            ng, nb, x, xn_bf, DMLP, 288);
    }

    // ---- head (xn_bf already = LNf output) ----
    k_mm<64, 128, 4, 256><<<1 * 144, 256, 0, stream>>>(
        xn_bf, c1wt, conv1_b, nullptr, c1n, nullptr, nullptr, nullptr,
        NROWS, 128, 9 * 256, 24, 24, 1, 144);
    k_up2n<<<(NB * 48 * 48 * 16 + 255) / 256, 256, 0, stream>>>(c1n, u1n, 24, 128);
    k_mm<128, 64, 4, 128><<<1 * 288, 256, 0, stream>>>(
        u1n, c2wt, conv2_b, nullptr, c2n, nullptr, nullptr, nullptr,
        NB * 48 * 48, 64, 9 * 128, 48, 48, 1, 288);
    k_up2n<<<(NB * 96 * 96 * 8 + 255) / 256, 256, 0, stream>>>(c2n, u2n, 48, 64);
    k_conv3n<<<(NB * 9216 + 255) / 256, 256, 0, stream>>>(u2n, conv3_w, conv3_b, c3);
    k_resize4<<<(OUT_TOTAL + 255) / 256, 256, 0, stream>>>(c3, (float*)d_out);
}

// Round 9
// 1305.636 us; speedup vs baseline: 9.3839x; 1.0479x over previous
//
#include <hip/hip_runtime.h>
#include <cfloat>
#include <cmath>

// ---------------- problem constants ----------------
constexpr int NB    = 16;    // batch
constexpr int IMGSZ = 384;
constexpr int PSZ   = 16;
constexpr int NCH   = 3;
constexpr int DMODEL= 256;
constexpr int DEPTH = 6;
constexpr int NHEAD = 4;
constexpr int DHEAD = 64;
constexpr int DQKV  = 768;   // 3*INNER
constexpr int QKS   = 512;   // Q,K row stride (V lives only in vT)
constexpr int DMLP  = 512;
constexpr int NCLS  = 21;
constexpr int HPATCH= 24;    // IMG/P
constexpr int NTOK  = 576;   // HP*HP
constexpr int NPD   = 768;   // C*P*P
constexpr int TOPK  = 16;
constexpr int NROWS = NB * NTOK;          // 9216
constexpr int OUT_TOTAL = NB * NCLS * IMGSZ * IMGSZ; // 49545216

// attention tiling
constexpr int RPB    = 16;           // query rows per block
constexpr int NBLK   = NTOK / RPB;   // 36 blocks per (b,h)
constexpr int CHUNK  = 64;           // key/value chunk
constexpr int NCHUNK = NTOK / CHUNK; // 9
constexpr int SCP    = 577;          // score row stride (f32)

typedef __attribute__((ext_vector_type(8))) short bf16x8;
typedef __attribute__((ext_vector_type(4))) float f32x4;

__device__ __forceinline__ unsigned short f2bf(float f) {
    unsigned u = __builtin_bit_cast(unsigned, f);
    unsigned r = (u + 0x7FFFu + ((u >> 16) & 1u)) >> 16;
    return (unsigned short)r;
}
__device__ __forceinline__ float bf2f(unsigned short h) {
    unsigned u = ((unsigned)h) << 16;
    return __builtin_bit_cast(float, u);
}

// ---------------- weight cast+transpose: W[L][K][N] f32 -> Wt[L][N][K] bf16 --
__global__ __launch_bounds__(256) void k_castT(const float* __restrict__ src,
                                               unsigned short* __restrict__ dst,
                                               int K, int N) {
    int t = blockIdx.x * 256 + threadIdx.x;
    if (t >= K * N) return;
    size_t base = (size_t)blockIdx.y * K * N;
    int n = t / K, k = t - n * K;
    dst[base + t] = f2bf(src[base + (size_t)k * N + n]);
}

// conv w [OC][IC][3][3] f32 -> [OC][9][IC] bf16 (tap-major K)
template <int IC>
__global__ __launch_bounds__(256) void k_castConv(const float* __restrict__ src,
                                                  unsigned short* __restrict__ dst,
                                                  int OC) {
    int t = blockIdx.x * 256 + threadIdx.x;
    if (t >= OC * 9 * IC) return;
    int oc = t / (9 * IC);
    int r = t - oc * 9 * IC;
    int tap = r / IC, ic = r - tap * IC;
    dst[t] = f2bf(src[((size_t)(oc * IC + ic)) * 9 + tap]);
}

// ---------------- patchify: img[B,3,384,384] -> A[9216,768] bf16 ------------
__global__ __launch_bounds__(256) void k_patchify(const float* __restrict__ img,
                                                  unsigned short* __restrict__ A) {
    int t = blockIdx.x * 256 + threadIdx.x;
    if (t >= NROWS * NPD) return;
    int r  = t / NPD, pd = t - r * NPD;
    int b  = r / NTOK, n = r - b * NTOK;
    int hy = n / HPATCH, hx = n - hy * HPATCH;
    int c  = pd % NCH;  int q = pd / NCH;
    int p2 = q % PSZ;   int p1 = q / PSZ;
    A[t] = f2bf(img[(((size_t)(b * NCH + c)) * IMGSZ + hy * PSZ + p1) * IMGSZ + hx * PSZ + p2]);
}

// ---------------- unified bf16 MFMA GEMM / implicit conv --------------------
// out[M,N] = A[M,K](bf16) @ Wt[N,K]^T(bf16), fp32 accumulate.
// EPI: 2 bias+gelu->bf16 | 4 bias+relu->bf16
//      8 qkv: cols<512 -> hi/lo @stride 512; cols>=512 -> vT hi/lo only
// CIN>0: gather A from NHWC [NB][H][W][CIN] with 3x3 taps (K = 9*CIN, tap-major)
// Flat grid of gxd*gyd blocks; XCD-aware swizzle keyed on M-tile (gyd%8==0).
template <int BM, int BN, int EPI, int CIN>
__global__ __launch_bounds__(256) void k_mm(
    const unsigned short* __restrict__ Abf,
    const unsigned short* __restrict__ Wt,
    const float* __restrict__ bias,
    float* __restrict__ outf,
    unsigned short* __restrict__ outb,
    unsigned short* __restrict__ outb2,
    unsigned short* __restrict__ vth,
    unsigned short* __restrict__ vtl,
    int M, int Nn, int K, int H, int Wd, int gxd, int gyd)
{
    constexpr int MF = BM / 32;
    constexpr int NF = BN / 32;
    constexpr bool GATHER = (CIN > 0);
    constexpr int AREP = BM * 4 / 256;
    constexpr int BREP = BN * 4 / 256;
    __shared__ __align__(16) short As[4][BM][8];
    __shared__ __align__(16) short Bs[4][BN][8];
    const int tid = threadIdx.x;
    // XCD swizzle: all blocks sharing an M-tile window land on one XCD
    const int p = blockIdx.x;
    const int xr = p & 7, xq = p >> 3;
    const int bm = (xr * (gyd >> 3) + xq / gxd) * BM;
    const int bn = (xq % gxd) * BN;
    const int lane = tid & 63, wid = tid >> 6;
    const int wm = wid >> 1, wn = wid & 1;
    const int l15 = lane & 15, lg = lane >> 4;

    int pb_[AREP], py_[AREP], px_[AREP];
    if (GATHER) {
        #pragma unroll
        for (int rep = 0; rep < AREP; ++rep) {
            int idx = rep * 256 + tid;
            int m = idx >> 2;
            int pix = bm + m;
            px_[rep] = pix % Wd;
            int r = pix / Wd;
            py_[rep] = r % H;
            pb_[rep] = r / H;
        }
    }

    f32x4 acc[MF][NF];
    #pragma unroll
    for (int i = 0; i < MF; ++i)
        #pragma unroll
        for (int j = 0; j < NF; ++j)
            acc[i][j] = (f32x4){0.f, 0.f, 0.f, 0.f};

    for (int k0 = 0; k0 < K; k0 += 32) {
        #pragma unroll
        for (int rep = 0; rep < AREP; ++rep) {
            int idx = rep * 256 + tid;
            int m = idx >> 2, kg = idx & 3;
            if (!GATHER) {
                *(bf16x8*)As[kg][m] =
                    *(const bf16x8*)(Abf + (size_t)(bm + m) * K + k0 + kg * 8);
            } else {
                int k = k0 + kg * 8;
                int tap = k / CIN;
                int ic = k - tap * CIN;
                int dy = tap / 3 - 1, dx = tap % 3 - 1;
                int yy = py_[rep] + dy, xx = px_[rep] + dx;
                bf16x8 v = (bf16x8){0, 0, 0, 0, 0, 0, 0, 0};
                if ((unsigned)yy < (unsigned)H && (unsigned)xx < (unsigned)Wd)
                    v = *(const bf16x8*)(Abf +
                        ((size_t)((pb_[rep] * H + yy) * Wd + xx)) * CIN + ic);
                *(bf16x8*)As[kg][m] = v;
            }
        }
        #pragma unroll
        for (int rep = 0; rep < BREP; ++rep) {
            int idx = rep * 256 + tid;
            int n = idx >> 2, kg = idx & 3;
            *(bf16x8*)Bs[kg][n] =
                *(const bf16x8*)(Wt + (size_t)(bn + n) * K + k0 + kg * 8);
        }
        __syncthreads();
        bf16x8 af[MF], bfv[NF];
        #pragma unroll
        for (int i = 0; i < MF; ++i)
            af[i] = *(const bf16x8*)As[lg][wm * (BM / 2) + i * 16 + l15];
        #pragma unroll
        for (int j = 0; j < NF; ++j)
            bfv[j] = *(const bf16x8*)Bs[lg][wn * (BN / 2) + j * 16 + l15];
        #pragma unroll
        for (int i = 0; i < MF; ++i)
            #pragma unroll
            for (int j = 0; j < NF; ++j)
                acc[i][j] = __builtin_amdgcn_mfma_f32_16x16x32_bf16(
                    af[i], bfv[j], acc[i][j], 0, 0, 0);
        __syncthreads();
    }

    if constexpr (EPI == 8) {
        #pragma unroll
        for (int i = 0; i < MF; ++i) {
            const int row0 = bm + wm * (BM / 2) + i * 16 + lg * 4;
            #pragma unroll
            for (int j = 0; j < NF; ++j) {
                const int col = bn + wn * (BN / 2) + j * 16 + l15;
                if (col < 512) {   // uniform per block (bn multiple of 128)
                    #pragma unroll
                    for (int r = 0; r < 4; ++r) {
                        float v = acc[i][j][r];
                        unsigned short hi = f2bf(v);
                        outb[(size_t)(row0 + r) * QKS + col] = hi;
                        outb2[(size_t)(row0 + r) * QKS + col] = f2bf(v - bf2f(hi));
                    }
                } else {
                    const int d = col - 512, hh = d >> 6, dd = d & 63;
                    const int bb = row0 / NTOK, n = row0 % NTOK;   // 4 rows same bb
                    unsigned long long ph = 0ull, pl = 0ull;
                    #pragma unroll
                    for (int r = 0; r < 4; ++r) {
                        float v = acc[i][j][r];
                        unsigned short hi = f2bf(v);
                        unsigned short lo = f2bf(v - bf2f(hi));
                        ph |= (unsigned long long)hi << (16 * r);
                        pl |= (unsigned long long)lo << (16 * r);
                    }
                    const size_t off = (size_t)((bb * NHEAD + hh) * DHEAD + dd) * NTOK + n;
                    *(unsigned long long*)(vth + off) = ph;
                    *(unsigned long long*)(vtl + off) = pl;
                }
            }
        }
    } else {
        #pragma unroll
        for (int i = 0; i < MF; ++i) {
            const int row0 = bm + wm * (BM / 2) + i * 16 + lg * 4;
            #pragma unroll
            for (int j = 0; j < NF; ++j) {
                const int col = bn + wn * (BN / 2) + j * 16 + l15;
                #pragma unroll
                for (int r = 0; r < 4; ++r) {
                    const int rr = row0 + r;
                    float v = acc[i][j][r] + bias[col];
                    if (EPI == 2) v = 0.5f * v * (1.0f + erff(v * 0.70710678118f));
                    if (EPI == 4) v = fmaxf(v, 0.f);
                    outb[(size_t)rr * Nn + col] = f2bf(v);
                }
            }
        }
    }
}

// ---------------- GEMM + bias(+residual/posemb) + LayerNorm fused -----------
template <int RES>
__global__ __launch_bounds__(256) void k_gemm_ln(
    const unsigned short* __restrict__ Abf,
    const unsigned short* __restrict__ Wt,
    const float* __restrict__ bias,
    const float* __restrict__ extra,
    const float* __restrict__ lng,
    const float* __restrict__ lnb,
    float* __restrict__ x,
    unsigned short* __restrict__ xn,
    int K, int gyd)
{
    constexpr int BM = 32;
    __shared__ __align__(16) short As[4][BM][8];
    __shared__ __align__(16) short Bs[4][256][8];
    __shared__ float redS[BM][4];
    __shared__ float redQ[BM][4];
    const int tid = threadIdx.x;
    const int p = blockIdx.x;
    const int xr = p & 7, xq = p >> 3;
    const int bm = (xr * (gyd >> 3) + xq) * BM;
    const int lane = tid & 63, wn = tid >> 6;
    const int l15 = lane & 15, lg = lane >> 4;

    f32x4 acc[2][4];
    #pragma unroll
    for (int i = 0; i < 2; ++i)
        #pragma unroll
        for (int j = 0; j < 4; ++j)
            acc[i][j] = (f32x4){0.f, 0.f, 0.f, 0.f};

    for (int k0 = 0; k0 < K; k0 += 32) {
        if (tid < BM * 4) {
            int m = tid >> 2, kg = tid & 3;
            *(bf16x8*)As[kg][m] = *(const bf16x8*)(Abf + (size_t)(bm + m) * K + k0 + kg * 8);
        }
        #pragma unroll
        for (int rep = 0; rep < 4; ++rep) {
            int idx = rep * 256 + tid;
            int n = idx >> 2, kg = idx & 3;
            *(bf16x8*)Bs[kg][n] = *(const bf16x8*)(Wt + (size_t)n * K + k0 + kg * 8);
        }
        __syncthreads();
        bf16x8 af[2], bfv[4];
        #pragma unroll
        for (int i = 0; i < 2; ++i)
            af[i] = *(const bf16x8*)As[lg][i * 16 + l15];
        #pragma unroll
        for (int j = 0; j < 4; ++j)
            bfv[j] = *(const bf16x8*)Bs[lg][wn * 64 + j * 16 + l15];
        #pragma unroll
        for (int i = 0; i < 2; ++i)
            #pragma unroll
            for (int j = 0; j < 4; ++j)
                acc[i][j] = __builtin_amdgcn_mfma_f32_16x16x32_bf16(
                    af[i], bfv[j], acc[i][j], 0, 0, 0);
        __syncthreads();
    }

    // ---- epilogue: bias (+res/pos), write x, keep v in acc ----
    #pragma unroll
    for (int i = 0; i < 2; ++i) {
        #pragma unroll
        for (int j = 0; j < 4; ++j) {
            const int col = wn * 64 + j * 16 + l15;
            #pragma unroll
            for (int r = 0; r < 4; ++r) {
                const int rr = bm + i * 16 + lg * 4 + r;
                float v = acc[i][j][r] + bias[col];
                if (RES) v += x[(size_t)rr * DMODEL + col];
                else     v += extra[(size_t)(rr % NTOK) * DMODEL + col];
                x[(size_t)rr * DMODEL + col] = v;
                acc[i][j][r] = v;
            }
        }
    }
    // ---- pass 1: mean ----
    float s[2][4];
    #pragma unroll
    for (int i = 0; i < 2; ++i)
        #pragma unroll
        for (int r = 0; r < 4; ++r)
            s[i][r] = ((acc[i][0][r] + acc[i][1][r]) + acc[i][2][r]) + acc[i][3][r];
    #pragma unroll
    for (int off = 1; off < 16; off <<= 1)
        #pragma unroll
        for (int i = 0; i < 2; ++i)
            #pragma unroll
            for (int r = 0; r < 4; ++r)
                s[i][r] += __shfl_xor(s[i][r], off);
    if (l15 == 0)
        #pragma unroll
        for (int i = 0; i < 2; ++i)
            #pragma unroll
            for (int r = 0; r < 4; ++r)
                redS[i * 16 + lg * 4 + r][wn] = s[i][r];
    __syncthreads();
    float mu[2][4];
    #pragma unroll
    for (int i = 0; i < 2; ++i)
        #pragma unroll
        for (int r = 0; r < 4; ++r) {
            const float* q = redS[i * 16 + lg * 4 + r];
            mu[i][r] = (((q[0] + q[1]) + q[2]) + q[3]) * (1.0f / DMODEL);
        }
    // ---- pass 2: variance ----
    float qq[2][4];
    #pragma unroll
    for (int i = 0; i < 2; ++i)
        #pragma unroll
        for (int r = 0; r < 4; ++r) {
            float d0 = acc[i][0][r] - mu[i][r], d1 = acc[i][1][r] - mu[i][r];
            float d2 = acc[i][2][r] - mu[i][r], d3 = acc[i][3][r] - mu[i][r];
            qq[i][r] = ((d0 * d0 + d1 * d1) + d2 * d2) + d3 * d3;
        }
    #pragma unroll
    for (int off = 1; off < 16; off <<= 1)
        #pragma unroll
        for (int i = 0; i < 2; ++i)
            #pragma unroll
            for (int r = 0; r < 4; ++r)
                qq[i][r] += __shfl_xor(qq[i][r], off);
    if (l15 == 0)
        #pragma unroll
        for (int i = 0; i < 2; ++i)
            #pragma unroll
            for (int r = 0; r < 4; ++r)
                redQ[i * 16 + lg * 4 + r][wn] = qq[i][r];
    __syncthreads();
    #pragma unroll
    for (int i = 0; i < 2; ++i) {
        #pragma unroll
        for (int r = 0; r < 4; ++r) {
            const float* q = redQ[i * 16 + lg * 4 + r];
            float var = (((q[0] + q[1]) + q[2]) + q[3]) * (1.0f / DMODEL);
            float rstd = rsqrtf(var + 1e-5f);
            const int rr = bm + i * 16 + lg * 4 + r;
            #pragma unroll
            for (int j = 0; j < 4; ++j) {
                const int col = wn * 64 + j * 16 + l15;
                float o = (acc[i][j][r] - mu[i][r]) * rstd * lng[col] + lnb[col];
                xn[(size_t)rr * DMODEL + col] = f2bf(o);
            }
        }
    }
}

// ---------------- wave-private hi/lo fragment quad (2 ksl x hi/lo) ----------
struct KF { bf16x8 h0, h1, l0, l1; };
__device__ __forceinline__ KF ldkf(const unsigned short* __restrict__ hi,
                                   const unsigned short* __restrict__ lo,
                                   size_t off) {
    KF f;
    f.h0 = *(const bf16x8*)(hi + off);
    f.h1 = *(const bf16x8*)(hi + off + 32);
    f.l0 = *(const bf16x8*)(lo + off);
    f.l1 = *(const bf16x8*)(lo + off + 32);
    return f;
}

// ---------------- MFMA hybrid attention, 16 rows/block, 512 threads ---------
// 8 waves: wave w = (par = w>>2 chunk-parity, ct = w&3 column tile).
// Score + PV chunk loops split by parity (each wave does 4-5 chunks);
// top-16 handles 2 rows/wave (was 4) -> half the serial VALU per wave.
// PV partials cross-half reduced via LDS. 32 waves/CU occupancy.
__global__ __launch_bounds__(512, 8) void k_attn(
    const unsigned short* __restrict__ qhi,
    const unsigned short* __restrict__ qlo,
    const unsigned short* __restrict__ vthi,
    const unsigned short* __restrict__ vtlo,
    const float* __restrict__ alpha_l,
    unsigned short* __restrict__ ao) {
    __shared__ __align__(16) unsigned char ub[16 * SCP * 4];  // 36928 B
    float* scp = (float*)ub;                  // [16][577] f32
    short* pj  = (short*)ub;                  // [2buf][2hl][16][72] bf16 (9216 B overlay)
    float* red = (float*)(ub + 16384);        // [64][17] f32 PV partials (4352 B)

    const int tid = threadIdx.x;
    const int lane = tid & 63;
    const int w = tid >> 6;                   // 0..7
    const int par = w >> 2;                   // chunk parity handled by this wave
    const int ct = w & 3;                     // column tile
    const int l15 = lane & 15, lg = lane >> 4;
    const int xr = blockIdx.x & 7, xq = blockIdx.x >> 3;
    const int g = xr + 8 * (xq / NBLK);       // group = b*4+h
    const int b = g >> 2, h = g & 3;
    const int i0 = (xq % NBLK) * RPB;

    // ---- Q fragments (A operand), wave-uniform: rows i0+l15 ----
    bf16x8 aqh0, aqh1, aql0, aql1;
    {
        const size_t qoff = (size_t)(b * NTOK + i0 + l15) * QKS + h * DHEAD + lg * 8;
        aqh0 = *(const bf16x8*)(qhi + qoff);
        aqh1 = *(const bf16x8*)(qhi + qoff + 32);
        aql0 = *(const bf16x8*)(qlo + qoff);
        aql1 = *(const bf16x8*)(qlo + qoff + 32);
    }

    // ---- score phase: chunks of this wave's parity ----
    const size_t kRow = (size_t)(b * NTOK + ct * 16 + l15) * QKS + DMODEL + h * DHEAD + lg * 8;
    for (int c = par; c < NCHUNK; c += 2) {
        KF kc = ldkf(qhi, qlo, kRow + (size_t)c * CHUNK * QKS);
        f32x4 sD = (f32x4){0.f, 0.f, 0.f, 0.f};
        sD = __builtin_amdgcn_mfma_f32_16x16x32_bf16(aqh0, kc.h0, sD, 0, 0, 0);
        sD = __builtin_amdgcn_mfma_f32_16x16x32_bf16(aqh0, kc.l0, sD, 0, 0, 0);
        sD = __builtin_amdgcn_mfma_f32_16x16x32_bf16(aql0, kc.h0, sD, 0, 0, 0);
        sD = __builtin_amdgcn_mfma_f32_16x16x32_bf16(aqh1, kc.h1, sD, 0, 0, 0);
        sD = __builtin_amdgcn_mfma_f32_16x16x32_bf16(aqh1, kc.l1, sD, 0, 0, 0);
        sD = __builtin_amdgcn_mfma_f32_16x16x32_bf16(aql1, kc.h1, sD, 0, 0, 0);
        const int col = c * CHUNK + ct * 16 + l15;
        #pragma unroll
        for (int r = 0; r < 4; ++r)
            scp[(lg * 4 + r) * SCP + col] = sD[r] * 0.125f;
    }
    __syncthreads();   // all scores written

    // ---- pull scores to regs (wave w owns rows 2w, 2w+1) ----
    float o_[2][9];
    const int r0 = 2 * w;
    #pragma unroll
    for (int rr = 0; rr < 2; ++rr)
        #pragma unroll
        for (int t = 0; t < 9; ++t)
            o_[rr][t] = scp[(r0 + rr) * SCP + t * 64 + lane];
    __syncthreads();   // score reads done -> P overlay region may be written

    // ---- top-16: iteration-outer, 2 rows interleaved ----
    unsigned msk[2] = {0u, 0u};
    float M_[2];
    for (int k = 0; k < TOPK; ++k) {
        float lm[2];
        #pragma unroll
        for (int rr = 0; rr < 2; ++rr) {
            float m0 = -FLT_MAX;
            #pragma unroll
            for (int t = 0; t < 9; ++t) {
                float v = ((msk[rr] >> t) & 1u) ? -FLT_MAX : o_[rr][t];
                m0 = fmaxf(m0, v);
            }
            lm[rr] = m0;
        }
        #pragma unroll
        for (int off = 1; off < 64; off <<= 1) {
            #pragma unroll
            for (int rr = 0; rr < 2; ++rr)
                lm[rr] = fmaxf(lm[rr], __shfl_xor(lm[rr], off));
        }
        if (k == 0) {
            #pragma unroll
            for (int rr = 0; rr < 2; ++rr) M_[rr] = lm[rr];
        }
        #pragma unroll
        for (int rr = 0; rr < 2; ++rr) {
            int js = -1;
            #pragma unroll
            for (int t = 0; t < 9; ++t) {
                if (js < 0) {   // wave-uniform guard (js from ballot is uniform)
                    unsigned long long bal =
                        __ballot((((msk[rr] >> t) & 1u) == 0u) && (o_[rr][t] == lm[rr]));
                    if (bal) js = t * 64 + (int)__builtin_ctzll(bal);
                }
            }
            if ((js & 63) == lane) msk[rr] |= 1u << (js >> 6);
        }
    }

    // ---- softmax denominators + coefficients ----
    const float al = fminf(fmaxf(alpha_l[0], 0.f), 1.f);
    float gs[2], ss[2];
    #pragma unroll
    for (int rr = 0; rr < 2; ++rr) {
        float g_ = 0.f, s_ = 0.f;
        #pragma unroll
        for (int t = 0; t < 9; ++t) {
            float e = __expf(o_[rr][t] - M_[rr]);
            g_ += e;
            if ((msk[rr] >> t) & 1u) s_ += e;
        }
        gs[rr] = g_; ss[rr] = s_;
    }
    #pragma unroll
    for (int off = 1; off < 64; off <<= 1) {
        #pragma unroll
        for (int rr = 0; rr < 2; ++rr) {
            gs[rr] += __shfl_xor(gs[rr], off);
            ss[rr] += __shfl_xor(ss[rr], off);
        }
    }
    float ca[2], cs[2];
    #pragma unroll
    for (int rr = 0; rr < 2; ++rr) {
        ca[rr] = al / gs[rr];
        cs[rr] = (1.f - al) / ss[rr];
    }

    // ---- PV phase: all waves write P rows each chunk; parity-half does MFMA --
    const size_t vRow = (size_t)((b * NHEAD + h) * DHEAD + ct * 16 + l15) * NTOK + lg * 8;
    f32x4 acc = (f32x4){0.f, 0.f, 0.f, 0.f};
    for (int c = 0; c < NCHUNK; ++c) {
        short* pb = pj + (c & 1) * (2 * 16 * 72);
        #pragma unroll
        for (int rr = 0; rr < 2; ++rr) {
            float e = __expf(o_[rr][c] - M_[rr]);
            float wv = e * (ca[rr] + (((msk[rr] >> c) & 1u) ? cs[rr] : 0.f));
            unsigned short hi = f2bf(wv);
            pb[(r0 + rr) * 72 + lane] = (short)hi;
            pb[16 * 72 + (r0 + rr) * 72 + lane] = (short)f2bf(wv - bf2f(hi));
        }
        __syncthreads();   // all 16 rows' P slice visible
        if ((c & 1) == par) {
            KF vc = ldkf(vthi, vtlo, vRow + (size_t)c * CHUNK);
            const short* pr = pb + l15 * 72 + lg * 8;
            bf16x8 ah0 = *(const bf16x8*)(pr);
            bf16x8 ah1 = *(const bf16x8*)(pr + 32);
            bf16x8 al0 = *(const bf16x8*)(pr + 16 * 72);
            bf16x8 al1 = *(const bf16x8*)(pr + 16 * 72 + 32);
            acc = __builtin_amdgcn_mfma_f32_16x16x32_bf16(ah0, vc.h0, acc, 0, 0, 0);
            acc = __builtin_amdgcn_mfma_f32_16x16x32_bf16(ah0, vc.l0, acc, 0, 0, 0);
            acc = __builtin_amdgcn_mfma_f32_16x16x32_bf16(al0, vc.h0, acc, 0, 0, 0);
            acc = __builtin_amdgcn_mfma_f32_16x16x32_bf16(ah1, vc.h1, acc, 0, 0, 0);
            acc = __builtin_amdgcn_mfma_f32_16x16x32_bf16(ah1, vc.l1, acc, 0, 0, 0);
            acc = __builtin_amdgcn_mfma_f32_16x16x32_bf16(al1, vc.h1, acc, 0, 0, 0);
        }
    }
    // ---- cross-half PV reduction + output ----
    if (par == 1) {
        #pragma unroll
        for (int r = 0; r < 4; ++r)
            red[(ct * 16 + l15) * 17 + lg * 4 + r] = acc[r];
    }
    __syncthreads();
    if (par == 0) {
        const int qrow = i0 + lg * 4;
        const int dcol = h * DHEAD + ct * 16 + l15;
        #pragma unroll
        for (int r = 0; r < 4; ++r) {
            float v = acc[r] + red[(ct * 16 + l15) * 17 + lg * 4 + r];
            ao[(size_t)(b * NTOK + qrow + r) * DMODEL + dcol] = f2bf(v);
        }
    }
}

// ---------------- bilinear helpers (jax.image.resize half-pixel) ------------
__device__ __forceinline__ void bilin_axis(float sF, int H, int& i0, int& i1, float& f) {
    float fl = floorf(sF);
    f = sF - fl;
    int lo = (int)fl;
    i0 = lo < 0 ? 0 : (lo > H - 1 ? H - 1 : lo);
    int hi = lo + 1;
    i1 = hi < 0 ? 0 : (hi > H - 1 ? H - 1 : hi);
}

// NHWC bf16 2x bilinear upsample
__global__ __launch_bounds__(256) void k_up2n(const unsigned short* __restrict__ in,
                                              unsigned short* __restrict__ outp,
                                              int Hin, int C) {
    const int Ho = 2 * Hin;
    const int CG = C / 8;
    const int total = NB * Ho * Ho * CG;
    int t = blockIdx.x * 256 + threadIdx.x;
    if (t >= total) return;
    int cg = t % CG; int r = t / CG;
    int x = r % Ho; r /= Ho;
    int y = r % Ho; int b = r / Ho;
    int i0, i1, j0, j1; float fy, fx;
    bilin_axis(0.5f * y - 0.25f, Hin, i0, i1, fy);
    bilin_axis(0.5f * x - 0.25f, Hin, j0, j1, fx);
    const unsigned short* base = in + (size_t)b * Hin * Hin * C + cg * 8;
    const bf16x8 p00 = *(const bf16x8*)(base + (size_t)(i0 * Hin + j0) * C);
    const bf16x8 p01 = *(const bf16x8*)(base + (size_t)(i0 * Hin + j1) * C);
    const bf16x8 p10 = *(const bf16x8*)(base + (size_t)(i1 * Hin + j0) * C);
    const bf16x8 p11 = *(const bf16x8*)(base + (size_t)(i1 * Hin + j1) * C);
    bf16x8 o;
    #pragma unroll
    for (int e = 0; e < 8; ++e) {
        float v = (1.f - fy) * ((1.f - fx) * bf2f((unsigned short)p00[e]) + fx * bf2f((unsigned short)p01[e]))
                + fy        * ((1.f - fx) * bf2f((unsigned short)p10[e]) + fx * bf2f((unsigned short)p11[e]));
        o[e] = (short)f2bf(v);
    }
    *(bf16x8*)(outp + (size_t)t * 8) = o;
}

// ---------------- conv3: 1x1, 64->21, NHWC bf16 in -> NCHW f32 out ----------
__global__ __launch_bounds__(256) void k_conv3n(const unsigned short* __restrict__ in,
                                                const float* __restrict__ w,
                                                const float* __restrict__ bias,
                                                float* __restrict__ outp) {
    __shared__ float ws_[NCLS * 64];
    for (int i = threadIdx.x; i < NCLS * 64; i += 256) ws_[i] = w[i];
    __syncthreads();
    int t = blockIdx.x * 256 + threadIdx.x;
    if (t >= NB * 9216) return;
    int pix = t % 9216, b = t / 9216;
    float xv[64];
    const unsigned short* p = in + (size_t)t * 64;
    #pragma unroll
    for (int c = 0; c < 8; ++c) {
        bf16x8 v = *(const bf16x8*)(p + c * 8);
        #pragma unroll
        for (int e = 0; e < 8; ++e) xv[c * 8 + e] = bf2f((unsigned short)v[e]);
    }
    float* op = outp + (size_t)b * NCLS * 9216 + pix;
    #pragma unroll
    for (int o = 0; o < NCLS; ++o) {
        float acc = bias[o];
        #pragma unroll
        for (int ic = 0; ic < 64; ++ic) acc += ws_[o * 64 + ic] * xv[ic];
        op[(size_t)o * 9216] = acc;
    }
}

// ---------------- final resize 96 -> 384 (4x bilinear), f32 NCHW ------------
__global__ __launch_bounds__(256) void k_resize4(const float* __restrict__ in,
                                                 float* __restrict__ outp) {
    int t = blockIdx.x * 256 + threadIdx.x;
    if (t >= OUT_TOTAL) return;
    int x = t % IMGSZ; int r = t / IMGSZ; int y = r % IMGSZ; int bc = r / IMGSZ;
    int i0, i1, j0, j1; float fy, fx;
    bilin_axis(0.25f * y - 0.375f, 96, i0, i1, fy);
    bilin_axis(0.25f * x - 0.375f, 96, j0, j1, fx);
    const float* p = in + (size_t)bc * 9216;
    outp[t] = (1.f - fy) * ((1.f - fx) * p[i0 * 96 + j0] + fx * p[i0 * 96 + j1])
            + fy        * ((1.f - fx) * p[i1 * 96 + j0] + fx * p[i1 * 96 + j1]);
}

// ---------------- orchestration ----------------
extern "C" void kernel_launch(void* const* d_in, const int* in_sizes, int n_in,
                              void* d_out, int out_size, void* d_ws, size_t ws_size,
                              hipStream_t stream) {
    const float* img     = (const float*)d_in[0];
    const float* patch_w = (const float*)d_in[1];
    const float* patch_b = (const float*)d_in[2];
    const float* pos_emb = (const float*)d_in[3];
    const float* ln1_g   = (const float*)d_in[4];
    const float* ln1_b   = (const float*)d_in[5];
    const float* qkv_w   = (const float*)d_in[6];
    const float* out_w   = (const float*)d_in[7];
    const float* out_b   = (const float*)d_in[8];
    const float* alpha   = (const float*)d_in[9];
    const float* ln2_g   = (const float*)d_in[10];
    const float* ln2_b   = (const float*)d_in[11];
    const float* ff_w1   = (const float*)d_in[12];
    const float* ff_b1   = (const float*)d_in[13];
    const float* ff_w2   = (const float*)d_in[14];
    const float* ff_b2   = (const float*)d_in[15];
    const float* lnf_g   = (const float*)d_in[16];
    const float* lnf_b   = (const float*)d_in[17];
    const float* conv1_w = (const float*)d_in[18];
    const float* conv1_b = (const float*)d_in[19];
    const float* conv2_w = (const float*)d_in[20];
    const float* conv2_b = (const float*)d_in[21];
    const float* conv3_w = (const float*)d_in[22];
    const float* conv3_b = (const float*)d_in[23];

    // ---- workspace layout (~78 MB) ----
    float* x = (float*)d_ws;                                         // [9216][256] f32
    unsigned short* qkv_hi = (unsigned short*)(x + (size_t)NROWS * DMODEL); // [9216][512] (Q,K)
    unsigned short* qkv_lo = qkv_hi + (size_t)NROWS * QKS;           // [9216][512]
    unsigned short* xn_bf  = qkv_lo + (size_t)NROWS * QKS;           // [9216][256]
    unsigned short* ao_bf  = xn_bf + (size_t)NROWS * DMODEL;         // [9216][256]
    unsigned short* h_bf   = ao_bf + (size_t)NROWS * DMODEL;         // [9216][512]
    unsigned short* pA     = h_bf + (size_t)NROWS * DMLP;            // [9216][768]
    unsigned short* wts    = pA + (size_t)NROWS * NPD;
    unsigned short* pwt  = wts;                       // [256][768]
    unsigned short* qwt  = pwt  + 768 * 256;          // [6][768][256]
    unsigned short* owt  = qwt  + 6 * 768 * 256;      // [6][256][256]
    unsigned short* f1wt = owt  + 6 * 256 * 256;      // [6][512][256]
    unsigned short* f2wt = f1wt + 6 * 256 * 512;      // [6][256][512]
    unsigned short* c1wt = f2wt + 6 * 512 * 256;      // [128][9*256]
    unsigned short* c2wt = c1wt + 128 * 9 * 256;      // [64][9*128]
    unsigned short* vthi = c2wt + 64 * 9 * 128;       // [64*64][576]
    unsigned short* vtlo = vthi + (size_t)64 * 64 * NTOK;
    // conv-stage aliases (transformer buffers free by then)
    unsigned short* c1n = ao_bf;            // [16][24][24][128]
    unsigned short* u1n = h_bf;             // [16][48][48][128]
    unsigned short* c2n = xn_bf;            // [16][48][48][64]
    unsigned short* u2n = qkv_hi;           // [16][96][96][64] (spans hi+lo exactly)
    float* c3 = (float*)pA;                 // [16][21][96][96] f32

    // ---- weight casts ----
    k_castT<<<dim3(768, 1), 256, 0, stream>>>(patch_w, pwt, NPD, DMODEL);
    k_castT<<<dim3(768, 6), 256, 0, stream>>>(qkv_w, qwt, DMODEL, DQKV);
    k_castT<<<dim3(256, 6), 256, 0, stream>>>(out_w, owt, DMODEL, DMODEL);
    k_castT<<<dim3(512, 6), 256, 0, stream>>>(ff_w1, f1wt, DMODEL, DMLP);
    k_castT<<<dim3(512, 6), 256, 0, stream>>>(ff_w2, f2wt, DMLP, DMODEL);
    k_castConv<256><<<1152, 256, 0, stream>>>(conv1_w, c1wt, 128);
    k_castConv<128><<<288, 256, 0, stream>>>(conv2_w, c2wt, 64);

    // ---- patch embed + pos + LN1(layer0), fused ----
    k_patchify<<<(NROWS * NPD + 255) / 256, 256, 0, stream>>>(img, pA);
    k_gemm_ln<0><<<288, 256, 0, stream>>>(
        pA, pwt, patch_b, pos_emb, ln1_g, ln1_b, x, xn_bf, NPD, 288);

    // ---- transformer layers ----
    for (int l = 0; l < DEPTH; ++l) {
        // QKV GEMM: Q,K -> qkv hi/lo (stride 512); V -> vT hi/lo directly
        k_mm<128, 128, 8, 0><<<6 * 72, 256, 0, stream>>>(
            xn_bf, qwt + (size_t)l * DQKV * DMODEL, nullptr,
            nullptr, qkv_hi, qkv_lo, vthi, vtlo,
            NROWS, DQKV, DMODEL, 0, 0, 6, 72);
        k_attn<<<NBLK * NHEAD * NB, 512, 0, stream>>>(
            qkv_hi, qkv_lo, vthi, vtlo, alpha + l, ao_bf);
        // out-proj + bias + residual + LN2, fused
        k_gemm_ln<1><<<288, 256, 0, stream>>>(
            ao_bf, owt + (size_t)l * DMODEL * DMODEL, out_b + l * DMODEL, nullptr,
            ln2_g + l * DMODEL, ln2_b + l * DMODEL, x, xn_bf, DMODEL, 288);
        // ff1 + gelu
        k_mm<128, 128, 2, 0><<<4 * 72, 256, 0, stream>>>(
            xn_bf, f1wt + (size_t)l * DMLP * DMODEL, ff_b1 + l * DMLP,
            nullptr, h_bf, nullptr, nullptr, nullptr,
            NROWS, DMLP, DMODEL, 0, 0, 4, 72);
        // ff2 + bias + residual + LN(next layer's ln1, or lnf on last)
        const float* ng = (l + 1 < DEPTH) ? (ln1_g + (l + 1) * DMODEL) : lnf_g;
        const float* nb = (l + 1 < DEPTH) ? (ln1_b + (l + 1) * DMODEL) : lnf_b;
        k_gemm_ln<1><<<288, 256, 0, stream>>>(
            h_bf, f2wt + (size_t)l * DMODEL * DMLP, ff_b2 + l * DMODEL, nullptr,
            ng, nb, x, xn_bf, DMLP, 288);
    }

    // ---- head (xn_bf already = LNf output) ----
    k_mm<64, 128, 4, 256><<<1 * 144, 256, 0, stream>>>(
        xn_bf, c1wt, conv1_b, nullptr, c1n, nullptr, nullptr, nullptr,
        NROWS, 128, 9 * 256, 24, 24, 1, 144);
    k_up2n<<<(NB * 48 * 48 * 16 + 255) / 256, 256, 0, stream>>>(c1n, u1n, 24, 128);
    k_mm<128, 64, 4, 128><<<1 * 288, 256, 0, stream>>>(
        u1n, c2wt, conv2_b, nullptr, c2n, nullptr, nullptr, nullptr,
        NB * 48 * 48, 64, 9 * 128, 48, 48, 1, 288);
    k_up2n<<<(NB * 96 * 96 * 8 + 255) / 256, 256, 0, stream>>>(c2n, u2n, 48, 64);
    k_conv3n<<<(NB * 9216 + 255) / 256, 256, 0, stream>>>(u2n, conv3_w, conv3_b, c3);
    k_resize4<<<(OUT_TOTAL + 255) / 256, 256, 0, stream>>>(c3, (float*)d_out);
}

// Round 10
// 1292.794 us; speedup vs baseline: 9.4771x; 1.0099x over previous
//
#include <hip/hip_runtime.h>
#include <cfloat>
#include <cmath>

// ---------------- problem constants ----------------
constexpr int NB    = 16;    // batch
constexpr int IMGSZ = 384;
constexpr int PSZ   = 16;
constexpr int NCH   = 3;
constexpr int DMODEL= 256;
constexpr int DEPTH = 6;
constexpr int NHEAD = 4;
constexpr int DHEAD = 64;
constexpr int DQKV  = 768;   // 3*INNER
constexpr int QKS   = 512;   // Q,K row stride (V lives only in vT)
constexpr int DMLP  = 512;
constexpr int NCLS  = 21;
constexpr int HPATCH= 24;    // IMG/P
constexpr int NTOK  = 576;   // HP*HP
constexpr int NPD   = 768;   // C*P*P
constexpr int TOPK  = 16;
constexpr int NROWS = NB * NTOK;          // 9216
constexpr int OUT_TOTAL = NB * NCLS * IMGSZ * IMGSZ; // 49545216

// attention tiling
constexpr int RPB    = 16;           // query rows per block
constexpr int NBLK   = NTOK / RPB;   // 36 blocks per (b,h)
constexpr int CHUNK  = 64;           // key/value chunk
constexpr int NCHUNK = NTOK / CHUNK; // 9
constexpr int SCP    = 577;          // score row stride (f32)
constexpr int PPS    = 584;          // full-P row stride (bf16)

typedef __attribute__((ext_vector_type(8))) short bf16x8;
typedef __attribute__((ext_vector_type(4))) float f32x4;

__device__ __forceinline__ unsigned short f2bf(float f) {
    unsigned u = __builtin_bit_cast(unsigned, f);
    unsigned r = (u + 0x7FFFu + ((u >> 16) & 1u)) >> 16;
    return (unsigned short)r;
}
__device__ __forceinline__ float bf2f(unsigned short h) {
    unsigned u = ((unsigned)h) << 16;
    return __builtin_bit_cast(float, u);
}

// ---------------- weight cast+transpose: W[L][K][N] f32 -> Wt[L][N][K] bf16 --
__global__ __launch_bounds__(256) void k_castT(const float* __restrict__ src,
                                               unsigned short* __restrict__ dst,
                                               int K, int N) {
    int t = blockIdx.x * 256 + threadIdx.x;
    if (t >= K * N) return;
    size_t base = (size_t)blockIdx.y * K * N;
    int n = t / K, k = t - n * K;
    dst[base + t] = f2bf(src[base + (size_t)k * N + n]);
}

// conv w [OC][IC][3][3] f32 -> [OC][9][IC] bf16 (tap-major K)
template <int IC>
__global__ __launch_bounds__(256) void k_castConv(const float* __restrict__ src,
                                                  unsigned short* __restrict__ dst,
                                                  int OC) {
    int t = blockIdx.x * 256 + threadIdx.x;
    if (t >= OC * 9 * IC) return;
    int oc = t / (9 * IC);
    int r = t - oc * 9 * IC;
    int tap = r / IC, ic = r - tap * IC;
    dst[t] = f2bf(src[((size_t)(oc * IC + ic)) * 9 + tap]);
}

// ---------------- patchify: img[B,3,384,384] -> A[9216,768] bf16 ------------
__global__ __launch_bounds__(256) void k_patchify(const float* __restrict__ img,
                                                  unsigned short* __restrict__ A) {
    int t = blockIdx.x * 256 + threadIdx.x;
    if (t >= NROWS * NPD) return;
    int r  = t / NPD, pd = t - r * NPD;
    int b  = r / NTOK, n = r - b * NTOK;
    int hy = n / HPATCH, hx = n - hy * HPATCH;
    int c  = pd % NCH;  int q = pd / NCH;
    int p2 = q % PSZ;   int p1 = q / PSZ;
    A[t] = f2bf(img[(((size_t)(b * NCH + c)) * IMGSZ + hy * PSZ + p1) * IMGSZ + hx * PSZ + p2]);
}

// ---------------- unified bf16 MFMA GEMM / implicit conv --------------------
// out[M,N] = A[M,K](bf16) @ Wt[N,K]^T(bf16), fp32 accumulate.
// EPI: 2 bias+gelu->bf16 | 4 bias+relu->bf16
//      8 qkv: cols<512 -> hi/lo @stride 512; cols>=512 -> vT hi/lo only
// CIN>0: gather A from NHWC [NB][H][W][CIN] with 3x3 taps (K = 9*CIN, tap-major)
// Flat grid of gxd*gyd blocks; XCD-aware swizzle keyed on M-tile (gyd%8==0).
template <int BM, int BN, int EPI, int CIN>
__global__ __launch_bounds__(256) void k_mm(
    const unsigned short* __restrict__ Abf,
    const unsigned short* __restrict__ Wt,
    const float* __restrict__ bias,
    float* __restrict__ outf,
    unsigned short* __restrict__ outb,
    unsigned short* __restrict__ outb2,
    unsigned short* __restrict__ vth,
    unsigned short* __restrict__ vtl,
    int M, int Nn, int K, int H, int Wd, int gxd, int gyd)
{
    constexpr int MF = BM / 32;
    constexpr int NF = BN / 32;
    constexpr bool GATHER = (CIN > 0);
    constexpr int AREP = BM * 4 / 256;
    constexpr int BREP = BN * 4 / 256;
    __shared__ __align__(16) short As[4][BM][8];
    __shared__ __align__(16) short Bs[4][BN][8];
    const int tid = threadIdx.x;
    // XCD swizzle: all blocks sharing an M-tile window land on one XCD
    const int p = blockIdx.x;
    const int xr = p & 7, xq = p >> 3;
    const int bm = (xr * (gyd >> 3) + xq / gxd) * BM;
    const int bn = (xq % gxd) * BN;
    const int lane = tid & 63, wid = tid >> 6;
    const int wm = wid >> 1, wn = wid & 1;
    const int l15 = lane & 15, lg = lane >> 4;

    int pb_[AREP], py_[AREP], px_[AREP];
    if (GATHER) {
        #pragma unroll
        for (int rep = 0; rep < AREP; ++rep) {
            int idx = rep * 256 + tid;
            int m = idx >> 2;
            int pix = bm + m;
            px_[rep] = pix % Wd;
            int r = pix / Wd;
            py_[rep] = r % H;
            pb_[rep] = r / H;
        }
    }

    f32x4 acc[MF][NF];
    #pragma unroll
    for (int i = 0; i < MF; ++i)
        #pragma unroll
        for (int j = 0; j < NF; ++j)
            acc[i][j] = (f32x4){0.f, 0.f, 0.f, 0.f};

    for (int k0 = 0; k0 < K; k0 += 32) {
        #pragma unroll
        for (int rep = 0; rep < AREP; ++rep) {
            int idx = rep * 256 + tid;
            int m = idx >> 2, kg = idx & 3;
            if (!GATHER) {
                *(bf16x8*)As[kg][m] =
                    *(const bf16x8*)(Abf + (size_t)(bm + m) * K + k0 + kg * 8);
            } else {
                int k = k0 + kg * 8;
                int tap = k / CIN;
                int ic = k - tap * CIN;
                int dy = tap / 3 - 1, dx = tap % 3 - 1;
                int yy = py_[rep] + dy, xx = px_[rep] + dx;
                bf16x8 v = (bf16x8){0, 0, 0, 0, 0, 0, 0, 0};
                if ((unsigned)yy < (unsigned)H && (unsigned)xx < (unsigned)Wd)
                    v = *(const bf16x8*)(Abf +
                        ((size_t)((pb_[rep] * H + yy) * Wd + xx)) * CIN + ic);
                *(bf16x8*)As[kg][m] = v;
            }
        }
        #pragma unroll
        for (int rep = 0; rep < BREP; ++rep) {
            int idx = rep * 256 + tid;
            int n = idx >> 2, kg = idx & 3;
            *(bf16x8*)Bs[kg][n] =
                *(const bf16x8*)(Wt + (size_t)(bn + n) * K + k0 + kg * 8);
        }
        __syncthreads();
        bf16x8 af[MF], bfv[NF];
        #pragma unroll
        for (int i = 0; i < MF; ++i)
            af[i] = *(const bf16x8*)As[lg][wm * (BM / 2) + i * 16 + l15];
        #pragma unroll
        for (int j = 0; j < NF; ++j)
            bfv[j] = *(const bf16x8*)Bs[lg][wn * (BN / 2) + j * 16 + l15];
        #pragma unroll
        for (int i = 0; i < MF; ++i)
            #pragma unroll
            for (int j = 0; j < NF; ++j)
                acc[i][j] = __builtin_amdgcn_mfma_f32_16x16x32_bf16(
                    af[i], bfv[j], acc[i][j], 0, 0, 0);
        __syncthreads();
    }

    if constexpr (EPI == 8) {
        #pragma unroll
        for (int i = 0; i < MF; ++i) {
            const int row0 = bm + wm * (BM / 2) + i * 16 + lg * 4;
            #pragma unroll
            for (int j = 0; j < NF; ++j) {
                const int col = bn + wn * (BN / 2) + j * 16 + l15;
                if (col < 512) {   // uniform per block (bn multiple of 128)
                    #pragma unroll
                    for (int r = 0; r < 4; ++r) {
                        float v = acc[i][j][r];
                        unsigned short hi = f2bf(v);
                        outb[(size_t)(row0 + r) * QKS + col] = hi;
                        outb2[(size_t)(row0 + r) * QKS + col] = f2bf(v - bf2f(hi));
                    }
                } else {
                    const int d = col - 512, hh = d >> 6, dd = d & 63;
                    const int bb = row0 / NTOK, n = row0 % NTOK;   // 4 rows same bb
                    unsigned long long ph = 0ull, pl = 0ull;
                    #pragma unroll
                    for (int r = 0; r < 4; ++r) {
                        float v = acc[i][j][r];
                        unsigned short hi = f2bf(v);
                        unsigned short lo = f2bf(v - bf2f(hi));
                        ph |= (unsigned long long)hi << (16 * r);
                        pl |= (unsigned long long)lo << (16 * r);
                    }
                    const size_t off = (size_t)((bb * NHEAD + hh) * DHEAD + dd) * NTOK + n;
                    *(unsigned long long*)(vth + off) = ph;
                    *(unsigned long long*)(vtl + off) = pl;
                }
            }
        }
    } else {
        #pragma unroll
        for (int i = 0; i < MF; ++i) {
            const int row0 = bm + wm * (BM / 2) + i * 16 + lg * 4;
            #pragma unroll
            for (int j = 0; j < NF; ++j) {
                const int col = bn + wn * (BN / 2) + j * 16 + l15;
                #pragma unroll
                for (int r = 0; r < 4; ++r) {
                    const int rr = row0 + r;
                    float v = acc[i][j][r] + bias[col];
                    if (EPI == 2) v = 0.5f * v * (1.0f + erff(v * 0.70710678118f));
                    if (EPI == 4) v = fmaxf(v, 0.f);
                    outb[(size_t)rr * Nn + col] = f2bf(v);
                }
            }
        }
    }
}

// ---------------- GEMM + bias(+residual/posemb) + LayerNorm fused -----------
template <int RES>
__global__ __launch_bounds__(256) void k_gemm_ln(
    const unsigned short* __restrict__ Abf,
    const unsigned short* __restrict__ Wt,
    const float* __restrict__ bias,
    const float* __restrict__ extra,
    const float* __restrict__ lng,
    const float* __restrict__ lnb,
    float* __restrict__ x,
    unsigned short* __restrict__ xn,
    int K, int gyd)
{
    constexpr int BM = 32;
    __shared__ __align__(16) short As[4][BM][8];
    __shared__ __align__(16) short Bs[4][256][8];
    __shared__ float redS[BM][4];
    __shared__ float redQ[BM][4];
    const int tid = threadIdx.x;
    const int p = blockIdx.x;
    const int xr = p & 7, xq = p >> 3;
    const int bm = (xr * (gyd >> 3) + xq) * BM;
    const int lane = tid & 63, wn = tid >> 6;
    const int l15 = lane & 15, lg = lane >> 4;

    f32x4 acc[2][4];
    #pragma unroll
    for (int i = 0; i < 2; ++i)
        #pragma unroll
        for (int j = 0; j < 4; ++j)
            acc[i][j] = (f32x4){0.f, 0.f, 0.f, 0.f};

    for (int k0 = 0; k0 < K; k0 += 32) {
        if (tid < BM * 4) {
            int m = tid >> 2, kg = tid & 3;
            *(bf16x8*)As[kg][m] = *(const bf16x8*)(Abf + (size_t)(bm + m) * K + k0 + kg * 8);
        }
        #pragma unroll
        for (int rep = 0; rep < 4; ++rep) {
            int idx = rep * 256 + tid;
            int n = idx >> 2, kg = idx & 3;
            *(bf16x8*)Bs[kg][n] = *(const bf16x8*)(Wt + (size_t)n * K + k0 + kg * 8);
        }
        __syncthreads();
        bf16x8 af[2], bfv[4];
        #pragma unroll
        for (int i = 0; i < 2; ++i)
            af[i] = *(const bf16x8*)As[lg][i * 16 + l15];
        #pragma unroll
        for (int j = 0; j < 4; ++j)
            bfv[j] = *(const bf16x8*)Bs[lg][wn * 64 + j * 16 + l15];
        #pragma unroll
        for (int i = 0; i < 2; ++i)
            #pragma unroll
            for (int j = 0; j < 4; ++j)
                acc[i][j] = __builtin_amdgcn_mfma_f32_16x16x32_bf16(
                    af[i], bfv[j], acc[i][j], 0, 0, 0);
        __syncthreads();
    }

    // ---- epilogue: bias (+res/pos), write x, keep v in acc ----
    #pragma unroll
    for (int i = 0; i < 2; ++i) {
        #pragma unroll
        for (int j = 0; j < 4; ++j) {
            const int col = wn * 64 + j * 16 + l15;
            #pragma unroll
            for (int r = 0; r < 4; ++r) {
                const int rr = bm + i * 16 + lg * 4 + r;
                float v = acc[i][j][r] + bias[col];
                if (RES) v += x[(size_t)rr * DMODEL + col];
                else     v += extra[(size_t)(rr % NTOK) * DMODEL + col];
                x[(size_t)rr * DMODEL + col] = v;
                acc[i][j][r] = v;
            }
        }
    }
    // ---- pass 1: mean ----
    float s[2][4];
    #pragma unroll
    for (int i = 0; i < 2; ++i)
        #pragma unroll
        for (int r = 0; r < 4; ++r)
            s[i][r] = ((acc[i][0][r] + acc[i][1][r]) + acc[i][2][r]) + acc[i][3][r];
    #pragma unroll
    for (int off = 1; off < 16; off <<= 1)
        #pragma unroll
        for (int i = 0; i < 2; ++i)
            #pragma unroll
            for (int r = 0; r < 4; ++r)
                s[i][r] += __shfl_xor(s[i][r], off);
    if (l15 == 0)
        #pragma unroll
        for (int i = 0; i < 2; ++i)
            #pragma unroll
            for (int r = 0; r < 4; ++r)
                redS[i * 16 + lg * 4 + r][wn] = s[i][r];
    __syncthreads();
    float mu[2][4];
    #pragma unroll
    for (int i = 0; i < 2; ++i)
        #pragma unroll
        for (int r = 0; r < 4; ++r) {
            const float* q = redS[i * 16 + lg * 4 + r];
            mu[i][r] = (((q[0] + q[1]) + q[2]) + q[3]) * (1.0f / DMODEL);
        }
    // ---- pass 2: variance ----
    float qq[2][4];
    #pragma unroll
    for (int i = 0; i < 2; ++i)
        #pragma unroll
        for (int r = 0; r < 4; ++r) {
            float d0 = acc[i][0][r] - mu[i][r], d1 = acc[i][1][r] - mu[i][r];
            float d2 = acc[i][2][r] - mu[i][r], d3 = acc[i][3][r] - mu[i][r];
            qq[i][r] = ((d0 * d0 + d1 * d1) + d2 * d2) + d3 * d3;
        }
    #pragma unroll
    for (int off = 1; off < 16; off <<= 1)
        #pragma unroll
        for (int i = 0; i < 2; ++i)
            #pragma unroll
            for (int r = 0; r < 4; ++r)
                qq[i][r] += __shfl_xor(qq[i][r], off);
    if (l15 == 0)
        #pragma unroll
        for (int i = 0; i < 2; ++i)
            #pragma unroll
            for (int r = 0; r < 4; ++r)
                redQ[i * 16 + lg * 4 + r][wn] = qq[i][r];
    __syncthreads();
    #pragma unroll
    for (int i = 0; i < 2; ++i) {
        #pragma unroll
        for (int r = 0; r < 4; ++r) {
            const float* q = redQ[i * 16 + lg * 4 + r];
            float var = (((q[0] + q[1]) + q[2]) + q[3]) * (1.0f / DMODEL);
            float rstd = rsqrtf(var + 1e-5f);
            const int rr = bm + i * 16 + lg * 4 + r;
            #pragma unroll
            for (int j = 0; j < 4; ++j) {
                const int col = wn * 64 + j * 16 + l15;
                float o = (acc[i][j][r] - mu[i][r]) * rstd * lng[col] + lnb[col];
                xn[(size_t)rr * DMODEL + col] = f2bf(o);
            }
        }
    }
}

// ---------------- wave-private hi/lo fragment quad (2 ksl x hi/lo) ----------
struct KF { bf16x8 h0, h1, l0, l1; };
__device__ __forceinline__ KF ldkf(const unsigned short* __restrict__ hi,
                                   const unsigned short* __restrict__ lo,
                                   size_t off) {
    KF f;
    f.h0 = *(const bf16x8*)(hi + off);
    f.h1 = *(const bf16x8*)(hi + off + 32);
    f.l0 = *(const bf16x8*)(lo + off);
    f.l1 = *(const bf16x8*)(lo + off + 32);
    return f;
}

// ---------------- MFMA hybrid attention, 16 rows/block, 512 threads ---------
// 8 waves (par = w>>2 chunk parity, ct = w&3 column tile).
// After score pull the scp buffer is dead -> full P hi/lo [2][16][584]
// overlays it. P written once, ONE barrier, then the PV loop runs
// barrier-free with 1-chunk V prefetch. Barriers: 11 -> 5.
__global__ __launch_bounds__(512, 8) void k_attn(
    const unsigned short* __restrict__ qhi,
    const unsigned short* __restrict__ qlo,
    const unsigned short* __restrict__ vthi,
    const unsigned short* __restrict__ vtlo,
    const float* __restrict__ alpha_l,
    unsigned short* __restrict__ ao) {
    __shared__ __align__(16) unsigned char ub[2 * RPB * PPS * 2];  // 37376 B
    float* scp = (float*)ub;                  // [16][577] f32 (dead after pull)
    short* php = (short*)ub;                  // [2hl][16][584] bf16 (overlay)
    float* red = (float*)ub;                  // [64][17] f32 (overlay, post-PV)

    const int tid = threadIdx.x;
    const int lane = tid & 63;
    const int w = tid >> 6;                   // 0..7
    const int par = w >> 2;                   // chunk parity handled by this wave
    const int ct = w & 3;                     // column tile
    const int l15 = lane & 15, lg = lane >> 4;
    const int xr = blockIdx.x & 7, xq = blockIdx.x >> 3;
    const int g = xr + 8 * (xq / NBLK);       // group = b*4+h
    const int b = g >> 2, h = g & 3;
    const int i0 = (xq % NBLK) * RPB;

    // ---- Q fragments (A operand), wave-uniform: rows i0+l15 ----
    bf16x8 aqh0, aqh1, aql0, aql1;
    {
        const size_t qoff = (size_t)(b * NTOK + i0 + l15) * QKS + h * DHEAD + lg * 8;
        aqh0 = *(const bf16x8*)(qhi + qoff);
        aqh1 = *(const bf16x8*)(qhi + qoff + 32);
        aql0 = *(const bf16x8*)(qlo + qoff);
        aql1 = *(const bf16x8*)(qlo + qoff + 32);
    }

    // ---- score phase: chunks of this wave's parity ----
    const size_t kRow = (size_t)(b * NTOK + ct * 16 + l15) * QKS + DMODEL + h * DHEAD + lg * 8;
    for (int c = par; c < NCHUNK; c += 2) {
        KF kc = ldkf(qhi, qlo, kRow + (size_t)c * CHUNK * QKS);
        f32x4 sD = (f32x4){0.f, 0.f, 0.f, 0.f};
        sD = __builtin_amdgcn_mfma_f32_16x16x32_bf16(aqh0, kc.h0, sD, 0, 0, 0);
        sD = __builtin_amdgcn_mfma_f32_16x16x32_bf16(aqh0, kc.l0, sD, 0, 0, 0);
        sD = __builtin_amdgcn_mfma_f32_16x16x32_bf16(aql0, kc.h0, sD, 0, 0, 0);
        sD = __builtin_amdgcn_mfma_f32_16x16x32_bf16(aqh1, kc.h1, sD, 0, 0, 0);
        sD = __builtin_amdgcn_mfma_f32_16x16x32_bf16(aqh1, kc.l1, sD, 0, 0, 0);
        sD = __builtin_amdgcn_mfma_f32_16x16x32_bf16(aql1, kc.h1, sD, 0, 0, 0);
        const int col = c * CHUNK + ct * 16 + l15;
        #pragma unroll
        for (int r = 0; r < 4; ++r)
            scp[(lg * 4 + r) * SCP + col] = sD[r] * 0.125f;
    }
    __syncthreads();   // all scores written

    // ---- pull scores to regs (wave w owns rows 2w, 2w+1) ----
    float o_[2][9];
    const int r0 = 2 * w;
    #pragma unroll
    for (int rr = 0; rr < 2; ++rr)
        #pragma unroll
        for (int t = 0; t < 9; ++t)
            o_[rr][t] = scp[(r0 + rr) * SCP + t * 64 + lane];
    __syncthreads();   // score reads done -> scp region reusable as P

    // ---- top-16: iteration-outer, 2 rows interleaved ----
    unsigned msk[2] = {0u, 0u};
    float M_[2];
    for (int k = 0; k < TOPK; ++k) {
        float lm[2];
        #pragma unroll
        for (int rr = 0; rr < 2; ++rr) {
            float m0 = -FLT_MAX;
            #pragma unroll
            for (int t = 0; t < 9; ++t) {
                float v = ((msk[rr] >> t) & 1u) ? -FLT_MAX : o_[rr][t];
                m0 = fmaxf(m0, v);
            }
            lm[rr] = m0;
        }
        #pragma unroll
        for (int off = 1; off < 64; off <<= 1) {
            #pragma unroll
            for (int rr = 0; rr < 2; ++rr)
                lm[rr] = fmaxf(lm[rr], __shfl_xor(lm[rr], off));
        }
        if (k == 0) {
            #pragma unroll
            for (int rr = 0; rr < 2; ++rr) M_[rr] = lm[rr];
        }
        #pragma unroll
        for (int rr = 0; rr < 2; ++rr) {
            int js = -1;
            #pragma unroll
            for (int t = 0; t < 9; ++t) {
                if (js < 0) {   // wave-uniform guard (js from ballot is uniform)
                    unsigned long long bal =
                        __ballot((((msk[rr] >> t) & 1u) == 0u) && (o_[rr][t] == lm[rr]));
                    if (bal) js = t * 64 + (int)__builtin_ctzll(bal);
                }
            }
            if ((js & 63) == lane) msk[rr] |= 1u << (js >> 6);
        }
    }

    // ---- softmax denominators + coefficients ----
    const float al = fminf(fmaxf(alpha_l[0], 0.f), 1.f);
    float gs[2], ss[2];
    #pragma unroll
    for (int rr = 0; rr < 2; ++rr) {
        float g_ = 0.f, s_ = 0.f;
        #pragma unroll
        for (int t = 0; t < 9; ++t) {
            float e = __expf(o_[rr][t] - M_[rr]);
            g_ += e;
            if ((msk[rr] >> t) & 1u) s_ += e;
        }
        gs[rr] = g_; ss[rr] = s_;
    }
    #pragma unroll
    for (int off = 1; off < 64; off <<= 1) {
        #pragma unroll
        for (int rr = 0; rr < 2; ++rr) {
            gs[rr] += __shfl_xor(gs[rr], off);
            ss[rr] += __shfl_xor(ss[rr], off);
        }
    }
    float ca[2], cs[2];
    #pragma unroll
    for (int rr = 0; rr < 2; ++rr) {
        ca[rr] = al / gs[rr];
        cs[rr] = (1.f - al) / ss[rr];
    }

    // ---- write FULL P hi/lo (rows 2w, 2w+1 over all 9 chunks) ----
    #pragma unroll
    for (int rr = 0; rr < 2; ++rr) {
        const int row = r0 + rr;
        #pragma unroll
        for (int t = 0; t < 9; ++t) {
            float e = __expf(o_[rr][t] - M_[rr]);
            float wv = e * (ca[rr] + (((msk[rr] >> t) & 1u) ? cs[rr] : 0.f));
            unsigned short hi = f2bf(wv);
            php[row * PPS + t * 64 + lane] = (short)hi;
            php[RPB * PPS + row * PPS + t * 64 + lane] = (short)f2bf(wv - bf2f(hi));
        }
    }
    __syncthreads();   // full P visible

    // ---- PV phase: barrier-free, parity chunks, V prefetched 1 ahead ----
    const size_t vRow = (size_t)((b * NHEAD + h) * DHEAD + ct * 16 + l15) * NTOK + lg * 8;
    f32x4 acc = (f32x4){0.f, 0.f, 0.f, 0.f};
    KF vc = ldkf(vthi, vtlo, vRow + (size_t)par * CHUNK);
    for (int c = par; c < NCHUNK; c += 2) {
        KF vn;
        if (c + 2 < NCHUNK)
            vn = ldkf(vthi, vtlo, vRow + (size_t)(c + 2) * CHUNK);
        const short* pr = php + l15 * PPS + c * 64 + lg * 8;
        bf16x8 ah0 = *(const bf16x8*)(pr);
        bf16x8 ah1 = *(const bf16x8*)(pr + 32);
        bf16x8 al0 = *(const bf16x8*)(pr + RPB * PPS);
        bf16x8 al1 = *(const bf16x8*)(pr + RPB * PPS + 32);
        acc = __builtin_amdgcn_mfma_f32_16x16x32_bf16(ah0, vc.h0, acc, 0, 0, 0);
        acc = __builtin_amdgcn_mfma_f32_16x16x32_bf16(ah0, vc.l0, acc, 0, 0, 0);
        acc = __builtin_amdgcn_mfma_f32_16x16x32_bf16(al0, vc.h0, acc, 0, 0, 0);
        acc = __builtin_amdgcn_mfma_f32_16x16x32_bf16(ah1, vc.h1, acc, 0, 0, 0);
        acc = __builtin_amdgcn_mfma_f32_16x16x32_bf16(ah1, vc.l1, acc, 0, 0, 0);
        acc = __builtin_amdgcn_mfma_f32_16x16x32_bf16(al1, vc.h1, acc, 0, 0, 0);
        if (c + 2 < NCHUNK) vc = vn;
    }
    __syncthreads();   // all P reads done -> red may overlay
    if (par == 1) {
        #pragma unroll
        for (int r = 0; r < 4; ++r)
            red[(ct * 16 + l15) * 17 + lg * 4 + r] = acc[r];
    }
    __syncthreads();
    if (par == 0) {
        const int qrow = i0 + lg * 4;
        const int dcol = h * DHEAD + ct * 16 + l15;
        #pragma unroll
        for (int r = 0; r < 4; ++r) {
            float v = acc[r] + red[(ct * 16 + l15) * 17 + lg * 4 + r];
            ao[(size_t)(b * NTOK + qrow + r) * DMODEL + dcol] = f2bf(v);
        }
    }
}

// ---------------- bilinear helpers (jax.image.resize half-pixel) ------------
__device__ __forceinline__ void bilin_axis(float sF, int H, int& i0, int& i1, float& f) {
    float fl = floorf(sF);
    f = sF - fl;
    int lo = (int)fl;
    i0 = lo < 0 ? 0 : (lo > H - 1 ? H - 1 : lo);
    int hi = lo + 1;
    i1 = hi < 0 ? 0 : (hi > H - 1 ? H - 1 : hi);
}

// NHWC bf16 2x bilinear upsample
__global__ __launch_bounds__(256) void k_up2n(const unsigned short* __restrict__ in,
                                              unsigned short* __restrict__ outp,
                                              int Hin, int C) {
    const int Ho = 2 * Hin;
    const int CG = C / 8;
    const int total = NB * Ho * Ho * CG;
    int t = blockIdx.x * 256 + threadIdx.x;
    if (t >= total) return;
    int cg = t % CG; int r = t / CG;
    int x = r % Ho; r /= Ho;
    int y = r % Ho; int b = r / Ho;
    int i0, i1, j0, j1; float fy, fx;
    bilin_axis(0.5f * y - 0.25f, Hin, i0, i1, fy);
    bilin_axis(0.5f * x - 0.25f, Hin, j0, j1, fx);
    const unsigned short* base = in + (size_t)b * Hin * Hin * C + cg * 8;
    const bf16x8 p00 = *(const bf16x8*)(base + (size_t)(i0 * Hin + j0) * C);
    const bf16x8 p01 = *(const bf16x8*)(base + (size_t)(i0 * Hin + j1) * C);
    const bf16x8 p10 = *(const bf16x8*)(base + (size_t)(i1 * Hin + j0) * C);
    const bf16x8 p11 = *(const bf16x8*)(base + (size_t)(i1 * Hin + j1) * C);
    bf16x8 o;
    #pragma unroll
    for (int e = 0; e < 8; ++e) {
        float v = (1.f - fy) * ((1.f - fx) * bf2f((unsigned short)p00[e]) + fx * bf2f((unsigned short)p01[e]))
                + fy        * ((1.f - fx) * bf2f((unsigned short)p10[e]) + fx * bf2f((unsigned short)p11[e]));
        o[e] = (short)f2bf(v);
    }
    *(bf16x8*)(outp + (size_t)t * 8) = o;
}

// ---------------- conv3: 1x1, 64->21, NHWC bf16 in -> NCHW f32 out ----------
__global__ __launch_bounds__(256) void k_conv3n(const unsigned short* __restrict__ in,
                                                const float* __restrict__ w,
                                                const float* __restrict__ bias,
                                                float* __restrict__ outp) {
    __shared__ float ws_[NCLS * 64];
    for (int i = threadIdx.x; i < NCLS * 64; i += 256) ws_[i] = w[i];
    __syncthreads();
    int t = blockIdx.x * 256 + threadIdx.x;
    if (t >= NB * 9216) return;
    int pix = t % 9216, b = t / 9216;
    float xv[64];
    const unsigned short* p = in + (size_t)t * 64;
    #pragma unroll
    for (int c = 0; c < 8; ++c) {
        bf16x8 v = *(const bf16x8*)(p + c * 8);
        #pragma unroll
        for (int e = 0; e < 8; ++e) xv[c * 8 + e] = bf2f((unsigned short)v[e]);
    }
    float* op = outp + (size_t)b * NCLS * 9216 + pix;
    #pragma unroll
    for (int o = 0; o < NCLS; ++o) {
        float acc = bias[o];
        #pragma unroll
        for (int ic = 0; ic < 64; ++ic) acc += ws_[o * 64 + ic] * xv[ic];
        op[(size_t)o * 9216] = acc;
    }
}

// ---------------- final resize 96 -> 384 (4x bilinear), f32 NCHW ------------
__global__ __launch_bounds__(256) void k_resize4(const float* __restrict__ in,
                                                 float* __restrict__ outp) {
    int t = blockIdx.x * 256 + threadIdx.x;
    if (t >= OUT_TOTAL) return;
    int x = t % IMGSZ; int r = t / IMGSZ; int y = r % IMGSZ; int bc = r / IMGSZ;
    int i0, i1, j0, j1; float fy, fx;
    bilin_axis(0.25f * y - 0.375f, 96, i0, i1, fy);
    bilin_axis(0.25f * x - 0.375f, 96, j0, j1, fx);
    const float* p = in + (size_t)bc * 9216;
    outp[t] = (1.f - fy) * ((1.f - fx) * p[i0 * 96 + j0] + fx * p[i0 * 96 + j1])
            + fy        * ((1.f - fx) * p[i1 * 96 + j0] + fx * p[i1 * 96 + j1]);
}

// ---------------- orchestration ----------------
extern "C" void kernel_launch(void* const* d_in, const int* in_sizes, int n_in,
                              void* d_out, int out_size, void* d_ws, size_t ws_size,
                              hipStream_t stream) {
    const float* img     = (const float*)d_in[0];
    const float* patch_w = (const float*)d_in[1];
    const float* patch_b = (const float*)d_in[2];
    const float* pos_emb = (const float*)d_in[3];
    const float* ln1_g   = (const float*)d_in[4];
    const float* ln1_b   = (const float*)d_in[5];
    const float* qkv_w   = (const float*)d_in[6];
    const float* out_w   = (const float*)d_in[7];
    const float* out_b   = (const float*)d_in[8];
    const float* alpha   = (const float*)d_in[9];
    const float* ln2_g   = (const float*)d_in[10];
    const float* ln2_b   = (const float*)d_in[11];
    const float* ff_w1   = (const float*)d_in[12];
    const float* ff_b1   = (const float*)d_in[13];
    const float* ff_w2   = (const float*)d_in[14];
    const float* ff_b2   = (const float*)d_in[15];
    const float* lnf_g   = (const float*)d_in[16];
    const float* lnf_b   = (const float*)d_in[17];
    const float* conv1_w = (const float*)d_in[18];
    const float* conv1_b = (const float*)d_in[19];
    const float* conv2_w = (const float*)d_in[20];
    const float* conv2_b = (const float*)d_in[21];
    const float* conv3_w = (const float*)d_in[22];
    const float* conv3_b = (const float*)d_in[23];

    // ---- workspace layout (~78 MB) ----
    float* x = (float*)d_ws;                                         // [9216][256] f32
    unsigned short* qkv_hi = (unsigned short*)(x + (size_t)NROWS * DMODEL); // [9216][512] (Q,K)
    unsigned short* qkv_lo = qkv_hi + (size_t)NROWS * QKS;           // [9216][512]
    unsigned short* xn_bf  = qkv_lo + (size_t)NROWS * QKS;           // [9216][256]
    unsigned short* ao_bf  = xn_bf + (size_t)NROWS * DMODEL;         // [9216][256]
    unsigned short* h_bf   = ao_bf + (size_t)NROWS * DMODEL;         // [9216][512]
    unsigned short* pA     = h_bf + (size_t)NROWS * DMLP;            // [9216][768]
    unsigned short* wts    = pA + (size_t)NROWS * NPD;
    unsigned short* pwt  = wts;                       // [256][768]
    unsigned short* qwt  = pwt  + 768 * 256;          // [6][768][256]
    unsigned short* owt  = qwt  + 6 * 768 * 256;      // [6][256][256]
    unsigned short* f1wt = owt  + 6 * 256 * 256;      // [6][512][256]
    unsigned short* f2wt = f1wt + 6 * 256 * 512;      // [6][256][512]
    unsigned short* c1wt = f2wt + 6 * 512 * 256;      // [128][9*256]
    unsigned short* c2wt = c1wt + 128 * 9 * 256;      // [64][9*128]
    unsigned short* vthi = c2wt + 64 * 9 * 128;       // [64*64][576]
    unsigned short* vtlo = vthi + (size_t)64 * 64 * NTOK;
    // conv-stage aliases (transformer buffers free by then)
    unsigned short* c1n = ao_bf;            // [16][24][24][128]
    unsigned short* u1n = h_bf;             // [16][48][48][128]
    unsigned short* c2n = xn_bf;            // [16][48][48][64]
    unsigned short* u2n = qkv_hi;           // [16][96][96][64] (spans hi+lo exactly)
    float* c3 = (float*)pA;                 // [16][21][96][96] f32

    // ---- weight casts ----
    k_castT<<<dim3(768, 1), 256, 0, stream>>>(patch_w, pwt, NPD, DMODEL);
    k_castT<<<dim3(768, 6), 256, 0, stream>>>(qkv_w, qwt, DMODEL, DQKV);
    k_castT<<<dim3(256, 6), 256, 0, stream>>>(out_w, owt, DMODEL, DMODEL);
    k_castT<<<dim3(512, 6), 256, 0, stream>>>(ff_w1, f1wt, DMODEL, DMLP);
    k_castT<<<dim3(512, 6), 256, 0, stream>>>(ff_w2, f2wt, DMLP, DMODEL);
    k_castConv<256><<<1152, 256, 0, stream>>>(conv1_w, c1wt, 128);
    k_castConv<128><<<288, 256, 0, stream>>>(conv2_w, c2wt, 64);

    // ---- patch embed + pos + LN1(layer0), fused ----
    k_patchify<<<(NROWS * NPD + 255) / 256, 256, 0, stream>>>(img, pA);
    k_gemm_ln<0><<<288, 256, 0, stream>>>(
        pA, pwt, patch_b, pos_emb, ln1_g, ln1_b, x, xn_bf, NPD, 288);

    // ---- transformer layers ----
    for (int l = 0; l < DEPTH; ++l) {
        // QKV GEMM: Q,K -> qkv hi/lo (stride 512); V -> vT hi/lo directly
        k_mm<128, 128, 8, 0><<<6 * 72, 256, 0, stream>>>(
            xn_bf, qwt + (size_t)l * DQKV * DMODEL, nullptr,
            nullptr, qkv_hi, qkv_lo, vthi, vtlo,
            NROWS, DQKV, DMODEL, 0, 0, 6, 72);
        k_attn<<<NBLK * NHEAD * NB, 512, 0, stream>>>(
            qkv_hi, qkv_lo, vthi, vtlo, alpha + l, ao_bf);
        // out-proj + bias + residual + LN2, fused
        k_gemm_ln<1><<<288, 256, 0, stream>>>(
            ao_bf, owt + (size_t)l * DMODEL * DMODEL, out_b + l * DMODEL, nullptr,
            ln2_g + l * DMODEL, ln2_b + l * DMODEL, x, xn_bf, DMODEL, 288);
        // ff1 + gelu
        k_mm<128, 128, 2, 0><<<4 * 72, 256, 0, stream>>>(
            xn_bf, f1wt + (size_t)l * DMLP * DMODEL, ff_b1 + l * DMLP,
            nullptr, h_bf, nullptr, nullptr, nullptr,
            NROWS, DMLP, DMODEL, 0, 0, 4, 72);
        // ff2 + bias + residual + LN(next layer's ln1, or lnf on last)
        const float* ng = (l + 1 < DEPTH) ? (ln1_g + (l + 1) * DMODEL) : lnf_g;
        const float* nb = (l + 1 < DEPTH) ? (ln1_b + (l + 1) * DMODEL) : lnf_b;
        k_gemm_ln<1><<<288, 256, 0, stream>>>(
            h_bf, f2wt + (size_t)l * DMODEL * DMLP, ff_b2 + l * DMODEL, nullptr,
            ng, nb, x, xn_bf, DMLP, 288);
    }

    // ---- head (xn_bf already = LNf output) ----
    k_mm<64, 128, 4, 256><<<1 * 144, 256, 0, stream>>>(
        xn_bf, c1wt, conv1_b, nullptr, c1n, nullptr, nullptr, nullptr,
        NROWS, 128, 9 * 256, 24, 24, 1, 144);
    k_up2n<<<(NB * 48 * 48 * 16 + 255) / 256, 256, 0, stream>>>(c1n, u1n, 24, 128);
    k_mm<128, 64, 4, 128><<<1 * 288, 256, 0, stream>>>(
        u1n, c2wt, conv2_b, nullptr, c2n, nullptr, nullptr, nullptr,
        NB * 48 * 48, 64, 9 * 128, 48, 48, 1, 288);
    k_up2n<<<(NB * 96 * 96 * 8 + 255) / 256, 256, 0, stream>>>(c2n, u2n, 48, 64);
    k_conv3n<<<(NB * 9216 + 255) / 256, 256, 0, stream>>>(u2n, conv3_w, conv3_b, c3);
    k_resize4<<<(OUT_TOTAL + 255) / 256, 256, 0, stream>>>(c3, (float*)d_out);
}

// Round 11
// 1281.413 us; speedup vs baseline: 9.5613x; 1.0089x over previous
//
#include <hip/hip_runtime.h>
#include <cfloat>
#include <cmath>

// ---------------- problem constants ----------------
constexpr int NB    = 16;    // batch
constexpr int IMGSZ = 384;
constexpr int PSZ   = 16;
constexpr int NCH   = 3;
constexpr int DMODEL= 256;
constexpr int DEPTH = 6;
constexpr int NHEAD = 4;
constexpr int DHEAD = 64;
constexpr int DQKV  = 768;   // 3*INNER
constexpr int QKS   = 512;   // Q,K row stride (V lives only in vT)
constexpr int DMLP  = 512;
constexpr int NCLS  = 21;
constexpr int HPATCH= 24;    // IMG/P
constexpr int NTOK  = 576;   // HP*HP
constexpr int NPD   = 768;   // C*P*P
constexpr int TOPK  = 16;
constexpr int NROWS = NB * NTOK;          // 9216
constexpr int OUT_TOTAL = NB * NCLS * IMGSZ * IMGSZ; // 49545216

// attention tiling
constexpr int RPB    = 16;           // query rows per block
constexpr int NBLK   = NTOK / RPB;   // 36 blocks per (b,h)
constexpr int CHUNK  = 64;           // key/value chunk
constexpr int NCHUNK = NTOK / CHUNK; // 9
constexpr int SCP    = 577;          // score row stride (f32)
constexpr int PPS    = 584;          // full-P row stride (bf16)

typedef __attribute__((ext_vector_type(8))) short bf16x8;
typedef __attribute__((ext_vector_type(4))) float f32x4;

__device__ __forceinline__ unsigned short f2bf(float f) {
    unsigned u = __builtin_bit_cast(unsigned, f);
    unsigned r = (u + 0x7FFFu + ((u >> 16) & 1u)) >> 16;
    return (unsigned short)r;
}
__device__ __forceinline__ float bf2f(unsigned short h) {
    unsigned u = ((unsigned)h) << 16;
    return __builtin_bit_cast(float, u);
}

// ---------------- merged weight cast+transpose (all 25 matrices) ------------
// y=0: patch (K=768,N=256); y=1..6 qkv (256,768); y=7..12 out (256,256);
// y=13..18 ff1 (256,512); y=19..24 ff2 (512,256). dst[n*K+k] = bf16(src[k*N+n])
__global__ __launch_bounds__(256) void k_castAll(
    const float* __restrict__ patch_w, const float* __restrict__ qkv_w,
    const float* __restrict__ out_w,   const float* __restrict__ ff_w1,
    const float* __restrict__ ff_w2,
    unsigned short* __restrict__ pwt,  unsigned short* __restrict__ qwt,
    unsigned short* __restrict__ owt,  unsigned short* __restrict__ f1wt,
    unsigned short* __restrict__ f2wt) {
    const int y = blockIdx.y;
    const float* src; unsigned short* dst; int K, N;
    if (y == 0)      { src = patch_w; dst = pwt; K = 768; N = 256; }
    else if (y < 7)  { int l = y - 1;  K = 256; N = 768;
                       src = qkv_w + (size_t)l * K * N; dst = qwt + (size_t)l * K * N; }
    else if (y < 13) { int l = y - 7;  K = 256; N = 256;
                       src = out_w + (size_t)l * K * N; dst = owt + (size_t)l * K * N; }
    else if (y < 19) { int l = y - 13; K = 256; N = 512;
                       src = ff_w1 + (size_t)l * K * N; dst = f1wt + (size_t)l * K * N; }
    else             { int l = y - 19; K = 512; N = 256;
                       src = ff_w2 + (size_t)l * K * N; dst = f2wt + (size_t)l * K * N; }
    int t = blockIdx.x * 256 + threadIdx.x;
    if (t >= K * N) return;
    int n = t / K, k = t - n * K;
    dst[t] = f2bf(src[(size_t)k * N + n]);
}

// conv w [OC][IC][3][3] f32 -> [OC][9][IC] bf16 (tap-major K)
template <int IC>
__global__ __launch_bounds__(256) void k_castConv(const float* __restrict__ src,
                                                  unsigned short* __restrict__ dst,
                                                  int OC) {
    int t = blockIdx.x * 256 + threadIdx.x;
    if (t >= OC * 9 * IC) return;
    int oc = t / (9 * IC);
    int r = t - oc * 9 * IC;
    int tap = r / IC, ic = r - tap * IC;
    dst[t] = f2bf(src[((size_t)(oc * IC + ic)) * 9 + tap]);
}

// ---------------- patchify: img[B,3,384,384] -> A[9216,768] bf16 ------------
__global__ __launch_bounds__(256) void k_patchify(const float* __restrict__ img,
                                                  unsigned short* __restrict__ A) {
    int t = blockIdx.x * 256 + threadIdx.x;
    if (t >= NROWS * NPD) return;
    int r  = t / NPD, pd = t - r * NPD;
    int b  = r / NTOK, n = r - b * NTOK;
    int hy = n / HPATCH, hx = n - hy * HPATCH;
    int c  = pd % NCH;  int q = pd / NCH;
    int p2 = q % PSZ;   int p1 = q / PSZ;
    A[t] = f2bf(img[(((size_t)(b * NCH + c)) * IMGSZ + hy * PSZ + p1) * IMGSZ + hx * PSZ + p2]);
}

// ---------------- unified bf16 MFMA GEMM / implicit conv --------------------
// out[M,N] = A[M,K](bf16) @ Wt[N,K]^T(bf16), fp32 accumulate.
// EPI: 2 bias+gelu->bf16 | 4 bias+relu->bf16
//      8 qkv: cols<512 -> hi/lo @stride 512; cols>=512 -> vT hi/lo only
// CIN>0: gather A from NHWC [NB][H][W][CIN] with 3x3 taps (K = 9*CIN, tap-major)
// Flat grid of gxd*gyd blocks; XCD-aware swizzle keyed on M-tile (gyd%8==0).
template <int BM, int BN, int EPI, int CIN>
__global__ __launch_bounds__(256) void k_mm(
    const unsigned short* __restrict__ Abf,
    const unsigned short* __restrict__ Wt,
    const float* __restrict__ bias,
    float* __restrict__ outf,
    unsigned short* __restrict__ outb,
    unsigned short* __restrict__ outb2,
    unsigned short* __restrict__ vth,
    unsigned short* __restrict__ vtl,
    int M, int Nn, int K, int H, int Wd, int gxd, int gyd)
{
    constexpr int MF = BM / 32;
    constexpr int NF = BN / 32;
    constexpr bool GATHER = (CIN > 0);
    constexpr int AREP = BM * 4 / 256;
    constexpr int BREP = BN * 4 / 256;
    __shared__ __align__(16) short As[4][BM][8];
    __shared__ __align__(16) short Bs[4][BN][8];
    const int tid = threadIdx.x;
    // XCD swizzle: all blocks sharing an M-tile window land on one XCD
    const int p = blockIdx.x;
    const int xr = p & 7, xq = p >> 3;
    const int bm = (xr * (gyd >> 3) + xq / gxd) * BM;
    const int bn = (xq % gxd) * BN;
    const int lane = tid & 63, wid = tid >> 6;
    const int wm = wid >> 1, wn = wid & 1;
    const int l15 = lane & 15, lg = lane >> 4;

    int pb_[AREP], py_[AREP], px_[AREP];
    if (GATHER) {
        #pragma unroll
        for (int rep = 0; rep < AREP; ++rep) {
            int idx = rep * 256 + tid;
            int m = idx >> 2;
            int pix = bm + m;
            px_[rep] = pix % Wd;
            int r = pix / Wd;
            py_[rep] = r % H;
            pb_[rep] = r / H;
        }
    }

    f32x4 acc[MF][NF];
    #pragma unroll
    for (int i = 0; i < MF; ++i)
        #pragma unroll
        for (int j = 0; j < NF; ++j)
            acc[i][j] = (f32x4){0.f, 0.f, 0.f, 0.f};

    for (int k0 = 0; k0 < K; k0 += 32) {
        #pragma unroll
        for (int rep = 0; rep < AREP; ++rep) {
            int idx = rep * 256 + tid;
            int m = idx >> 2, kg = idx & 3;
            if (!GATHER) {
                *(bf16x8*)As[kg][m] =
                    *(const bf16x8*)(Abf + (size_t)(bm + m) * K + k0 + kg * 8);
            } else {
                int k = k0 + kg * 8;
                int tap = k / CIN;
                int ic = k - tap * CIN;
                int dy = tap / 3 - 1, dx = tap % 3 - 1;
                int yy = py_[rep] + dy, xx = px_[rep] + dx;
                bf16x8 v = (bf16x8){0, 0, 0, 0, 0, 0, 0, 0};
                if ((unsigned)yy < (unsigned)H && (unsigned)xx < (unsigned)Wd)
                    v = *(const bf16x8*)(Abf +
                        ((size_t)((pb_[rep] * H + yy) * Wd + xx)) * CIN + ic);
                *(bf16x8*)As[kg][m] = v;
            }
        }
        #pragma unroll
        for (int rep = 0; rep < BREP; ++rep) {
            int idx = rep * 256 + tid;
            int n = idx >> 2, kg = idx & 3;
            *(bf16x8*)Bs[kg][n] =
                *(const bf16x8*)(Wt + (size_t)(bn + n) * K + k0 + kg * 8);
        }
        __syncthreads();
        bf16x8 af[MF], bfv[NF];
        #pragma unroll
        for (int i = 0; i < MF; ++i)
            af[i] = *(const bf16x8*)As[lg][wm * (BM / 2) + i * 16 + l15];
        #pragma unroll
        for (int j = 0; j < NF; ++j)
            bfv[j] = *(const bf16x8*)Bs[lg][wn * (BN / 2) + j * 16 + l15];
        #pragma unroll
        for (int i = 0; i < MF; ++i)
            #pragma unroll
            for (int j = 0; j < NF; ++j)
                acc[i][j] = __builtin_amdgcn_mfma_f32_16x16x32_bf16(
                    af[i], bfv[j], acc[i][j], 0, 0, 0);
        __syncthreads();
    }

    if constexpr (EPI == 8) {
        #pragma unroll
        for (int i = 0; i < MF; ++i) {
            const int row0 = bm + wm * (BM / 2) + i * 16 + lg * 4;
            #pragma unroll
            for (int j = 0; j < NF; ++j) {
                const int col = bn + wn * (BN / 2) + j * 16 + l15;
                if (col < 512) {   // uniform per block (bn multiple of 128)
                    #pragma unroll
                    for (int r = 0; r < 4; ++r) {
                        float v = acc[i][j][r];
                        unsigned short hi = f2bf(v);
                        outb[(size_t)(row0 + r) * QKS + col] = hi;
                        outb2[(size_t)(row0 + r) * QKS + col] = f2bf(v - bf2f(hi));
                    }
                } else {
                    const int d = col - 512, hh = d >> 6, dd = d & 63;
                    const int bb = row0 / NTOK, n = row0 % NTOK;   // 4 rows same bb
                    unsigned long long ph = 0ull, pl = 0ull;
                    #pragma unroll
                    for (int r = 0; r < 4; ++r) {
                        float v = acc[i][j][r];
                        unsigned short hi = f2bf(v);
                        unsigned short lo = f2bf(v - bf2f(hi));
                        ph |= (unsigned long long)hi << (16 * r);
                        pl |= (unsigned long long)lo << (16 * r);
                    }
                    const size_t off = (size_t)((bb * NHEAD + hh) * DHEAD + dd) * NTOK + n;
                    *(unsigned long long*)(vth + off) = ph;
                    *(unsigned long long*)(vtl + off) = pl;
                }
            }
        }
    } else {
        #pragma unroll
        for (int i = 0; i < MF; ++i) {
            const int row0 = bm + wm * (BM / 2) + i * 16 + lg * 4;
            #pragma unroll
            for (int j = 0; j < NF; ++j) {
                const int col = bn + wn * (BN / 2) + j * 16 + l15;
                #pragma unroll
                for (int r = 0; r < 4; ++r) {
                    const int rr = row0 + r;
                    float v = acc[i][j][r] + bias[col];
                    if (EPI == 2) v = 0.5f * v * (1.0f + erff(v * 0.70710678118f));
                    if (EPI == 4) v = fmaxf(v, 0.f);
                    outb[(size_t)rr * Nn + col] = f2bf(v);
                }
            }
        }
    }
}

// ---------------- GEMM + bias(+residual/posemb) + LayerNorm fused -----------
template <int RES>
__global__ __launch_bounds__(256) void k_gemm_ln(
    const unsigned short* __restrict__ Abf,
    const unsigned short* __restrict__ Wt,
    const float* __restrict__ bias,
    const float* __restrict__ extra,
    const float* __restrict__ lng,
    const float* __restrict__ lnb,
    float* __restrict__ x,
    unsigned short* __restrict__ xn,
    int K, int gyd)
{
    constexpr int BM = 32;
    __shared__ __align__(16) short As[4][BM][8];
    __shared__ __align__(16) short Bs[4][256][8];
    __shared__ float redS[BM][4];
    __shared__ float redQ[BM][4];
    const int tid = threadIdx.x;
    const int p = blockIdx.x;
    const int xr = p & 7, xq = p >> 3;
    const int bm = (xr * (gyd >> 3) + xq) * BM;
    const int lane = tid & 63, wn = tid >> 6;
    const int l15 = lane & 15, lg = lane >> 4;

    f32x4 acc[2][4];
    #pragma unroll
    for (int i = 0; i < 2; ++i)
        #pragma unroll
        for (int j = 0; j < 4; ++j)
            acc[i][j] = (f32x4){0.f, 0.f, 0.f, 0.f};

    for (int k0 = 0; k0 < K; k0 += 32) {
        if (tid < BM * 4) {
            int m = tid >> 2, kg = tid & 3;
            *(bf16x8*)As[kg][m] = *(const bf16x8*)(Abf + (size_t)(bm + m) * K + k0 + kg * 8);
        }
        #pragma unroll
        for (int rep = 0; rep < 4; ++rep) {
            int idx = rep * 256 + tid;
            int n = idx >> 2, kg = idx & 3;
            *(bf16x8*)Bs[kg][n] = *(const bf16x8*)(Wt + (size_t)n * K + k0 + kg * 8);
        }
        __syncthreads();
        bf16x8 af[2], bfv[4];
        #pragma unroll
        for (int i = 0; i < 2; ++i)
            af[i] = *(const bf16x8*)As[lg][i * 16 + l15];
        #pragma unroll
        for (int j = 0; j < 4; ++j)
            bfv[j] = *(const bf16x8*)Bs[lg][wn * 64 + j * 16 + l15];
        #pragma unroll
        for (int i = 0; i < 2; ++i)
            #pragma unroll
            for (int j = 0; j < 4; ++j)
                acc[i][j] = __builtin_amdgcn_mfma_f32_16x16x32_bf16(
                    af[i], bfv[j], acc[i][j], 0, 0, 0);
        __syncthreads();
    }

    // ---- epilogue: bias (+res/pos), write x, keep v in acc ----
    #pragma unroll
    for (int i = 0; i < 2; ++i) {
        #pragma unroll
        for (int j = 0; j < 4; ++j) {
            const int col = wn * 64 + j * 16 + l15;
            #pragma unroll
            for (int r = 0; r < 4; ++r) {
                const int rr = bm + i * 16 + lg * 4 + r;
                float v = acc[i][j][r] + bias[col];
                if (RES) v += x[(size_t)rr * DMODEL + col];
                else     v += extra[(size_t)(rr % NTOK) * DMODEL + col];
                x[(size_t)rr * DMODEL + col] = v;
                acc[i][j][r] = v;
            }
        }
    }
    // ---- pass 1: mean ----
    float s[2][4];
    #pragma unroll
    for (int i = 0; i < 2; ++i)
        #pragma unroll
        for (int r = 0; r < 4; ++r)
            s[i][r] = ((acc[i][0][r] + acc[i][1][r]) + acc[i][2][r]) + acc[i][3][r];
    #pragma unroll
    for (int off = 1; off < 16; off <<= 1)
        #pragma unroll
        for (int i = 0; i < 2; ++i)
            #pragma unroll
            for (int r = 0; r < 4; ++r)
                s[i][r] += __shfl_xor(s[i][r], off);
    if (l15 == 0)
        #pragma unroll
        for (int i = 0; i < 2; ++i)
            #pragma unroll
            for (int r = 0; r < 4; ++r)
                redS[i * 16 + lg * 4 + r][wn] = s[i][r];
    __syncthreads();
    float mu[2][4];
    #pragma unroll
    for (int i = 0; i < 2; ++i)
        #pragma unroll
        for (int r = 0; r < 4; ++r) {
            const float* q = redS[i * 16 + lg * 4 + r];
            mu[i][r] = (((q[0] + q[1]) + q[2]) + q[3]) * (1.0f / DMODEL);
        }
    // ---- pass 2: variance ----
    float qq[2][4];
    #pragma unroll
    for (int i = 0; i < 2; ++i)
        #pragma unroll
        for (int r = 0; r < 4; ++r) {
            float d0 = acc[i][0][r] - mu[i][r], d1 = acc[i][1][r] - mu[i][r];
            float d2 = acc[i][2][r] - mu[i][r], d3 = acc[i][3][r] - mu[i][r];
            qq[i][r] = ((d0 * d0 + d1 * d1) + d2 * d2) + d3 * d3;
        }
    #pragma unroll
    for (int off = 1; off < 16; off <<= 1)
        #pragma unroll
        for (int i = 0; i < 2; ++i)
            #pragma unroll
            for (int r = 0; r < 4; ++r)
                qq[i][r] += __shfl_xor(qq[i][r], off);
    if (l15 == 0)
        #pragma unroll
        for (int i = 0; i < 2; ++i)
            #pragma unroll
            for (int r = 0; r < 4; ++r)
                redQ[i * 16 + lg * 4 + r][wn] = qq[i][r];
    __syncthreads();
    #pragma unroll
    for (int i = 0; i < 2; ++i) {
        #pragma unroll
        for (int r = 0; r < 4; ++r) {
            const float* q = redQ[i * 16 + lg * 4 + r];
            float var = (((q[0] + q[1]) + q[2]) + q[3]) * (1.0f / DMODEL);
            float rstd = rsqrtf(var + 1e-5f);
            const int rr = bm + i * 16 + lg * 4 + r;
            #pragma unroll
            for (int j = 0; j < 4; ++j) {
                const int col = wn * 64 + j * 16 + l15;
                float o = (acc[i][j][r] - mu[i][r]) * rstd * lng[col] + lnb[col];
                xn[(size_t)rr * DMODEL + col] = f2bf(o);
            }
        }
    }
}

// ---------------- wave-private hi/lo fragment quad (2 ksl x hi/lo) ----------
struct KF { bf16x8 h0, h1, l0, l1; };
__device__ __forceinline__ KF ldkf(const unsigned short* __restrict__ hi,
                                   const unsigned short* __restrict__ lo,
                                   size_t off) {
    KF f;
    f.h0 = *(const bf16x8*)(hi + off);
    f.h1 = *(const bf16x8*)(hi + off + 32);
    f.l0 = *(const bf16x8*)(lo + off);
    f.l1 = *(const bf16x8*)(lo + off + 32);
    return f;
}

// ---------------- MFMA hybrid attention, 16 rows/block, 512 threads ---------
// 8 waves (par = w>>2 chunk parity, ct = w&3 column tile). Full-P overlay on
// dead score buffer (round-10 structure). This round: first V chunk's load is
// hoisted BEFORE the top-k so its L2 latency hides under the serial VALU.
__global__ __launch_bounds__(512, 8) void k_attn(
    const unsigned short* __restrict__ qhi,
    const unsigned short* __restrict__ qlo,
    const unsigned short* __restrict__ vthi,
    const unsigned short* __restrict__ vtlo,
    const float* __restrict__ alpha_l,
    unsigned short* __restrict__ ao) {
    __shared__ __align__(16) unsigned char ub[2 * RPB * PPS * 2];  // 37376 B
    float* scp = (float*)ub;                  // [16][577] f32 (dead after pull)
    short* php = (short*)ub;                  // [2hl][16][584] bf16 (overlay)
    float* red = (float*)ub;                  // [64][17] f32 (overlay, post-PV)

    const int tid = threadIdx.x;
    const int lane = tid & 63;
    const int w = tid >> 6;                   // 0..7
    const int par = w >> 2;                   // chunk parity handled by this wave
    const int ct = w & 3;                     // column tile
    const int l15 = lane & 15, lg = lane >> 4;
    const int xr = blockIdx.x & 7, xq = blockIdx.x >> 3;
    const int g = xr + 8 * (xq / NBLK);       // group = b*4+h
    const int b = g >> 2, h = g & 3;
    const int i0 = (xq % NBLK) * RPB;

    // ---- Q fragments (A operand), wave-uniform: rows i0+l15 ----
    bf16x8 aqh0, aqh1, aql0, aql1;
    {
        const size_t qoff = (size_t)(b * NTOK + i0 + l15) * QKS + h * DHEAD + lg * 8;
        aqh0 = *(const bf16x8*)(qhi + qoff);
        aqh1 = *(const bf16x8*)(qhi + qoff + 32);
        aql0 = *(const bf16x8*)(qlo + qoff);
        aql1 = *(const bf16x8*)(qlo + qoff + 32);
    }

    // ---- score phase: chunks of this wave's parity ----
    const size_t kRow = (size_t)(b * NTOK + ct * 16 + l15) * QKS + DMODEL + h * DHEAD + lg * 8;
    for (int c = par; c < NCHUNK; c += 2) {
        KF kc = ldkf(qhi, qlo, kRow + (size_t)c * CHUNK * QKS);
        f32x4 sD = (f32x4){0.f, 0.f, 0.f, 0.f};
        sD = __builtin_amdgcn_mfma_f32_16x16x32_bf16(aqh0, kc.h0, sD, 0, 0, 0);
        sD = __builtin_amdgcn_mfma_f32_16x16x32_bf16(aqh0, kc.l0, sD, 0, 0, 0);
        sD = __builtin_amdgcn_mfma_f32_16x16x32_bf16(aql0, kc.h0, sD, 0, 0, 0);
        sD = __builtin_amdgcn_mfma_f32_16x16x32_bf16(aqh1, kc.h1, sD, 0, 0, 0);
        sD = __builtin_amdgcn_mfma_f32_16x16x32_bf16(aqh1, kc.l1, sD, 0, 0, 0);
        sD = __builtin_amdgcn_mfma_f32_16x16x32_bf16(aql1, kc.h1, sD, 0, 0, 0);
        const int col = c * CHUNK + ct * 16 + l15;
        #pragma unroll
        for (int r = 0; r < 4; ++r)
            scp[(lg * 4 + r) * SCP + col] = sD[r] * 0.125f;
    }
    // ---- hoisted first V-chunk load: latency hides under topk VALU ----
    const size_t vRow = (size_t)((b * NHEAD + h) * DHEAD + ct * 16 + l15) * NTOK + lg * 8;
    KF vc = ldkf(vthi, vtlo, vRow + (size_t)par * CHUNK);
    __syncthreads();   // all scores written

    // ---- pull scores to regs (wave w owns rows 2w, 2w+1) ----
    float o_[2][9];
    const int r0 = 2 * w;
    #pragma unroll
    for (int rr = 0; rr < 2; ++rr)
        #pragma unroll
        for (int t = 0; t < 9; ++t)
            o_[rr][t] = scp[(r0 + rr) * SCP + t * 64 + lane];
    __syncthreads();   // score reads done -> scp region reusable as P

    // ---- top-16: iteration-outer, 2 rows interleaved ----
    unsigned msk[2] = {0u, 0u};
    float M_[2];
    for (int k = 0; k < TOPK; ++k) {
        float lm[2];
        #pragma unroll
        for (int rr = 0; rr < 2; ++rr) {
            float m0 = -FLT_MAX;
            #pragma unroll
            for (int t = 0; t < 9; ++t) {
                float v = ((msk[rr] >> t) & 1u) ? -FLT_MAX : o_[rr][t];
                m0 = fmaxf(m0, v);
            }
            lm[rr] = m0;
        }
        #pragma unroll
        for (int off = 1; off < 64; off <<= 1) {
            #pragma unroll
            for (int rr = 0; rr < 2; ++rr)
                lm[rr] = fmaxf(lm[rr], __shfl_xor(lm[rr], off));
        }
        if (k == 0) {
            #pragma unroll
            for (int rr = 0; rr < 2; ++rr) M_[rr] = lm[rr];
        }
        #pragma unroll
        for (int rr = 0; rr < 2; ++rr) {
            int js = -1;
            #pragma unroll
            for (int t = 0; t < 9; ++t) {
                if (js < 0) {   // wave-uniform guard (js from ballot is uniform)
                    unsigned long long bal =
                        __ballot((((msk[rr] >> t) & 1u) == 0u) && (o_[rr][t] == lm[rr]));
                    if (bal) js = t * 64 + (int)__builtin_ctzll(bal);
                }
            }
            if ((js & 63) == lane) msk[rr] |= 1u << (js >> 6);
        }
    }

    // ---- softmax denominators + coefficients ----
    const float al = fminf(fmaxf(alpha_l[0], 0.f), 1.f);
    float gs[2], ss[2];
    #pragma unroll
    for (int rr = 0; rr < 2; ++rr) {
        float g_ = 0.f, s_ = 0.f;
        #pragma unroll
        for (int t = 0; t < 9; ++t) {
            float e = __expf(o_[rr][t] - M_[rr]);
            g_ += e;
            if ((msk[rr] >> t) & 1u) s_ += e;
        }
        gs[rr] = g_; ss[rr] = s_;
    }
    #pragma unroll
    for (int off = 1; off < 64; off <<= 1) {
        #pragma unroll
        for (int rr = 0; rr < 2; ++rr) {
            gs[rr] += __shfl_xor(gs[rr], off);
            ss[rr] += __shfl_xor(ss[rr], off);
        }
    }
    float ca[2], cs[2];
    #pragma unroll
    for (int rr = 0; rr < 2; ++rr) {
        ca[rr] = al / gs[rr];
        cs[rr] = (1.f - al) / ss[rr];
    }

    // ---- write FULL P hi/lo (rows 2w, 2w+1 over all 9 chunks) ----
    #pragma unroll
    for (int rr = 0; rr < 2; ++rr) {
        const int row = r0 + rr;
        #pragma unroll
        for (int t = 0; t < 9; ++t) {
            float e = __expf(o_[rr][t] - M_[rr]);
            float wv = e * (ca[rr] + (((msk[rr] >> t) & 1u) ? cs[rr] : 0.f));
            unsigned short hi = f2bf(wv);
            php[row * PPS + t * 64 + lane] = (short)hi;
            php[RPB * PPS + row * PPS + t * 64 + lane] = (short)f2bf(wv - bf2f(hi));
        }
    }
    __syncthreads();   // full P visible

    // ---- PV phase: barrier-free, parity chunks, V prefetched 1 ahead ----
    f32x4 acc = (f32x4){0.f, 0.f, 0.f, 0.f};
    for (int c = par; c < NCHUNK; c += 2) {
        KF vn;
        if (c + 2 < NCHUNK)
            vn = ldkf(vthi, vtlo, vRow + (size_t)(c + 2) * CHUNK);
        const short* pr = php + l15 * PPS + c * 64 + lg * 8;
        bf16x8 ah0 = *(const bf16x8*)(pr);
        bf16x8 ah1 = *(const bf16x8*)(pr + 32);
        bf16x8 al0 = *(const bf16x8*)(pr + RPB * PPS);
        bf16x8 al1 = *(const bf16x8*)(pr + RPB * PPS + 32);
        acc = __builtin_amdgcn_mfma_f32_16x16x32_bf16(ah0, vc.h0, acc, 0, 0, 0);
        acc = __builtin_amdgcn_mfma_f32_16x16x32_bf16(ah0, vc.l0, acc, 0, 0, 0);
        acc = __builtin_amdgcn_mfma_f32_16x16x32_bf16(al0, vc.h0, acc, 0, 0, 0);
        acc = __builtin_amdgcn_mfma_f32_16x16x32_bf16(ah1, vc.h1, acc, 0, 0, 0);
        acc = __builtin_amdgcn_mfma_f32_16x16x32_bf16(ah1, vc.l1, acc, 0, 0, 0);
        acc = __builtin_amdgcn_mfma_f32_16x16x32_bf16(al1, vc.h1, acc, 0, 0, 0);
        if (c + 2 < NCHUNK) vc = vn;
    }
    __syncthreads();   // all P reads done -> red may overlay
    if (par == 1) {
        #pragma unroll
        for (int r = 0; r < 4; ++r)
            red[(ct * 16 + l15) * 17 + lg * 4 + r] = acc[r];
    }
    __syncthreads();
    if (par == 0) {
        const int qrow = i0 + lg * 4;
        const int dcol = h * DHEAD + ct * 16 + l15;
        #pragma unroll
        for (int r = 0; r < 4; ++r) {
            float v = acc[r] + red[(ct * 16 + l15) * 17 + lg * 4 + r];
            ao[(size_t)(b * NTOK + qrow + r) * DMODEL + dcol] = f2bf(v);
        }
    }
}

// ---------------- bilinear helpers (jax.image.resize half-pixel) ------------
__device__ __forceinline__ void bilin_axis(float sF, int H, int& i0, int& i1, float& f) {
    float fl = floorf(sF);
    f = sF - fl;
    int lo = (int)fl;
    i0 = lo < 0 ? 0 : (lo > H - 1 ? H - 1 : lo);
    int hi = lo + 1;
    i1 = hi < 0 ? 0 : (hi > H - 1 ? H - 1 : hi);
}

// NHWC bf16 2x bilinear upsample
__global__ __launch_bounds__(256) void k_up2n(const unsigned short* __restrict__ in,
                                              unsigned short* __restrict__ outp,
                                              int Hin, int C) {
    const int Ho = 2 * Hin;
    const int CG = C / 8;
    const int total = NB * Ho * Ho * CG;
    int t = blockIdx.x * 256 + threadIdx.x;
    if (t >= total) return;
    int cg = t % CG; int r = t / CG;
    int x = r % Ho; r /= Ho;
    int y = r % Ho; int b = r / Ho;
    int i0, i1, j0, j1; float fy, fx;
    bilin_axis(0.5f * y - 0.25f, Hin, i0, i1, fy);
    bilin_axis(0.5f * x - 0.25f, Hin, j0, j1, fx);
    const unsigned short* base = in + (size_t)b * Hin * Hin * C + cg * 8;
    const bf16x8 p00 = *(const bf16x8*)(base + (size_t)(i0 * Hin + j0) * C);
    const bf16x8 p01 = *(const bf16x8*)(base + (size_t)(i0 * Hin + j1) * C);
    const bf16x8 p10 = *(const bf16x8*)(base + (size_t)(i1 * Hin + j0) * C);
    const bf16x8 p11 = *(const bf16x8*)(base + (size_t)(i1 * Hin + j1) * C);
    bf16x8 o;
    #pragma unroll
    for (int e = 0; e < 8; ++e) {
        float v = (1.f - fy) * ((1.f - fx) * bf2f((unsigned short)p00[e]) + fx * bf2f((unsigned short)p01[e]))
                + fy        * ((1.f - fx) * bf2f((unsigned short)p10[e]) + fx * bf2f((unsigned short)p11[e]));
        o[e] = (short)f2bf(v);
    }
    *(bf16x8*)(outp + (size_t)t * 8) = o;
}

// ---------------- conv3: 1x1, 64->21, NHWC bf16 in -> NCHW f32 out ----------
__global__ __launch_bounds__(256) void k_conv3n(const unsigned short* __restrict__ in,
                                                const float* __restrict__ w,
                                                const float* __restrict__ bias,
                                                float* __restrict__ outp) {
    __shared__ float ws_[NCLS * 64];
    for (int i = threadIdx.x; i < NCLS * 64; i += 256) ws_[i] = w[i];
    __syncthreads();
    int t = blockIdx.x * 256 + threadIdx.x;
    if (t >= NB * 9216) return;
    int pix = t % 9216, b = t / 9216;
    float xv[64];
    const unsigned short* p = in + (size_t)t * 64;
    #pragma unroll
    for (int c = 0; c < 8; ++c) {
        bf16x8 v = *(const bf16x8*)(p + c * 8);
        #pragma unroll
        for (int e = 0; e < 8; ++e) xv[c * 8 + e] = bf2f((unsigned short)v[e]);
    }
    float* op = outp + (size_t)b * NCLS * 9216 + pix;
    #pragma unroll
    for (int o = 0; o < NCLS; ++o) {
        float acc = bias[o];
        #pragma unroll
        for (int ic = 0; ic < 64; ++ic) acc += ws_[o * 64 + ic] * xv[ic];
        op[(size_t)o * 9216] = acc;
    }
}

// ---------------- final resize 96 -> 384 (4x bilinear), f32 NCHW, float4 ----
__global__ __launch_bounds__(256) void k_resize4(const float* __restrict__ in,
                                                 float* __restrict__ outp) {
    int t = blockIdx.x * 256 + threadIdx.x;   // over OUT_TOTAL/4
    if (t >= OUT_TOTAL / 4) return;
    const int xq = t % (IMGSZ / 4);
    int r = t / (IMGSZ / 4);
    const int y = r % IMGSZ;
    const int bc = r / IMGSZ;
    int i0, i1; float fy;
    bilin_axis(0.25f * y - 0.375f, 96, i0, i1, fy);
    const float* p = in + (size_t)bc * 9216;
    const float* row0 = p + i0 * 96;
    const float* row1 = p + i1 * 96;
    float4 o;
    float* oe = (float*)&o;
    #pragma unroll
    for (int e = 0; e < 4; ++e) {
        const int x = xq * 4 + e;
        int j0, j1; float fx;
        bilin_axis(0.25f * x - 0.375f, 96, j0, j1, fx);
        oe[e] = (1.f - fy) * ((1.f - fx) * row0[j0] + fx * row0[j1])
              + fy        * ((1.f - fx) * row1[j0] + fx * row1[j1]);
    }
    *(float4*)(outp + (size_t)t * 4) = o;
}

// ---------------- orchestration ----------------
extern "C" void kernel_launch(void* const* d_in, const int* in_sizes, int n_in,
                              void* d_out, int out_size, void* d_ws, size_t ws_size,
                              hipStream_t stream) {
    const float* img     = (const float*)d_in[0];
    const float* patch_w = (const float*)d_in[1];
    const float* patch_b = (const float*)d_in[2];
    const float* pos_emb = (const float*)d_in[3];
    const float* ln1_g   = (const float*)d_in[4];
    const float* ln1_b   = (const float*)d_in[5];
    const float* qkv_w   = (const float*)d_in[6];
    const float* out_w   = (const float*)d_in[7];
    const float* out_b   = (const float*)d_in[8];
    const float* alpha   = (const float*)d_in[9];
    const float* ln2_g   = (const float*)d_in[10];
    const float* ln2_b   = (const float*)d_in[11];
    const float* ff_w1   = (const float*)d_in[12];
    const float* ff_b1   = (const float*)d_in[13];
    const float* ff_w2   = (const float*)d_in[14];
    const float* ff_b2   = (const float*)d_in[15];
    const float* lnf_g   = (const float*)d_in[16];
    const float* lnf_b   = (const float*)d_in[17];
    const float* conv1_w = (const float*)d_in[18];
    const float* conv1_b = (const float*)d_in[19];
    const float* conv2_w = (const float*)d_in[20];
    const float* conv2_b = (const float*)d_in[21];
    const float* conv3_w = (const float*)d_in[22];
    const float* conv3_b = (const float*)d_in[23];

    // ---- workspace layout (~78 MB) ----
    float* x = (float*)d_ws;                                         // [9216][256] f32
    unsigned short* qkv_hi = (unsigned short*)(x + (size_t)NROWS * DMODEL); // [9216][512] (Q,K)
    unsigned short* qkv_lo = qkv_hi + (size_t)NROWS * QKS;           // [9216][512]
    unsigned short* xn_bf  = qkv_lo + (size_t)NROWS * QKS;           // [9216][256]
    unsigned short* ao_bf  = xn_bf + (size_t)NROWS * DMODEL;         // [9216][256]
    unsigned short* h_bf   = ao_bf + (size_t)NROWS * DMODEL;         // [9216][512]
    unsigned short* pA     = h_bf + (size_t)NROWS * DMLP;            // [9216][768]
    unsigned short* wts    = pA + (size_t)NROWS * NPD;
    unsigned short* pwt  = wts;                       // [256][768]
    unsigned short* qwt  = pwt  + 768 * 256;          // [6][768][256]
    unsigned short* owt  = qwt  + 6 * 768 * 256;      // [6][256][256]
    unsigned short* f1wt = owt  + 6 * 256 * 256;      // [6][512][256]
    unsigned short* f2wt = f1wt + 6 * 256 * 512;      // [6][256][512]
    unsigned short* c1wt = f2wt + 6 * 512 * 256;      // [128][9*256]
    unsigned short* c2wt = c1wt + 128 * 9 * 256;      // [64][9*128]
    unsigned short* vthi = c2wt + 64 * 9 * 128;       // [64*64][576]
    unsigned short* vtlo = vthi + (size_t)64 * 64 * NTOK;
    // conv-stage aliases (transformer buffers free by then)
    unsigned short* c1n = ao_bf;            // [16][24][24][128]
    unsigned short* u1n = h_bf;             // [16][48][48][128]
    unsigned short* c2n = xn_bf;            // [16][48][48][64]
    unsigned short* u2n = qkv_hi;           // [16][96][96][64] (spans hi+lo exactly)
    float* c3 = (float*)pA;                 // [16][21][96][96] f32

    // ---- weight casts (merged) ----
    k_castAll<<<dim3(768, 25), 256, 0, stream>>>(
        patch_w, qkv_w, out_w, ff_w1, ff_w2, pwt, qwt, owt, f1wt, f2wt);
    k_castConv<256><<<1152, 256, 0, stream>>>(conv1_w, c1wt, 128);
    k_castConv<128><<<288, 256, 0, stream>>>(conv2_w, c2wt, 64);

    // ---- patch embed + pos + LN1(layer0), fused ----
    k_patchify<<<(NROWS * NPD + 255) / 256, 256, 0, stream>>>(img, pA);
    k_gemm_ln<0><<<288, 256, 0, stream>>>(
        pA, pwt, patch_b, pos_emb, ln1_g, ln1_b, x, xn_bf, NPD, 288);

    // ---- transformer layers ----
    for (int l = 0; l < DEPTH; ++l) {
        // QKV GEMM: Q,K -> qkv hi/lo (stride 512); V -> vT hi/lo directly
        k_mm<128, 128, 8, 0><<<6 * 72, 256, 0, stream>>>(
            xn_bf, qwt + (size_t)l * DQKV * DMODEL, nullptr,
            nullptr, qkv_hi, qkv_lo, vthi, vtlo,
            NROWS, DQKV, DMODEL, 0, 0, 6, 72);
        k_attn<<<NBLK * NHEAD * NB, 512, 0, stream>>>(
            qkv_hi, qkv_lo, vthi, vtlo, alpha + l, ao_bf);
        // out-proj + bias + residual + LN2, fused
        k_gemm_ln<1><<<288, 256, 0, stream>>>(
            ao_bf, owt + (size_t)l * DMODEL * DMODEL, out_b + l * DMODEL, nullptr,
            ln2_g + l * DMODEL, ln2_b + l * DMODEL, x, xn_bf, DMODEL, 288);
        // ff1 + gelu
        k_mm<128, 128, 2, 0><<<4 * 72, 256, 0, stream>>>(
            xn_bf, f1wt + (size_t)l * DMLP * DMODEL, ff_b1 + l * DMLP,
            nullptr, h_bf, nullptr, nullptr, nullptr,
            NROWS, DMLP, DMODEL, 0, 0, 4, 72);
        // ff2 + bias + residual + LN(next layer's ln1, or lnf on last)
        const float* ng = (l + 1 < DEPTH) ? (ln1_g + (l + 1) * DMODEL) : lnf_g;
        const float* nb = (l + 1 < DEPTH) ? (ln1_b + (l + 1) * DMODEL) : lnf_b;
        k_gemm_ln<1><<<288, 256, 0, stream>>>(
            h_bf, f2wt + (size_t)l * DMODEL * DMLP, ff_b2 + l * DMODEL, nullptr,
            ng, nb, x, xn_bf, DMLP, 288);
    }

    // ---- head (xn_bf already = LNf output) ----
    // conv1: BN=64 -> 288 blocks (was 144: half-idle tail on 256 CUs)
    k_mm<64, 64, 4, 256><<<2 * 144, 256, 0, stream>>>(
        xn_bf, c1wt, conv1_b, nullptr, c1n, nullptr, nullptr, nullptr,
        NROWS, 128, 9 * 256, 24, 24, 2, 144);
    k_up2n<<<(NB * 48 * 48 * 16 + 255) / 256, 256, 0, stream>>>(c1n, u1n, 24, 128);
    k_mm<128, 64, 4, 128><<<1 * 288, 256, 0, stream>>>(
        u1n, c2wt, conv2_b, nullptr, c2n, nullptr, nullptr, nullptr,
        NB * 48 * 48, 64, 9 * 128, 48, 48, 1, 288);
    k_up2n<<<(NB * 96 * 96 * 8 + 255) / 256, 256, 0, stream>>>(c2n, u2n, 48, 64);
    k_conv3n<<<(NB * 9216 + 255) / 256, 256, 0, stream>>>(u2n, conv3_w, conv3_b, c3);
    k_resize4<<<(OUT_TOTAL / 4 + 255) / 256, 256, 0, stream>>>(c3, (float*)d_out);
}